// Round 11
// baseline (378.020 us; speedup 1.0000x reference)
//
#include <hip/hip_runtime.h>
#include <math.h>

typedef unsigned short u16;
typedef __attribute__((ext_vector_type(8))) short short8;
typedef __attribute__((ext_vector_type(4))) float floatx4;

#define DEV __device__ __forceinline__

DEV u16 f2bs(float f){ union{float f; unsigned u;} v; v.f=f; unsigned r = v.u + 0x7fffu + ((v.u>>16)&1u); return (u16)(r>>16); }
DEV float bs2f(u16 u){ union{float f; unsigned u;} v; v.u = ((unsigned)u)<<16; return v.f; }

// tanh-form GELU (max |delta| vs exact-erf gelu ~3e-4; bf16-safe).
DEV float gelu_f(float x){
  float u2 = 2.f * x * (0.7978845608028654f + 0.03567740813636141f*x*x);
  float e = __expf(u2);
  float th = 1.f - 2.f/(e + 1.f);
  return 0.5f*x*(1.f + th);
}

#define GLL16(G,L) __builtin_amdgcn_global_load_lds((__attribute__((address_space(1))) const void*)(G), (__attribute__((address_space(3))) void*)(L), 16, 0, 0)

enum { EP_BF16=0, EP_F32RES=3, EP_GELU=4 };

// XCD-chunked bijective block swizzle (m204) + group-major (G rows) ordering.
DEV void swizzle_bid(int orig, int gx, int gy, int& bx, int& by){
  const int nwg = gx*gy;
  const int q = nwg >> 3, r = nwg & 7;
  const int xcd = orig & 7, idx = orig >> 3;
  const int logical = (xcd < r) ? xcd*(q+1) + idx : r*(q+1) + (xcd-r)*q + idx;
  const int G = 8;
  const int per = G*gx;
  const int gid = logical / per;
  const int rem = logical - gid*per;
  const int by0 = gid*G;
  const int rows = min(G, gy - by0);
  by = by0 + rem % rows;
  bx = rem / rows;
}

// C[m][n] = sum_k A[m][k]*B[n][k]  (B^T layout), bf16 in, fp32 acc.
// 256x256 tile, 8 waves (WM=128,WN=64 -> FM=8,FN=4): LDS-read/MFMA cycle
// ratio 1.2 (vs 2.4 at FM4/FN2) -- fixes the LDS-BW bound diagnosed in R10.
// BK=64 [rows][64] tiles, 8-chunk XOR swizzle (0 conflicts, R9-verified).
// Depth-2 counted vmcnt + raw barriers + setprio (R9-verified skeleton).
template<int BM,int BN,int WM,int WN,int MODE,bool LORA,bool SWZ>
__global__ __launch_bounds__((BM/WM)*(BN/WN)*64) void gemm_bt(
    const u16* __restrict__ A, int lda,
    const u16* __restrict__ B, int ldb,
    int K,
    u16* __restrict__ obf, float* __restrict__ of32, int ldc,
    const float* __restrict__ bias,
    const u16* __restrict__ tA, int tlda,   // [M][tlda], 64-wide slices, cols 16..63 zero
    const u16* __restrict__ lbB,            // [N][64], cols 16..63 zero
    const float* __restrict__ resid)
{
  constexpr int NWM = BM/WM, NWN = BN/WN, NW = NWM*NWN;
  constexpr int FM = WM/16, FN = WN/16;
  constexpr int TILE = (BM+BN)*64;           // u16 elements per buffer
  constexpr int LPT = (BM+BN)/(8*NW);        // GLL16 per wave per tile
  static_assert(NW==4 || NW==8, "4 or 8 waves");
  static_assert((BM/8)%NW==0 && (BN/8)%NW==0, "row-group striping");
  __shared__ u16 ab[2*TILE];

  const int tid = threadIdx.x;
  const int lane = tid & 63, wave = tid >> 6;
  const int wr = wave / NWN, wc = wave % NWN;
  const int row16 = lane & 15, kgrp = lane >> 4;
  int bx = blockIdx.x, by = blockIdx.y;
  if constexpr (SWZ)
    swizzle_bid(blockIdx.y*gridDim.x + blockIdx.x, gridDim.x, gridDim.y, bx, by);
  const int bm0 = by * BM, bn0 = bx * BN;

  const u16* Ab = A + (long)bm0*lda;
  const u16* Bb = B + (long)bn0*ldb;
  const int tsel = (LORA && tlda==192) ? ((bn0>>10)*64) : 0;
  // staging: lane covers (row = g*8 + (lane>>3), chunk = lane&7); source
  // chunk pre-swizzled by ^row&7 so LDS is linear but logically swizzled.
  const int srow = lane >> 3;
  const int gcol = ((lane&7) ^ srow) * 8;

  const int nKT = K >> 6;
  const int nIT = nKT + (LORA ? 1 : 0);

  auto stage = [&](int kt, int buf){
    const u16 *Ak, *Bk; long la_, lb_;
    if (!LORA || kt < nKT){ Ak = Ab + kt*64; la_ = lda; Bk = Bb + kt*64; lb_ = ldb; }
    else { Ak = tA + (long)bm0*tlda + tsel; la_ = tlda; Bk = lbB + (long)bn0*64; lb_ = 64; }
    char* l = (char*)(ab + buf*TILE);
    #pragma unroll
    for (int g0=0; g0<BM/8; g0+=NW){
      int g = g0 + wave;
      GLL16(Ak + (long)(g*8 + srow)*la_ + gcol, l + g*1024);
    }
    #pragma unroll
    for (int g0=0; g0<BN/8; g0+=NW){
      int g = g0 + wave;
      GLL16(Bk + (long)(g*8 + srow)*lb_ + gcol, l + BM*128 + g*1024);
    }
  };

  floatx4 acc[FM][FN];
  #pragma unroll
  for (int i=0;i<FM;i++)
    #pragma unroll
    for (int j=0;j<FN;j++)
      acc[i][j] = (floatx4){0.f,0.f,0.f,0.f};

  stage(0, 0);
  if (nIT > 1) stage(1, 1);
  int cur = 0;
  for (int kt=0; kt<nIT; ++kt){
    if (kt+1 < nIT) asm volatile("s_waitcnt vmcnt(%0)" :: "n"(LPT) : "memory");
    else            asm volatile("s_waitcnt vmcnt(0)" ::: "memory");
    __builtin_amdgcn_s_barrier();

    const char* lds = (const char*)(ab + cur*TILE);
    __builtin_amdgcn_s_setprio(1);
    #pragma unroll
    for (int ks=0; ks<2; ++ks){
      short8 af[FM], bfr[FN];
      #pragma unroll
      for (int mi=0;mi<FM;mi++){
        int r_ = wr*WM + mi*16 + row16;
        af[mi] = *(const short8*)(lds + r_*128 + (((ks*4 + kgrp) ^ (r_&7))<<4));
      }
      #pragma unroll
      for (int ni=0;ni<FN;ni++){
        int r_ = wc*WN + ni*16 + row16;
        bfr[ni] = *(const short8*)(lds + BM*128 + r_*128 + (((ks*4 + kgrp) ^ (r_&7))<<4));
      }
      #pragma unroll
      for (int mi=0;mi<FM;mi++)
        #pragma unroll
        for (int ni=0;ni<FN;ni++)
          acc[mi][ni] = __builtin_amdgcn_mfma_f32_16x16x32_bf16(af[mi], bfr[ni], acc[mi][ni], 0, 0, 0);
    }
    __builtin_amdgcn_s_setprio(0);

    asm volatile("s_waitcnt lgkmcnt(0)" ::: "memory");
    __builtin_amdgcn_sched_barrier(0);
    __builtin_amdgcn_s_barrier();        // all waves done reading buf[cur]
    if (kt+2 < nIT) stage(kt+2, cur);    // refill freed buffer
    cur ^= 1;
  }

  #pragma unroll
  for (int mi=0;mi<FM;mi++){
    #pragma unroll
    for (int r=0;r<4;r++){
      const int ml = wr*WM + mi*16 + kgrp*4 + r;
      const long mg = bm0 + ml;
      #pragma unroll
      for (int ni=0;ni<FN;ni++){
        const int nl = wc*WN + ni*16 + row16;
        const int ng = bn0 + nl;
        float v = acc[mi][ni][r] + bias[ng];
        if constexpr (MODE==EP_F32RES){
          v += resid[mg*ldc + ng];
          of32[mg*ldc + ng] = v;
        } else if constexpr (MODE==EP_GELU){
          obf[mg*ldc + ng] = f2bs(gelu_f(v));
        } else {
          obf[mg*ldc + ng] = f2bs(v);
        }
      }
    }
  }
}

// ---- LoRA stage-1 via MFMA: t[m][r] = sum_k A[m][k]*la[k][r] ----
// Output t: [M][tld], per-target 64-wide slice, cols 16..63 zeroed.
template<int NT>
__global__ __launch_bounds__(64) void lora_mfma(
    const u16* __restrict__ A, const int K,
    const u16* __restrict__ lat,
    u16* __restrict__ t, int tld)
{
  const int lane = threadIdx.x & 63;
  const int c = lane & 15, kg = lane >> 4;
  const int m0 = blockIdx.x * 16;
  const u16* Arow = A + (long)(m0 + c)*K + kg*8;
  const u16* Brow = lat + (long)c*K + kg*8;
  floatx4 acc[NT];
  #pragma unroll
  for (int tj=0;tj<NT;tj++) acc[tj] = (floatx4){0.f,0.f,0.f,0.f};
  const int nKS = K >> 5;
  #pragma unroll 4
  for (int ks=0; ks<nKS; ++ks){
    short8 a = *(const short8*)(Arow + ks*32);
    #pragma unroll
    for (int tj=0; tj<NT; ++tj){
      short8 b = *(const short8*)(Brow + (long)tj*16*K + ks*32);
      acc[tj] = __builtin_amdgcn_mfma_f32_16x16x32_bf16(a, b, acc[tj], 0, 0, 0);
    }
  }
  #pragma unroll
  for (int tj=0; tj<NT; ++tj)
    #pragma unroll
    for (int r=0;r<4;r++){
      u16* dst = t + (long)(m0 + kg*4 + r)*tld + tj*64;
      dst[c] = f2bs(acc[tj][r]);
      dst[16+c] = 0; dst[32+c] = 0; dst[48+c] = 0;
    }
}

// ---- fused flash attention: per (q-tile 128, head) block, 4 waves ----
__global__ __launch_bounds__(256) void flash_attn(
    const u16* __restrict__ qkv,   // [4096][3072]
    const u16* __restrict__ vt,    // [128][64][512]
    const float* __restrict__ mask,// [8][512]
    u16* __restrict__ attn_o)      // [4096][1024]
{
  __shared__ u16 sm[33792]; // Q[128][64] | K dbuf 2x4096 | V dbuf 2x4096 | P 4x[32][72]
  u16* Qs = sm;
  u16* Ps = sm + 24576;

  const int tid = threadIdx.x, lane = tid & 63, wave = tid >> 6;
  const int c = lane & 15, kg = lane >> 4;
  const int qt = blockIdx.x;        // 0..3
  const int z  = blockIdx.y;        // b*16+h
  const int b = z >> 4, h = z & 15;
  const int q0 = qt * 128;
  const int srow = lane >> 3;
  const int scol = ((lane&7) ^ srow) * 8;

  const u16* kbase = qkv + ((long)(b*512))*3072 + 1024 + h*64;
  const u16* vbase = vt + (long)z*64*512;

  auto stage_kv = [&](int kv, int buf){
    char* Kd = (char*)(sm + 8192  + buf*4096);
    char* Vd = (char*)(sm + 16384 + buf*4096);
    #pragma unroll
    for (int i=0;i<2;i++){
      int rb = i*32 + wave*8;
      GLL16(kbase + (long)(kv*64 + rb + srow)*3072 + scol, Kd + rb*128);
      GLL16(vbase + (long)(rb + srow)*512 + kv*64 + scol, Vd + rb*128);
    }
  };

  {
    const u16* src = qkv + ((long)(b*512 + q0))*3072 + h*64;
    #pragma unroll
    for (int i=0;i<4;i++){
      int rb = i*32 + wave*8;
      GLL16(src + (long)(rb + srow)*3072 + scol, (char*)Qs + rb*128);
    }
  }
  stage_kv(0, 0);
  __syncthreads();

  auto ld_swz = [&](const u16* t, int row, int koff8) -> short8 {
    return *(const short8*)((const char*)t + row*128 + ((koff8 ^ (row&7))<<4));
  };

  short8 af[2][2];
  #pragma unroll
  for (int mi=0;mi<2;mi++)
    #pragma unroll
    for (int ks=0;ks<2;ks++)
      af[mi][ks] = ld_swz(Qs, wave*32 + mi*16 + c, ks*4 + kg);

  floatx4 o_acc[2][4];
  float m_run[2][4], l_run[2][4];
  #pragma unroll
  for (int mi=0;mi<2;mi++){
    #pragma unroll
    for (int dj=0;dj<4;dj++) o_acc[mi][dj] = (floatx4){0.f,0.f,0.f,0.f};
    #pragma unroll
    for (int r=0;r<4;r++){ m_run[mi][r] = -3.0e38f; l_run[mi][r] = 0.f; }
  }

  int cur = 0;
  for (int kv=0; kv<8; ++kv){
    if (kv+1 < 8) stage_kv(kv+1, cur^1);   // prefetch next K/V
    const u16* Ks = sm + 8192  + cur*4096;
    const u16* Vs = sm + 16384 + cur*4096;

    floatx4 s_acc[2][4];
    #pragma unroll
    for (int mi=0;mi<2;mi++)
      #pragma unroll
      for (int ni=0;ni<4;ni++)
        s_acc[mi][ni] = (floatx4){0.f,0.f,0.f,0.f};
    #pragma unroll
    for (int ks=0;ks<2;ks++){
      short8 bf[4];
      #pragma unroll
      for (int ni=0;ni<4;ni++)
        bf[ni] = ld_swz(Ks, ni*16 + c, ks*4 + kg);
      #pragma unroll
      for (int mi=0;mi<2;mi++)
        #pragma unroll
        for (int ni=0;ni<4;ni++)
          s_acc[mi][ni] = __builtin_amdgcn_mfma_f32_16x16x32_bf16(af[mi][ks], bf[ni], s_acc[mi][ni], 0, 0, 0);
    }

    float mv[4];
    #pragma unroll
    for (int ni=0;ni<4;ni++) mv[ni] = mask[b*512 + kv*64 + ni*16 + c];

    #pragma unroll
    for (int mi=0;mi<2;mi++){
      #pragma unroll
      for (int r=0;r<4;r++){
        float s0 = s_acc[mi][0][r]*0.125f + mv[0];
        float s1 = s_acc[mi][1][r]*0.125f + mv[1];
        float s2 = s_acc[mi][2][r]*0.125f + mv[2];
        float s3 = s_acc[mi][3][r]*0.125f + mv[3];
        float tmax = fmaxf(fmaxf(s0,s1), fmaxf(s2,s3));
        #pragma unroll
        for (int o=1;o<16;o<<=1) tmax = fmaxf(tmax, __shfl_xor(tmax, o));
        const float mnew = fmaxf(m_run[mi][r], tmax);
        const float p0 = __expf(s0 - mnew), p1 = __expf(s1 - mnew);
        const float p2 = __expf(s2 - mnew), p3 = __expf(s3 - mnew);
        float psum = p0+p1+p2+p3;
        #pragma unroll
        for (int o=1;o<16;o<<=1) psum += __shfl_xor(psum, o);
        const float alpha = __expf(m_run[mi][r] - mnew);
        l_run[mi][r] = l_run[mi][r]*alpha + psum;
        m_run[mi][r] = mnew;
        #pragma unroll
        for (int dj=0;dj<4;dj++) o_acc[mi][dj][r] *= alpha;
        const int rl = mi*16 + kg*4 + r;
        u16* pw = Ps + wave*2304 + rl*72;
        pw[c]      = f2bs(p0);
        pw[16 + c] = f2bs(p1);
        pw[32 + c] = f2bs(p2);
        pw[48 + c] = f2bs(p3);
      }
    }
    __syncthreads();

    #pragma unroll
    for (int ks=0;ks<2;ks++){
      short8 pa[2], vb[4];
      #pragma unroll
      for (int mi=0;mi<2;mi++)
        pa[mi] = *(const short8*)&Ps[wave*2304 + (mi*16 + c)*72 + ks*32 + kg*8];
      #pragma unroll
      for (int dj=0;dj<4;dj++)
        vb[dj] = ld_swz(Vs, dj*16 + c, ks*4 + kg);
      __builtin_amdgcn_s_setprio(1);
      #pragma unroll
      for (int mi=0;mi<2;mi++)
        #pragma unroll
        for (int dj=0;dj<4;dj++)
          o_acc[mi][dj] = __builtin_amdgcn_mfma_f32_16x16x32_bf16(pa[mi], vb[dj], o_acc[mi][dj], 0, 0, 0);
      __builtin_amdgcn_s_setprio(0);
    }
    __syncthreads();
    cur ^= 1;
  }

  #pragma unroll
  for (int mi=0;mi<2;mi++){
    #pragma unroll
    for (int r=0;r<4;r++){
      const float inv = 1.f / l_run[mi][r];
      const int s_g = q0 + wave*32 + mi*16 + kg*4 + r;
      u16* dst = attn_o + (long)(b*512 + s_g)*1024 + h*64;
      #pragma unroll
      for (int dj=0;dj<4;dj++)
        dst[dj*16 + c] = f2bs(o_acc[mi][dj][r]*inv);
    }
  }
}

// ---- bulk fp32 -> bf16 conversion, float4 wide ----
__global__ __launch_bounds__(256) void convert_bulk(
  const float* __restrict__ x,
  const float* __restrict__ wq, const float* __restrict__ wk, const float* __restrict__ wv,
  const float* __restrict__ wo, const float* __restrict__ wup, const float* __restrict__ wdn,
  u16* __restrict__ xb, u16* __restrict__ wqkv, u16* __restrict__ wob,
  u16* __restrict__ wupb, u16* __restrict__ wdnb)
{
  const long NX = 4194304, NWt = 1048576;
  const long T4 = (NX + 3*NWt + NWt + NX + NX) >> 2;
  for (long i4 = (long)blockIdx.x*256 + threadIdx.x; i4 < T4; i4 += (long)gridDim.x*256){
    long j = i4 << 2;
    const float* src; u16* dst; long soff, doff;
    if (j < NX){ src=x; dst=xb; soff=j; doff=j; }
    else { j -= NX;
      if (j < 3*NWt){ int p=(int)(j>>20); src = p==0?wq:(p==1?wk:wv); dst=wqkv; soff = j & (NWt-1); doff = j; }
      else { j -= 3*NWt;
        if (j < NWt){ src=wo; dst=wob; soff=j; doff=j; }
        else { j -= NWt;
          if (j < NX){ src=wup; dst=wupb; soff=j; doff=j; }
          else { j -= NX; src=wdn; dst=wdnb; soff=j; doff=j; }
        }
      }
    }
    const float4 v = *(const float4*)(src + soff);
    ushort4 o;
    o.x = f2bs(v.x); o.y = f2bs(v.y); o.z = f2bs(v.z); o.w = f2bs(v.w);
    *(ushort4*)(dst + doff) = o;
  }
}

// ---- small conversions: bias concat, lb^T tiles ([N][64], cols 16..63 zero), la^T ----
__global__ __launch_bounds__(256) void convert_small(
  const float* __restrict__ bq, const float* __restrict__ bk, const float* __restrict__ bv,
  const float* __restrict__ lbq, const float* __restrict__ lbk, const float* __restrict__ lbv,
  const float* __restrict__ lbo, const float* __restrict__ lbup, const float* __restrict__ lbdn,
  const float* __restrict__ laq, const float* __restrict__ lak, const float* __restrict__ lav,
  const float* __restrict__ lao, const float* __restrict__ laup, const float* __restrict__ ladn,
  float* __restrict__ biascat, u16* __restrict__ lbtqkv, u16* __restrict__ lbto,
  u16* __restrict__ lbtup, u16* __restrict__ lbtdn,
  u16* __restrict__ latqkv, u16* __restrict__ lato,
  u16* __restrict__ latup, u16* __restrict__ latdn)
{
  long i = (long)blockIdx.x*256 + threadIdx.x;
  if (i < 3072){ int p=(int)(i>>10); biascat[i] = (p==0?bq:(p==1?bk:bv))[i&1023]; return; }
  i -= 3072;
  if (i < 49152){ int k=(int)(i/3072), n=(int)(i%3072); int p=n>>10;
    const float* l = p==0?lbq:(p==1?lbk:lbv);
    u16* d = lbtqkv + (long)n*64 + k;
    d[0] = f2bs(l[k*1024 + (n&1023)]); d[16]=0; d[32]=0; d[48]=0; return; }
  i -= 49152;
  if (i < 16384){ int k=(int)(i>>10), n=(int)(i&1023);
    u16* d = lbto + (long)n*64 + k;
    d[0] = f2bs(lbo[k*1024+n]); d[16]=0; d[32]=0; d[48]=0; return; }
  i -= 16384;
  if (i < 65536){ int k=(int)(i>>12), n=(int)(i&4095);
    u16* d = lbtup + (long)n*64 + k;
    d[0] = f2bs(lbup[k*4096+n]); d[16]=0; d[32]=0; d[48]=0; return; }
  i -= 65536;
  if (i < 16384){ int k=(int)(i>>10), n=(int)(i&1023);
    u16* d = lbtdn + (long)n*64 + k;
    d[0] = f2bs(lbdn[k*1024+n]); d[16]=0; d[32]=0; d[48]=0; return; }
  i -= 16384;
  if (i < 49152){ int r=(int)(i>>10), k=(int)(i&1023);
    const float* l = r<16 ? laq : (r<32 ? lak : lav);
    latqkv[i] = f2bs(l[k*16 + (r&15)]); return; }
  i -= 49152;
  if (i < 16384){ int r=(int)(i>>10), k=(int)(i&1023);
    lato[i] = f2bs(lao[k*16+r]); return; }
  i -= 16384;
  if (i < 16384){ int r=(int)(i>>10), k=(int)(i&1023);
    latup[i] = f2bs(laup[k*16+r]); return; }
  i -= 16384;
  if (i < 65536){ int r=(int)(i>>12), k=(int)(i&4095);
    latdn[i] = f2bs(ladn[k*16+r]); }
}

// ---- V transpose ----
__global__ __launch_bounds__(256) void transpose_v(const u16* __restrict__ qkv, u16* __restrict__ vt){
  const int st = blockIdx.x;     // s tile (0..7)
  const int z = blockIdx.y;      // b*16+h
  const int b = z >> 4, h = z & 15;
  __shared__ u16 tile[64][68];
  const int t = threadIdx.x;
  const int q16 = t & 15, g16 = t >> 4;
  const u16* src = qkv + ((long)(b*512 + st*64))*3072 + 2048 + h*64;
  #pragma unroll
  for (int i=0;i<4;i++){
    int s_l = i*16 + g16;
    const u16* pp = src + (long)s_l*3072 + q16*4;
    #pragma unroll
    for (int jj=0;jj<4;jj++) tile[s_l][q16*4+jj] = pp[jj];
  }
  __syncthreads();
  u16* dst = vt + (long)z*64*512 + st*64;
  #pragma unroll
  for (int i=0;i<4;i++){
    int d_l = i*16 + g16;
    int s_l = q16*4;
    unsigned long long v = (unsigned long long)tile[s_l][d_l]
      | ((unsigned long long)tile[s_l+1][d_l] << 16)
      | ((unsigned long long)tile[s_l+2][d_l] << 32)
      | ((unsigned long long)tile[s_l+3][d_l] << 48);
    *(unsigned long long*)(dst + (long)d_l*512 + s_l) = v;
  }
}

// ---- LayerNorm over rows of 1024 fp32; optional fp32 + bf16 outputs ----
__global__ __launch_bounds__(256) void ln_k(
    const float* __restrict__ in, float* __restrict__ outf, u16* __restrict__ outb,
    const float* __restrict__ gam, const float* __restrict__ bet)
{
  const long row = blockIdx.x;
  const float4 v = ((const float4*)(in + row*1024))[threadIdx.x];
  float s = v.x+v.y+v.z+v.w;
  float q = v.x*v.x + v.y*v.y + v.z*v.z + v.w*v.w;
  const int lane = threadIdx.x & 63, w = threadIdx.x >> 6;
  __shared__ float rs[4], rq[4];
  #pragma unroll
  for (int o=32;o;o>>=1){ s += __shfl_down(s,o); q += __shfl_down(q,o); }
  if (!lane){ rs[w]=s; rq[w]=q; }
  __syncthreads();
  const float S = rs[0]+rs[1]+rs[2]+rs[3];
  const float Q = rq[0]+rq[1]+rq[2]+rq[3];
  const float mu = S*(1.f/1024.f);
  const float var = Q*(1.f/1024.f) - mu*mu;
  const float rstd = rsqrtf(var + 1e-5f);
  const float4 g = ((const float4*)gam)[threadIdx.x];
  const float4 b = ((const float4*)bet)[threadIdx.x];
  float4 o;
  o.x = (v.x-mu)*rstd*g.x + b.x;
  o.y = (v.y-mu)*rstd*g.y + b.y;
  o.z = (v.z-mu)*rstd*g.z + b.z;
  o.w = (v.w-mu)*rstd*g.w + b.w;
  if (outf) ((float4*)(outf + row*1024))[threadIdx.x] = o;
  if (outb){
    uint2 u;
    u.x = (unsigned)f2bs(o.x) | ((unsigned)f2bs(o.y) << 16);
    u.y = (unsigned)f2bs(o.z) | ((unsigned)f2bs(o.w) << 16);
    ((uint2*)(outb + row*1024))[threadIdx.x] = u;
  }
}

extern "C" void kernel_launch(void* const* d_in, const int* in_sizes, int n_in,
                              void* d_out, int out_size, void* d_ws, size_t ws_size,
                              hipStream_t stream) {
  const float* x      = (const float*)d_in[0];
  const float* mask   = (const float*)d_in[1];
  const float* w_q    = (const float*)d_in[2];
  const float* b_q    = (const float*)d_in[3];
  const float* la_q   = (const float*)d_in[4];
  const float* lb_q   = (const float*)d_in[5];
  const float* w_k    = (const float*)d_in[6];
  const float* b_k    = (const float*)d_in[7];
  const float* la_k   = (const float*)d_in[8];
  const float* lb_k   = (const float*)d_in[9];
  const float* w_v    = (const float*)d_in[10];
  const float* b_v    = (const float*)d_in[11];
  const float* la_v   = (const float*)d_in[12];
  const float* lb_v   = (const float*)d_in[13];
  const float* w_o    = (const float*)d_in[14];
  const float* b_o    = (const float*)d_in[15];
  const float* la_o   = (const float*)d_in[16];
  const float* lb_o   = (const float*)d_in[17];
  const float* nw1    = (const float*)d_in[18];
  const float* nb1    = (const float*)d_in[19];
  const float* w_up   = (const float*)d_in[20];
  const float* b_up   = (const float*)d_in[21];
  const float* la_up  = (const float*)d_in[22];
  const float* lb_up  = (const float*)d_in[23];
  const float* w_dn   = (const float*)d_in[24];
  const float* b_dn   = (const float*)d_in[25];
  const float* la_dn  = (const float*)d_in[26];
  const float* lb_dn  = (const float*)d_in[27];
  const float* nw2    = (const float*)d_in[28];
  const float* nb2    = (const float*)d_in[29];
  float* out = (float*)d_out;

  char* ws = (char*)d_ws;
  size_t used = 0;
  auto alloc = [&](size_t bytes) -> char* {
    char* p = ws + used;
    used += (bytes + 255) & ~(size_t)255;
    return p;
  };
  u16*   xb      = (u16*)  alloc(4194304*2);
  u16*   wqkv    = (u16*)  alloc(3145728*2);
  u16*   wob     = (u16*)  alloc(1048576*2);
  u16*   wupb    = (u16*)  alloc(4194304*2);
  u16*   wdnb    = (u16*)  alloc(4194304*2);
  float* biascat = (float*)alloc(3072*4);
  u16*   lbtqkv  = (u16*)  alloc((size_t)3072*64*2);
  u16*   lbto    = (u16*)  alloc((size_t)1024*64*2);
  u16*   lbtup   = (u16*)  alloc((size_t)4096*64*2);
  u16*   lbtdn   = (u16*)  alloc((size_t)1024*64*2);
  u16*   latqkv  = (u16*)  alloc(48*1024*2);
  u16*   lato    = (u16*)  alloc(16*1024*2);
  u16*   latup   = (u16*)  alloc(16*1024*2);
  u16*   latdn   = (u16*)  alloc(16*4096*2);
  u16*   t_all   = (u16*)  alloc((size_t)4096*192*2);
  u16*   t_o     = (u16*)  alloc((size_t)4096*64*2);
  u16*   t_up    = (u16*)  alloc((size_t)4096*64*2);
  u16*   t_dn    = (u16*)  alloc((size_t)4096*64*2);
  u16*   qkv     = (u16*)  alloc((size_t)4096*3072*2);
  u16*   vt      = (u16*)  alloc((size_t)128*64*512*2);
  u16*   attn_o  = (u16*)  alloc(4194304*2);
  float* o_final = (float*)alloc((size_t)4194304*4);
  float* x_med   = (float*)alloc((size_t)4194304*4);
  u16*   x_med_b = (u16*)  alloc(4194304*2);
  u16*   fn      = (u16*)  alloc((size_t)4096*4096*2);
  if (used > ws_size) return;  // workspace too small -> clean validation failure

  // 1. convert
  convert_bulk<<<2048, 256, 0, stream>>>(x, w_q, w_k, w_v, w_o, w_up, w_dn,
                                         xb, wqkv, wob, wupb, wdnb);
  convert_small<<<1164, 256, 0, stream>>>(b_q, b_k, b_v, lb_q, lb_k, lb_v,
                                          lb_o, lb_up, lb_dn,
                                          la_q, la_k, la_v, la_o, la_up, la_dn,
                                          biascat, lbtqkv, lbto, lbtup, lbtdn,
                                          latqkv, lato, latup, latdn);
  // 2. LoRA stage-1 q,k,v fused (A = xb bf16, shared A-read)
  lora_mfma<3><<<256, 64, 0, stream>>>(xb, 1024, latqkv, t_all, 192);
  // 3. fused QKV GEMM -> qkv [4096, 3072] bf16  (256x256, 8 waves)
  gemm_bt<256,256,128,64,EP_BF16,true,true><<<dim3(12,16,1), 512, 0, stream>>>(
      xb, 1024, wqkv, 1024, 1024, qkv, nullptr, 3072,
      biascat, t_all, 192, lbtqkv, nullptr);
  // 4. V transpose -> vt [128][64][512]
  transpose_v<<<dim3(8,128), 256, 0, stream>>>(qkv, vt);
  // 5. fused flash attention -> attn_o bf16 [4096][1024]
  flash_attn<<<dim3(4,128), 256, 0, stream>>>(qkv, vt, mask, attn_o);
  // 6. LoRA stage-1 for O
  lora_mfma<1><<<256, 64, 0, stream>>>(attn_o, 1024, lato, t_o, 64);
  // 7. O projection + bias + lora + residual(x) -> o_final fp32  (256x256)
  gemm_bt<256,256,128,64,EP_F32RES,true,true><<<dim3(4,16,1), 512, 0, stream>>>(
      attn_o, 1024, wob, 1024, 1024, nullptr, o_final, 1024,
      b_o, t_o, 64, lbto, x);
  // 8. LN1 -> x_med fp32 + bf16
  ln_k<<<4096, 256, 0, stream>>>(o_final, x_med, x_med_b, nw1, nb1);
  // 9. LoRA stage-1 for up (A = x_med_b bf16)
  lora_mfma<1><<<256, 64, 0, stream>>>(x_med_b, 1024, latup, t_up, 64);
  // 10. up GEMM + bias + lora + GELU -> fn bf16 [4096,4096]  (256x256)
  gemm_bt<256,256,128,64,EP_GELU,true,true><<<dim3(16,16,1), 512, 0, stream>>>(
      x_med_b, 1024, wupb, 1024, 1024, fn, nullptr, 4096,
      b_up, t_up, 64, lbtup, nullptr);
  // 11. LoRA stage-1 for down (A = fn bf16, K=4096)
  lora_mfma<1><<<256, 64, 0, stream>>>(fn, 4096, latdn, t_dn, 64);
  // 12. down GEMM + bias + lora + residual(x_med) -> d_out fp32  (256x256)
  gemm_bt<256,256,128,64,EP_F32RES,true,true><<<dim3(4,16,1), 512, 0, stream>>>(
      fn, 4096, wdnb, 4096, 4096, nullptr, out, 1024,
      b_dn, t_dn, 64, lbtdn, x_med);
  // 13. LN2 in place on d_out
  ln_k<<<4096, 256, 0, stream>>>(out, out, nullptr, nw2, nb2);
}

// Round 12
// 283.954 us; speedup vs baseline: 1.3313x; 1.3313x over previous
//
#include <hip/hip_runtime.h>
#include <math.h>

typedef unsigned short u16;
typedef __attribute__((ext_vector_type(8))) short short8;
typedef __attribute__((ext_vector_type(4))) float floatx4;

#define DEV __device__ __forceinline__

DEV u16 f2bs(float f){ union{float f; unsigned u;} v; v.f=f; unsigned r = v.u + 0x7fffu + ((v.u>>16)&1u); return (u16)(r>>16); }
DEV float bs2f(u16 u){ union{float f; unsigned u;} v; v.u = ((unsigned)u)<<16; return v.f; }

// tanh-form GELU (max |delta| vs exact-erf gelu ~3e-4; bf16-safe).
DEV float gelu_f(float x){
  float u2 = 2.f * x * (0.7978845608028654f + 0.03567740813636141f*x*x);
  float e = __expf(u2);
  float th = 1.f - 2.f/(e + 1.f);
  return 0.5f*x*(1.f + th);
}

#define GLL16(G,L) __builtin_amdgcn_global_load_lds((__attribute__((address_space(1))) const void*)(G), (__attribute__((address_space(3))) void*)(L), 16, 0, 0)

enum { EP_BF16=0, EP_F32RES=3, EP_GELU=4 };

// XCD-chunked bijective block swizzle (m204) + group-major (G rows) ordering.
DEV void swizzle_bid(int orig, int gx, int gy, int& bx, int& by){
  const int nwg = gx*gy;
  const int q = nwg >> 3, r = nwg & 7;
  const int xcd = orig & 7, idx = orig >> 3;
  const int logical = (xcd < r) ? xcd*(q+1) + idx : r*(q+1) + (xcd-r)*q + idx;
  const int G = 8;
  const int per = G*gx;
  const int gid = logical / per;
  const int rem = logical - gid*per;
  const int by0 = gid*G;
  const int rows = min(G, gy - by0);
  by = by0 + rem % rows;
  bx = rem / rows;
}

// C[m][n] = sum_k A[m][k]*B[n][k]  (B^T layout), bf16 in, fp32 acc.
// Phase-distributed K-loop: per K-tile, 4 phases; phase q = {issue next-tile
// half-stage (<=2 GLL) | ds_read quadrant frags (ks=q>>1, mh=q&1) | MFMA}.
// One counted vmcnt(2)+barrier at tile start (next-tile's phase-0 loads in
// flight), one barrier at tile end. BK=64 [rows][64] XOR-swizzled LDS
// (0 conflicts, R9-verified). Per-wave loads: nA,nB <= 4 each.
template<int BM,int BN,int WM,int WN,int MODE,bool LORA,bool SWZ>
__global__ __launch_bounds__((BM/WM)*(BN/WN)*64) void gemm_bt(
    const u16* __restrict__ A, int lda,
    const u16* __restrict__ B, int ldb,
    int K,
    u16* __restrict__ obf, float* __restrict__ of32, int ldc,
    const float* __restrict__ bias,
    const u16* __restrict__ tA, int tlda,   // [M][tlda], 64-wide slices, cols 16..63 zero
    const u16* __restrict__ lbB,            // [N][64], cols 16..63 zero
    const float* __restrict__ resid)
{
  constexpr int NWM = BM/WM, NWN = BN/WN, NW = NWM*NWN;
  constexpr int FM = WM/16, FN = WN/16;
  constexpr int FMH = FM/2;
  constexpr int TILE = (BM+BN)*64;           // u16 elements per buffer
  constexpr int nA = (BM/8)/NW, nB = (BN/8)/NW;  // GLL per wave per tile per operand
  static_assert(NW==4 || NW==8, "4 or 8 waves");
  static_assert(nA>=1 && nA<=4 && nB>=1 && nB<=4, "phase distribution");
  static_assert((FM%2)==0, "FM even for mh split");
  __shared__ u16 ab[2*TILE];

  const int tid = threadIdx.x;
  const int lane = tid & 63, wave = tid >> 6;
  const int wr = wave / NWN, wc = wave % NWN;
  const int row16 = lane & 15, kgrp = lane >> 4;
  int bx = blockIdx.x, by = blockIdx.y;
  if constexpr (SWZ)
    swizzle_bid(blockIdx.y*gridDim.x + blockIdx.x, gridDim.x, gridDim.y, bx, by);
  const int bm0 = by * BM, bn0 = bx * BN;

  const u16* Ab = A + (long)bm0*lda;
  const u16* Bb = B + (long)bn0*ldb;
  const int tsel = (LORA && tlda==192) ? ((bn0>>10)*64) : 0;
  const int srow = lane >> 3;
  const int gcol = ((lane&7) ^ srow) * 8;

  const int nKT = K >> 6;
  const int nIT = nKT + (LORA ? 1 : 0);

  // issue phase-p loads of tile kt into buffer buf
  auto stage_ph = [&](int kt, int buf, int p){
    const u16 *Ak, *Bk; long la_, lb_;
    if (!LORA || kt < nKT){ Ak = Ab + kt*64; la_ = lda; Bk = Bb + kt*64; lb_ = ldb; }
    else { Ak = tA + (long)bm0*tlda + tsel; la_ = tlda; Bk = lbB + (long)bn0*64; lb_ = 64; }
    char* l = (char*)(ab + buf*TILE);
    if (p < nA){
      int g = p*NW + wave;
      GLL16(Ak + (long)(g*8 + srow)*la_ + gcol, l + g*1024);
    }
    if (p < nB){
      int g = p*NW + wave;
      GLL16(Bk + (long)(g*8 + srow)*lb_ + gcol, l + BM*128 + g*1024);
    }
  };

  floatx4 acc[FM][FN];
  #pragma unroll
  for (int i=0;i<FM;i++)
    #pragma unroll
    for (int j=0;j<FN;j++)
      acc[i][j] = (floatx4){0.f,0.f,0.f,0.f};

  #pragma unroll
  for (int p=0;p<4;p++) stage_ph(0, 0, p);   // prologue: tile 0 fully issued

  int cur = 0;
  for (int kt=0; kt<nIT; ++kt){
    const bool hasNext = (kt+1 < nIT);
    // phase 0 staging BEFORE the wait -> next tile's first loads stay in flight
    if (hasNext) stage_ph(kt+1, cur^1, 0);
    if (hasNext) asm volatile("s_waitcnt vmcnt(2)" ::: "memory");
    else         asm volatile("s_waitcnt vmcnt(0)" ::: "memory");
    __builtin_amdgcn_s_barrier();

    const char* lds = (const char*)(ab + cur*TILE);
    short8 bfr[FN];
    #pragma unroll
    for (int q=0; q<4; ++q){
      if (q>0 && hasNext) stage_ph(kt+1, cur^1, q);
      const int ks = q>>1, mh = q&1;
      if (mh == 0){
        #pragma unroll
        for (int ni=0;ni<FN;ni++){
          int r_ = wc*WN + ni*16 + row16;
          bfr[ni] = *(const short8*)(lds + BM*128 + r_*128 + (((ks*4 + kgrp) ^ (r_&7))<<4));
        }
      }
      short8 af[FMH];
      #pragma unroll
      for (int i=0;i<FMH;i++){
        int r_ = wr*WM + (mh*FMH + i)*16 + row16;
        af[i] = *(const short8*)(lds + r_*128 + (((ks*4 + kgrp) ^ (r_&7))<<4));
      }
      __builtin_amdgcn_s_setprio(1);
      #pragma unroll
      for (int i=0;i<FMH;i++)
        #pragma unroll
        for (int ni=0;ni<FN;ni++)
          acc[mh*FMH + i][ni] = __builtin_amdgcn_mfma_f32_16x16x32_bf16(af[i], bfr[ni], acc[mh*FMH + i][ni], 0, 0, 0);
      __builtin_amdgcn_s_setprio(0);
    }

    asm volatile("s_waitcnt lgkmcnt(0)" ::: "memory");
    __builtin_amdgcn_sched_barrier(0);
    __builtin_amdgcn_s_barrier();        // all waves done reading buf[cur]
    cur ^= 1;
  }

  #pragma unroll
  for (int mi=0;mi<FM;mi++){
    #pragma unroll
    for (int r=0;r<4;r++){
      const int ml = wr*WM + mi*16 + kgrp*4 + r;
      const long mg = bm0 + ml;
      #pragma unroll
      for (int ni=0;ni<FN;ni++){
        const int nl = wc*WN + ni*16 + row16;
        const int ng = bn0 + nl;
        float v = acc[mi][ni][r] + bias[ng];
        if constexpr (MODE==EP_F32RES){
          v += resid[mg*ldc + ng];
          of32[mg*ldc + ng] = v;
        } else if constexpr (MODE==EP_GELU){
          obf[mg*ldc + ng] = f2bs(gelu_f(v));
        } else {
          obf[mg*ldc + ng] = f2bs(v);
        }
      }
    }
  }
}

// ---- LoRA stage-1 via MFMA: t[m][r] = sum_k A[m][k]*la[k][r] ----
template<int NT>
__global__ __launch_bounds__(64) void lora_mfma(
    const u16* __restrict__ A, const int K,
    const u16* __restrict__ lat,
    u16* __restrict__ t, int tld)
{
  const int lane = threadIdx.x & 63;
  const int c = lane & 15, kg = lane >> 4;
  const int m0 = blockIdx.x * 16;
  const u16* Arow = A + (long)(m0 + c)*K + kg*8;
  const u16* Brow = lat + (long)c*K + kg*8;
  floatx4 acc[NT];
  #pragma unroll
  for (int tj=0;tj<NT;tj++) acc[tj] = (floatx4){0.f,0.f,0.f,0.f};
  const int nKS = K >> 5;
  #pragma unroll 4
  for (int ks=0; ks<nKS; ++ks){
    short8 a = *(const short8*)(Arow + ks*32);
    #pragma unroll
    for (int tj=0; tj<NT; ++tj){
      short8 b = *(const short8*)(Brow + (long)tj*16*K + ks*32);
      acc[tj] = __builtin_amdgcn_mfma_f32_16x16x32_bf16(a, b, acc[tj], 0, 0, 0);
    }
  }
  #pragma unroll
  for (int tj=0; tj<NT; ++tj)
    #pragma unroll
    for (int r=0;r<4;r++){
      u16* dst = t + (long)(m0 + kg*4 + r)*tld + tj*64;
      dst[c] = f2bs(acc[tj][r]);
      dst[16+c] = 0; dst[32+c] = 0; dst[48+c] = 0;
    }
}

// ---- fused flash attention: per (q-tile 128, head) block, 4 waves ----
__global__ __launch_bounds__(256) void flash_attn(
    const u16* __restrict__ qkv,   // [4096][3072]
    const u16* __restrict__ vt,    // [128][64][512]
    const float* __restrict__ mask,// [8][512]
    u16* __restrict__ attn_o)      // [4096][1024]
{
  __shared__ u16 sm[33792]; // Q[128][64] | K dbuf 2x4096 | V dbuf 2x4096 | P 4x[32][72]
  u16* Qs = sm;
  u16* Ps = sm + 24576;

  const int tid = threadIdx.x, lane = tid & 63, wave = tid >> 6;
  const int c = lane & 15, kg = lane >> 4;
  const int qt = blockIdx.x;        // 0..3
  const int z  = blockIdx.y;        // b*16+h
  const int b = z >> 4, h = z & 15;
  const int q0 = qt * 128;
  const int srow = lane >> 3;
  const int scol = ((lane&7) ^ srow) * 8;

  const u16* kbase = qkv + ((long)(b*512))*3072 + 1024 + h*64;
  const u16* vbase = vt + (long)z*64*512;

  auto stage_kv = [&](int kv, int buf){
    char* Kd = (char*)(sm + 8192  + buf*4096);
    char* Vd = (char*)(sm + 16384 + buf*4096);
    #pragma unroll
    for (int i=0;i<2;i++){
      int rb = i*32 + wave*8;
      GLL16(kbase + (long)(kv*64 + rb + srow)*3072 + scol, Kd + rb*128);
      GLL16(vbase + (long)(rb + srow)*512 + kv*64 + scol, Vd + rb*128);
    }
  };

  {
    const u16* src = qkv + ((long)(b*512 + q0))*3072 + h*64;
    #pragma unroll
    for (int i=0;i<4;i++){
      int rb = i*32 + wave*8;
      GLL16(src + (long)(rb + srow)*3072 + scol, (char*)Qs + rb*128);
    }
  }
  stage_kv(0, 0);
  __syncthreads();

  auto ld_swz = [&](const u16* t, int row, int koff8) -> short8 {
    return *(const short8*)((const char*)t + row*128 + ((koff8 ^ (row&7))<<4));
  };

  short8 af[2][2];
  #pragma unroll
  for (int mi=0;mi<2;mi++)
    #pragma unroll
    for (int ks=0;ks<2;ks++)
      af[mi][ks] = ld_swz(Qs, wave*32 + mi*16 + c, ks*4 + kg);

  floatx4 o_acc[2][4];
  float m_run[2][4], l_run[2][4];
  #pragma unroll
  for (int mi=0;mi<2;mi++){
    #pragma unroll
    for (int dj=0;dj<4;dj++) o_acc[mi][dj] = (floatx4){0.f,0.f,0.f,0.f};
    #pragma unroll
    for (int r=0;r<4;r++){ m_run[mi][r] = -3.0e38f; l_run[mi][r] = 0.f; }
  }

  int cur = 0;
  for (int kv=0; kv<8; ++kv){
    if (kv+1 < 8) stage_kv(kv+1, cur^1);   // prefetch next K/V
    const u16* Ks = sm + 8192  + cur*4096;
    const u16* Vs = sm + 16384 + cur*4096;

    floatx4 s_acc[2][4];
    #pragma unroll
    for (int mi=0;mi<2;mi++)
      #pragma unroll
      for (int ni=0;ni<4;ni++)
        s_acc[mi][ni] = (floatx4){0.f,0.f,0.f,0.f};
    #pragma unroll
    for (int ks=0;ks<2;ks++){
      short8 bf[4];
      #pragma unroll
      for (int ni=0;ni<4;ni++)
        bf[ni] = ld_swz(Ks, ni*16 + c, ks*4 + kg);
      #pragma unroll
      for (int mi=0;mi<2;mi++)
        #pragma unroll
        for (int ni=0;ni<4;ni++)
          s_acc[mi][ni] = __builtin_amdgcn_mfma_f32_16x16x32_bf16(af[mi][ks], bf[ni], s_acc[mi][ni], 0, 0, 0);
    }

    float mv[4];
    #pragma unroll
    for (int ni=0;ni<4;ni++) mv[ni] = mask[b*512 + kv*64 + ni*16 + c];

    #pragma unroll
    for (int mi=0;mi<2;mi++){
      #pragma unroll
      for (int r=0;r<4;r++){
        float s0 = s_acc[mi][0][r]*0.125f + mv[0];
        float s1 = s_acc[mi][1][r]*0.125f + mv[1];
        float s2 = s_acc[mi][2][r]*0.125f + mv[2];
        float s3 = s_acc[mi][3][r]*0.125f + mv[3];
        float tmax = fmaxf(fmaxf(s0,s1), fmaxf(s2,s3));
        #pragma unroll
        for (int o=1;o<16;o<<=1) tmax = fmaxf(tmax, __shfl_xor(tmax, o));
        const float mnew = fmaxf(m_run[mi][r], tmax);
        const float p0 = __expf(s0 - mnew), p1 = __expf(s1 - mnew);
        const float p2 = __expf(s2 - mnew), p3 = __expf(s3 - mnew);
        float psum = p0+p1+p2+p3;
        #pragma unroll
        for (int o=1;o<16;o<<=1) psum += __shfl_xor(psum, o);
        const float alpha = __expf(m_run[mi][r] - mnew);
        l_run[mi][r] = l_run[mi][r]*alpha + psum;
        m_run[mi][r] = mnew;
        #pragma unroll
        for (int dj=0;dj<4;dj++) o_acc[mi][dj][r] *= alpha;
        const int rl = mi*16 + kg*4 + r;
        u16* pw = Ps + wave*2304 + rl*72;
        pw[c]      = f2bs(p0);
        pw[16 + c] = f2bs(p1);
        pw[32 + c] = f2bs(p2);
        pw[48 + c] = f2bs(p3);
      }
    }
    __syncthreads();

    #pragma unroll
    for (int ks=0;ks<2;ks++){
      short8 pa[2], vb[4];
      #pragma unroll
      for (int mi=0;mi<2;mi++)
        pa[mi] = *(const short8*)&Ps[wave*2304 + (mi*16 + c)*72 + ks*32 + kg*8];
      #pragma unroll
      for (int dj=0;dj<4;dj++)
        vb[dj] = ld_swz(Vs, dj*16 + c, ks*4 + kg);
      __builtin_amdgcn_s_setprio(1);
      #pragma unroll
      for (int mi=0;mi<2;mi++)
        #pragma unroll
        for (int dj=0;dj<4;dj++)
          o_acc[mi][dj] = __builtin_amdgcn_mfma_f32_16x16x32_bf16(pa[mi], vb[dj], o_acc[mi][dj], 0, 0, 0);
      __builtin_amdgcn_s_setprio(0);
    }
    __syncthreads();
    cur ^= 1;
  }

  #pragma unroll
  for (int mi=0;mi<2;mi++){
    #pragma unroll
    for (int r=0;r<4;r++){
      const float inv = 1.f / l_run[mi][r];
      const int s_g = q0 + wave*32 + mi*16 + kg*4 + r;
      u16* dst = attn_o + (long)(b*512 + s_g)*1024 + h*64;
      #pragma unroll
      for (int dj=0;dj<4;dj++)
        dst[dj*16 + c] = f2bs(o_acc[mi][dj][r]*inv);
    }
  }
}

// ---- bulk fp32 -> bf16 conversion, float4 wide ----
__global__ __launch_bounds__(256) void convert_bulk(
  const float* __restrict__ x,
  const float* __restrict__ wq, const float* __restrict__ wk, const float* __restrict__ wv,
  const float* __restrict__ wo, const float* __restrict__ wup, const float* __restrict__ wdn,
  u16* __restrict__ xb, u16* __restrict__ wqkv, u16* __restrict__ wob,
  u16* __restrict__ wupb, u16* __restrict__ wdnb)
{
  const long NX = 4194304, NWt = 1048576;
  const long T4 = (NX + 3*NWt + NWt + NX + NX) >> 2;
  for (long i4 = (long)blockIdx.x*256 + threadIdx.x; i4 < T4; i4 += (long)gridDim.x*256){
    long j = i4 << 2;
    const float* src; u16* dst; long soff, doff;
    if (j < NX){ src=x; dst=xb; soff=j; doff=j; }
    else { j -= NX;
      if (j < 3*NWt){ int p=(int)(j>>20); src = p==0?wq:(p==1?wk:wv); dst=wqkv; soff = j & (NWt-1); doff = j; }
      else { j -= 3*NWt;
        if (j < NWt){ src=wo; dst=wob; soff=j; doff=j; }
        else { j -= NWt;
          if (j < NX){ src=wup; dst=wupb; soff=j; doff=j; }
          else { j -= NX; src=wdn; dst=wdnb; soff=j; doff=j; }
        }
      }
    }
    const float4 v = *(const float4*)(src + soff);
    ushort4 o;
    o.x = f2bs(v.x); o.y = f2bs(v.y); o.z = f2bs(v.z); o.w = f2bs(v.w);
    *(ushort4*)(dst + doff) = o;
  }
}

// ---- small conversions: bias concat, lb^T tiles ([N][64], cols 16..63 zero), la^T ----
__global__ __launch_bounds__(256) void convert_small(
  const float* __restrict__ bq, const float* __restrict__ bk, const float* __restrict__ bv,
  const float* __restrict__ lbq, const float* __restrict__ lbk, const float* __restrict__ lbv,
  const float* __restrict__ lbo, const float* __restrict__ lbup, const float* __restrict__ lbdn,
  const float* __restrict__ laq, const float* __restrict__ lak, const float* __restrict__ lav,
  const float* __restrict__ lao, const float* __restrict__ laup, const float* __restrict__ ladn,
  float* __restrict__ biascat, u16* __restrict__ lbtqkv, u16* __restrict__ lbto,
  u16* __restrict__ lbtup, u16* __restrict__ lbtdn,
  u16* __restrict__ latqkv, u16* __restrict__ lato,
  u16* __restrict__ latup, u16* __restrict__ latdn)
{
  long i = (long)blockIdx.x*256 + threadIdx.x;
  if (i < 3072){ int p=(int)(i>>10); biascat[i] = (p==0?bq:(p==1?bk:bv))[i&1023]; return; }
  i -= 3072;
  if (i < 49152){ int k=(int)(i/3072), n=(int)(i%3072); int p=n>>10;
    const float* l = p==0?lbq:(p==1?lbk:lbv);
    u16* d = lbtqkv + (long)n*64 + k;
    d[0] = f2bs(l[k*1024 + (n&1023)]); d[16]=0; d[32]=0; d[48]=0; return; }
  i -= 49152;
  if (i < 16384){ int k=(int)(i>>10), n=(int)(i&1023);
    u16* d = lbto + (long)n*64 + k;
    d[0] = f2bs(lbo[k*1024+n]); d[16]=0; d[32]=0; d[48]=0; return; }
  i -= 16384;
  if (i < 65536){ int k=(int)(i>>12), n=(int)(i&4095);
    u16* d = lbtup + (long)n*64 + k;
    d[0] = f2bs(lbup[k*4096+n]); d[16]=0; d[32]=0; d[48]=0; return; }
  i -= 65536;
  if (i < 16384){ int k=(int)(i>>10), n=(int)(i&1023);
    u16* d = lbtdn + (long)n*64 + k;
    d[0] = f2bs(lbdn[k*1024+n]); d[16]=0; d[32]=0; d[48]=0; return; }
  i -= 16384;
  if (i < 49152){ int r=(int)(i>>10), k=(int)(i&1023);
    const float* l = r<16 ? laq : (r<32 ? lak : lav);
    latqkv[i] = f2bs(l[k*16 + (r&15)]); return; }
  i -= 49152;
  if (i < 16384){ int r=(int)(i>>10), k=(int)(i&1023);
    lato[i] = f2bs(lao[k*16+r]); return; }
  i -= 16384;
  if (i < 16384){ int r=(int)(i>>10), k=(int)(i&1023);
    latup[i] = f2bs(laup[k*16+r]); return; }
  i -= 16384;
  if (i < 65536){ int r=(int)(i>>12), k=(int)(i&4095);
    latdn[i] = f2bs(ladn[k*16+r]); }
}

// ---- V transpose ----
__global__ __launch_bounds__(256) void transpose_v(const u16* __restrict__ qkv, u16* __restrict__ vt){
  const int st = blockIdx.x;     // s tile (0..7)
  const int z = blockIdx.y;      // b*16+h
  const int b = z >> 4, h = z & 15;
  __shared__ u16 tile[64][68];
  const int t = threadIdx.x;
  const int q16 = t & 15, g16 = t >> 4;
  const u16* src = qkv + ((long)(b*512 + st*64))*3072 + 2048 + h*64;
  #pragma unroll
  for (int i=0;i<4;i++){
    int s_l = i*16 + g16;
    const u16* pp = src + (long)s_l*3072 + q16*4;
    #pragma unroll
    for (int jj=0;jj<4;jj++) tile[s_l][q16*4+jj] = pp[jj];
  }
  __syncthreads();
  u16* dst = vt + (long)z*64*512 + st*64;
  #pragma unroll
  for (int i=0;i<4;i++){
    int d_l = i*16 + g16;
    int s_l = q16*4;
    unsigned long long v = (unsigned long long)tile[s_l][d_l]
      | ((unsigned long long)tile[s_l+1][d_l] << 16)
      | ((unsigned long long)tile[s_l+2][d_l] << 32)
      | ((unsigned long long)tile[s_l+3][d_l] << 48);
    *(unsigned long long*)(dst + (long)d_l*512 + s_l) = v;
  }
}

// ---- LayerNorm over rows of 1024 fp32; optional fp32 + bf16 outputs ----
__global__ __launch_bounds__(256) void ln_k(
    const float* __restrict__ in, float* __restrict__ outf, u16* __restrict__ outb,
    const float* __restrict__ gam, const float* __restrict__ bet)
{
  const long row = blockIdx.x;
  const float4 v = ((const float4*)(in + row*1024))[threadIdx.x];
  float s = v.x+v.y+v.z+v.w;
  float q = v.x*v.x + v.y*v.y + v.z*v.z + v.w*v.w;
  const int lane = threadIdx.x & 63, w = threadIdx.x >> 6;
  __shared__ float rs[4], rq[4];
  #pragma unroll
  for (int o=32;o;o>>=1){ s += __shfl_down(s,o); q += __shfl_down(q,o); }
  if (!lane){ rs[w]=s; rq[w]=q; }
  __syncthreads();
  const float S = rs[0]+rs[1]+rs[2]+rs[3];
  const float Q = rq[0]+rq[1]+rq[2]+rq[3];
  const float mu = S*(1.f/1024.f);
  const float var = Q*(1.f/1024.f) - mu*mu;
  const float rstd = rsqrtf(var + 1e-5f);
  const float4 g = ((const float4*)gam)[threadIdx.x];
  const float4 b = ((const float4*)bet)[threadIdx.x];
  float4 o;
  o.x = (v.x-mu)*rstd*g.x + b.x;
  o.y = (v.y-mu)*rstd*g.y + b.y;
  o.z = (v.z-mu)*rstd*g.z + b.z;
  o.w = (v.w-mu)*rstd*g.w + b.w;
  if (outf) ((float4*)(outf + row*1024))[threadIdx.x] = o;
  if (outb){
    uint2 u;
    u.x = (unsigned)f2bs(o.x) | ((unsigned)f2bs(o.y) << 16);
    u.y = (unsigned)f2bs(o.z) | ((unsigned)f2bs(o.w) << 16);
    ((uint2*)(outb + row*1024))[threadIdx.x] = u;
  }
}

extern "C" void kernel_launch(void* const* d_in, const int* in_sizes, int n_in,
                              void* d_out, int out_size, void* d_ws, size_t ws_size,
                              hipStream_t stream) {
  const float* x      = (const float*)d_in[0];
  const float* mask   = (const float*)d_in[1];
  const float* w_q    = (const float*)d_in[2];
  const float* b_q    = (const float*)d_in[3];
  const float* la_q   = (const float*)d_in[4];
  const float* lb_q   = (const float*)d_in[5];
  const float* w_k    = (const float*)d_in[6];
  const float* b_k    = (const float*)d_in[7];
  const float* la_k   = (const float*)d_in[8];
  const float* lb_k   = (const float*)d_in[9];
  const float* w_v    = (const float*)d_in[10];
  const float* b_v    = (const float*)d_in[11];
  const float* la_v   = (const float*)d_in[12];
  const float* lb_v   = (const float*)d_in[13];
  const float* w_o    = (const float*)d_in[14];
  const float* b_o    = (const float*)d_in[15];
  const float* la_o   = (const float*)d_in[16];
  const float* lb_o   = (const float*)d_in[17];
  const float* nw1    = (const float*)d_in[18];
  const float* nb1    = (const float*)d_in[19];
  const float* w_up   = (const float*)d_in[20];
  const float* b_up   = (const float*)d_in[21];
  const float* la_up  = (const float*)d_in[22];
  const float* lb_up  = (const float*)d_in[23];
  const float* w_dn   = (const float*)d_in[24];
  const float* b_dn   = (const float*)d_in[25];
  const float* la_dn  = (const float*)d_in[26];
  const float* lb_dn  = (const float*)d_in[27];
  const float* nw2    = (const float*)d_in[28];
  const float* nb2    = (const float*)d_in[29];
  float* out = (float*)d_out;

  char* ws = (char*)d_ws;
  size_t used = 0;
  auto alloc = [&](size_t bytes) -> char* {
    char* p = ws + used;
    used += (bytes + 255) & ~(size_t)255;
    return p;
  };
  u16*   xb      = (u16*)  alloc(4194304*2);
  u16*   wqkv    = (u16*)  alloc(3145728*2);
  u16*   wob     = (u16*)  alloc(1048576*2);
  u16*   wupb    = (u16*)  alloc(4194304*2);
  u16*   wdnb    = (u16*)  alloc(4194304*2);
  float* biascat = (float*)alloc(3072*4);
  u16*   lbtqkv  = (u16*)  alloc((size_t)3072*64*2);
  u16*   lbto    = (u16*)  alloc((size_t)1024*64*2);
  u16*   lbtup   = (u16*)  alloc((size_t)4096*64*2);
  u16*   lbtdn   = (u16*)  alloc((size_t)1024*64*2);
  u16*   latqkv  = (u16*)  alloc(48*1024*2);
  u16*   lato    = (u16*)  alloc(16*1024*2);
  u16*   latup   = (u16*)  alloc(16*1024*2);
  u16*   latdn   = (u16*)  alloc(16*4096*2);
  u16*   t_all   = (u16*)  alloc((size_t)4096*192*2);
  u16*   t_o     = (u16*)  alloc((size_t)4096*64*2);
  u16*   t_up    = (u16*)  alloc((size_t)4096*64*2);
  u16*   t_dn    = (u16*)  alloc((size_t)4096*64*2);
  u16*   qkv     = (u16*)  alloc((size_t)4096*3072*2);
  u16*   vt      = (u16*)  alloc((size_t)128*64*512*2);
  u16*   attn_o  = (u16*)  alloc(4194304*2);
  float* o_final = (float*)alloc((size_t)4194304*4);
  float* x_med   = (float*)alloc((size_t)4194304*4);
  u16*   x_med_b = (u16*)  alloc(4194304*2);
  u16*   fn      = (u16*)  alloc((size_t)4096*4096*2);
  if (used > ws_size) return;  // workspace too small -> clean validation failure

  // 1. convert
  convert_bulk<<<2048, 256, 0, stream>>>(x, w_q, w_k, w_v, w_o, w_up, w_dn,
                                         xb, wqkv, wob, wupb, wdnb);
  convert_small<<<1164, 256, 0, stream>>>(b_q, b_k, b_v, lb_q, lb_k, lb_v,
                                          lb_o, lb_up, lb_dn,
                                          la_q, la_k, la_v, la_o, la_up, la_dn,
                                          biascat, lbtqkv, lbto, lbtup, lbtdn,
                                          latqkv, lato, latup, latdn);
  // 2. LoRA stage-1 q,k,v fused (A = xb bf16, shared A-read)
  lora_mfma<3><<<256, 64, 0, stream>>>(xb, 1024, latqkv, t_all, 192);
  // 3. fused QKV GEMM -> qkv [4096, 3072] bf16  (256x256, 8 waves, 192 blocks)
  gemm_bt<256,256,128,64,EP_BF16,true,true><<<dim3(12,16,1), 512, 0, stream>>>(
      xb, 1024, wqkv, 1024, 1024, qkv, nullptr, 3072,
      biascat, t_all, 192, lbtqkv, nullptr);
  // 4. V transpose -> vt [128][64][512]
  transpose_v<<<dim3(8,128), 256, 0, stream>>>(qkv, vt);
  // 5. fused flash attention -> attn_o bf16 [4096][1024]
  flash_attn<<<dim3(4,128), 256, 0, stream>>>(qkv, vt, mask, attn_o);
  // 6. LoRA stage-1 for O
  lora_mfma<1><<<256, 64, 0, stream>>>(attn_o, 1024, lato, t_o, 64);
  // 7. O projection + bias + lora + residual(x) -> o_final fp32  (64x128, 512 blocks)
  gemm_bt<64,128,32,64,EP_F32RES,true,true><<<dim3(8,64,1), 256, 0, stream>>>(
      attn_o, 1024, wob, 1024, 1024, nullptr, o_final, 1024,
      b_o, t_o, 64, lbto, x);
  // 8. LN1 -> x_med fp32 + bf16
  ln_k<<<4096, 256, 0, stream>>>(o_final, x_med, x_med_b, nw1, nb1);
  // 9. LoRA stage-1 for up (A = x_med_b bf16)
  lora_mfma<1><<<256, 64, 0, stream>>>(x_med_b, 1024, latup, t_up, 64);
  // 10. up GEMM + bias + lora + GELU -> fn bf16 [4096,4096]  (256x256, 256 blocks)
  gemm_bt<256,256,128,64,EP_GELU,true,true><<<dim3(16,16,1), 512, 0, stream>>>(
      x_med_b, 1024, wupb, 1024, 1024, fn, nullptr, 4096,
      b_up, t_up, 64, lbtup, nullptr);
  // 11. LoRA stage-1 for down (A = fn bf16, K=4096)
  lora_mfma<1><<<256, 64, 0, stream>>>(fn, 4096, latdn, t_dn, 64);
  // 12. down GEMM + bias + lora + residual(x_med) -> d_out fp32  (64x128, 512 blocks)
  gemm_bt<64,128,32,64,EP_F32RES,true,true><<<dim3(8,64,1), 256, 0, stream>>>(
      fn, 4096, wdnb, 4096, 4096, nullptr, out, 1024,
      b_dn, t_dn, 64, lbtdn, x_med);
  // 13. LN2 in place on d_out
  ln_k<<<4096, 256, 0, stream>>>(out, out, nullptr, nw2, nb2);
}

// Round 13
// 276.111 us; speedup vs baseline: 1.3691x; 1.0284x over previous
//
#include <hip/hip_runtime.h>
#include <math.h>

typedef unsigned short u16;
typedef __attribute__((ext_vector_type(8))) short short8;
typedef __attribute__((ext_vector_type(4))) float floatx4;

#define DEV __device__ __forceinline__

DEV u16 f2bs(float f){ union{float f; unsigned u;} v; v.f=f; unsigned r = v.u + 0x7fffu + ((v.u>>16)&1u); return (u16)(r>>16); }
DEV float bs2f(u16 u){ union{float f; unsigned u;} v; v.u = ((unsigned)u)<<16; return v.f; }

// tanh-form GELU (max |delta| vs exact-erf gelu ~3e-4; bf16-safe).
DEV float gelu_f(float x){
  float u2 = 2.f * x * (0.7978845608028654f + 0.03567740813636141f*x*x);
  float e = __expf(u2);
  float th = 1.f - 2.f/(e + 1.f);
  return 0.5f*x*(1.f + th);
}

#define GLL16(G,L) __builtin_amdgcn_global_load_lds((__attribute__((address_space(1))) const void*)(G), (__attribute__((address_space(3))) void*)(L), 16, 0, 0)

enum { EP_BF16=0, EP_F32RES=3, EP_GELU=4 };

// XCD-chunked bijective block swizzle (m204) + group-major (G rows) ordering.
DEV void swizzle_bid(int orig, int gx, int gy, int& bx, int& by){
  const int nwg = gx*gy;
  const int q = nwg >> 3, r = nwg & 7;
  const int xcd = orig & 7, idx = orig >> 3;
  const int logical = (xcd < r) ? xcd*(q+1) + idx : r*(q+1) + (xcd-r)*q + idx;
  const int G = 8;
  const int per = G*gx;
  const int gid = logical / per;
  const int rem = logical - gid*per;
  const int by0 = gid*G;
  const int rows = min(G, gy - by0);
  by = by0 + rem % rows;
  bx = rem / rows;
}

// ======================= 256x256 8-phase GEMM (m201 port) =================
// 8 waves (2M x 4N), per-wave C 128x64 with INTERLEAVED ownership:
// rows {wr*64..}+{128+wr*64..}, cols {wc*32..}+{128+wc*32..} -> each quadrant
// (mh,nh) reads exactly one A-half / B-half, giving early slot retirement:
//   A0 last read q1, B0 q2, A1/B1 q3.
// Stage schedule: t.A0 @ (t-2,q2), t.B0 @ (t-2,q3), t.A1+B1 @ (t-1,q0)
// -> 2 half-tiles (vmcnt 4) stay in flight across every tile boundary.
// Per phase: [vmcnt@q0] barrier; ds_read frags; stage; lgkmcnt(0); 16 MFMA.
template<int MODE,bool LORA,bool SWZ>
__global__ __launch_bounds__(512) void gemm8(
    const u16* __restrict__ A, int lda,
    const u16* __restrict__ B, int ldb,
    int K,
    u16* __restrict__ obf, float* __restrict__ of32, int ldc,
    const float* __restrict__ bias,
    const u16* __restrict__ tA, int tlda,   // [M][tlda], 64-wide slices, cols 16..63 zero
    const u16* __restrict__ lbB,            // [N][64], cols 16..63 zero
    const float* __restrict__ resid)
{
  __shared__ u16 sm8[65536];  // 128 KB: 2 bufs x (A 32KB + B 32KB)
  const int tid = threadIdx.x;
  const int lane = tid & 63, wave = tid >> 6;
  const int wr = wave >> 2, wc = wave & 3;
  const int row16 = lane & 15, kgrp = lane >> 4;
  int bx = blockIdx.x, by = blockIdx.y;
  if constexpr (SWZ)
    swizzle_bid(blockIdx.y*gridDim.x + blockIdx.x, gridDim.x, gridDim.y, bx, by);
  const int bm0 = by*256, bn0 = bx*256;
  const u16* Ab = A + (long)bm0*lda;
  const u16* Bb = B + (long)bn0*ldb;
  const int tsel = (LORA && tlda==192) ? ((bn0>>10)*64) : 0;
  const int srow = lane >> 3;
  const int gcol = ((lane&7) ^ srow) * 8;
  const int nKT = K >> 6;
  const int nIT = nKT + (LORA ? 1 : 0);

  // stage one half-tile h of tile kt into buffer buf. h: 0=A0,1=B0,2=A1,3=B1.
  auto stage_half = [&](int kt, int h, int buf){
    const int isB = h & 1, hi = h >> 1;
    const u16* src; long ld;
    if (!LORA || kt < nKT){
      if (isB){ src = Bb + kt*64; ld = ldb; } else { src = Ab + kt*64; ld = lda; }
    } else {
      if (isB){ src = lbB + (long)bn0*64; ld = 64; }
      else    { src = tA + (long)bm0*tlda + tsel; ld = tlda; }
    }
    char* base = (char*)sm8 + buf*65536 + isB*32768 + hi*16384;
    #pragma unroll
    for (int rr=0; rr<2; ++rr){
      int g = wave + rr*8;
      GLL16(src + (long)(hi*128 + g*8 + srow)*ld + gcol, base + g*1024);
    }
  };
  auto ldA = [&](int buf, int mh, int i, int ks)->short8{
    int r_ = mh*128 + wr*64 + i*16 + row16;
    return *(const short8*)((const char*)sm8 + buf*65536 + r_*128 + (((ks*4+kgrp) ^ (r_&7))<<4));
  };
  auto ldB = [&](int buf, int nh, int j, int ks)->short8{
    int r_ = nh*128 + wc*32 + j*16 + row16;
    return *(const short8*)((const char*)sm8 + buf*65536 + 32768 + r_*128 + (((ks*4+kgrp) ^ (r_&7))<<4));
  };

  floatx4 acc[8][4];
  #pragma unroll
  for (int i=0;i<8;i++)
    #pragma unroll
    for (int j=0;j<4;j++)
      acc[i][j] = (floatx4){0.f,0.f,0.f,0.f};

  // prologue: tile0 full, tile1 A0+B0
  stage_half(0,0,0); stage_half(0,1,0); stage_half(0,2,0); stage_half(0,3,0);
  if (nIT>1){ stage_half(1,0,1); stage_half(1,1,1); }

#define MM8(mh,nh) \
  { _Pragma("unroll") \
    for (int i=0;i<4;i++) \
      _Pragma("unroll") \
      for (int j=0;j<2;j++) \
        _Pragma("unroll") \
        for (int ks=0;ks<2;ks++) \
          acc[(mh)*4+i][(nh)*2+j] = __builtin_amdgcn_mfma_f32_16x16x32_bf16(afr[i][ks], bfr[j][ks], acc[(mh)*4+i][(nh)*2+j], 0, 0, 0); }

  int buf = 0;
  for (int t=0; t<nIT; ++t, buf^=1){
    const bool n1 = (t+1 < nIT), n2 = (t+2 < nIT);
    short8 afr[4][2], bfr[2][2];
    // ---- q0: quadrant (mh=0, nh=0); vmcnt gate; stage t+1.A1,B1 ----
    if (n1) asm volatile("s_waitcnt vmcnt(4)" ::: "memory");
    else    asm volatile("s_waitcnt vmcnt(0)" ::: "memory");
    __builtin_amdgcn_s_barrier();
    #pragma unroll
    for (int i=0;i<4;i++){ afr[i][0]=ldA(buf,0,i,0); afr[i][1]=ldA(buf,0,i,1); }
    #pragma unroll
    for (int j=0;j<2;j++){ bfr[j][0]=ldB(buf,0,j,0); bfr[j][1]=ldB(buf,0,j,1); }
    if (n1){ stage_half(t+1,2,buf^1); stage_half(t+1,3,buf^1); }
    asm volatile("s_waitcnt lgkmcnt(0)" ::: "memory");
    __builtin_amdgcn_sched_barrier(0);
    __builtin_amdgcn_s_setprio(1);
    MM8(0,0);
    __builtin_amdgcn_s_setprio(0);
    // ---- q1: (mh=0, nh=1); reuse afr ----
    __builtin_amdgcn_s_barrier();
    #pragma unroll
    for (int j=0;j<2;j++){ bfr[j][0]=ldB(buf,1,j,0); bfr[j][1]=ldB(buf,1,j,1); }
    asm volatile("s_waitcnt lgkmcnt(0)" ::: "memory");
    __builtin_amdgcn_sched_barrier(0);
    __builtin_amdgcn_s_setprio(1);
    MM8(0,1);
    __builtin_amdgcn_s_setprio(0);
    // ---- q2: (mh=1, nh=0); stage t+2.A0 into freed A0 slot ----
    __builtin_amdgcn_s_barrier();
    #pragma unroll
    for (int i=0;i<4;i++){ afr[i][0]=ldA(buf,1,i,0); afr[i][1]=ldA(buf,1,i,1); }
    #pragma unroll
    for (int j=0;j<2;j++){ bfr[j][0]=ldB(buf,0,j,0); bfr[j][1]=ldB(buf,0,j,1); }
    if (n2) stage_half(t+2,0,buf);
    asm volatile("s_waitcnt lgkmcnt(0)" ::: "memory");
    __builtin_amdgcn_sched_barrier(0);
    __builtin_amdgcn_s_setprio(1);
    MM8(1,0);
    __builtin_amdgcn_s_setprio(0);
    // ---- q3: (mh=1, nh=1); stage t+2.B0 ----
    __builtin_amdgcn_s_barrier();
    #pragma unroll
    for (int j=0;j<2;j++){ bfr[j][0]=ldB(buf,1,j,0); bfr[j][1]=ldB(buf,1,j,1); }
    if (n2) stage_half(t+2,1,buf);
    asm volatile("s_waitcnt lgkmcnt(0)" ::: "memory");
    __builtin_amdgcn_sched_barrier(0);
    __builtin_amdgcn_s_setprio(1);
    MM8(1,1);
    __builtin_amdgcn_s_setprio(0);
  }
#undef MM8

  #pragma unroll
  for (int mi=0;mi<8;mi++){
    const int mloc = (mi<4) ? (wr*64 + mi*16) : (128 + wr*64 + (mi-4)*16);
    #pragma unroll
    for (int r=0;r<4;r++){
      const long mg = bm0 + mloc + kgrp*4 + r;
      #pragma unroll
      for (int ni=0;ni<4;ni++){
        const int nloc = (ni<2) ? (wc*32 + ni*16) : (128 + wc*32 + (ni-2)*16);
        const int ng = bn0 + nloc + row16;
        float v = acc[mi][ni][r] + bias[ng];
        if constexpr (MODE==EP_F32RES){
          v += resid[mg*ldc + ng];
          of32[mg*ldc + ng] = v;
        } else if constexpr (MODE==EP_GELU){
          obf[mg*ldc + ng] = f2bs(gelu_f(v));
        } else {
          obf[mg*ldc + ng] = f2bs(v);
        }
      }
    }
  }
}

// ============== R9/R10 depth-2 GEMM (for down / O: 64x128, 4 waves) ======
template<int BM,int BN,int WM,int WN,int MODE,bool LORA,bool SWZ>
__global__ __launch_bounds__((BM/WM)*(BN/WN)*64) void gemm_bt(
    const u16* __restrict__ A, int lda,
    const u16* __restrict__ B, int ldb,
    int K,
    u16* __restrict__ obf, float* __restrict__ of32, int ldc,
    const float* __restrict__ bias,
    const u16* __restrict__ tA, int tlda,
    const u16* __restrict__ lbB,
    const float* __restrict__ resid)
{
  constexpr int NWM = BM/WM, NWN = BN/WN, NW = NWM*NWN;
  constexpr int FM = WM/16, FN = WN/16;
  constexpr int TILE = (BM+BN)*64;
  constexpr int LPT = (BM+BN)/(8*NW);
  static_assert(NW==4 || NW==8, "4 or 8 waves");
  static_assert((BM/8)%NW==0 && (BN/8)%NW==0, "row-group striping");
  __shared__ u16 ab[2*TILE];

  const int tid = threadIdx.x;
  const int lane = tid & 63, wave = tid >> 6;
  const int wr = wave / NWN, wc = wave % NWN;
  const int row16 = lane & 15, kgrp = lane >> 4;
  int bx = blockIdx.x, by = blockIdx.y;
  if constexpr (SWZ)
    swizzle_bid(blockIdx.y*gridDim.x + blockIdx.x, gridDim.x, gridDim.y, bx, by);
  const int bm0 = by * BM, bn0 = bx * BN;

  const u16* Ab = A + (long)bm0*lda;
  const u16* Bb = B + (long)bn0*ldb;
  const int tsel = (LORA && tlda==192) ? ((bn0>>10)*64) : 0;
  const int srow = lane >> 3;
  const int gcol = ((lane&7) ^ srow) * 8;

  const int nKT = K >> 6;
  const int nIT = nKT + (LORA ? 1 : 0);

  auto stage = [&](int kt, int buf){
    const u16 *Ak, *Bk; long la_, lb_;
    if (!LORA || kt < nKT){ Ak = Ab + kt*64; la_ = lda; Bk = Bb + kt*64; lb_ = ldb; }
    else { Ak = tA + (long)bm0*tlda + tsel; la_ = tlda; Bk = lbB + (long)bn0*64; lb_ = 64; }
    char* l = (char*)(ab + buf*TILE);
    #pragma unroll
    for (int g0=0; g0<BM/8; g0+=NW){
      int g = g0 + wave;
      GLL16(Ak + (long)(g*8 + srow)*la_ + gcol, l + g*1024);
    }
    #pragma unroll
    for (int g0=0; g0<BN/8; g0+=NW){
      int g = g0 + wave;
      GLL16(Bk + (long)(g*8 + srow)*lb_ + gcol, l + BM*128 + g*1024);
    }
  };

  floatx4 acc[FM][FN];
  #pragma unroll
  for (int i=0;i<FM;i++)
    #pragma unroll
    for (int j=0;j<FN;j++)
      acc[i][j] = (floatx4){0.f,0.f,0.f,0.f};

  stage(0, 0);
  if (nIT > 1) stage(1, 1);
  int cur = 0;
  for (int kt=0; kt<nIT; ++kt){
    if (kt+1 < nIT) asm volatile("s_waitcnt vmcnt(%0)" :: "n"(LPT) : "memory");
    else            asm volatile("s_waitcnt vmcnt(0)" ::: "memory");
    __builtin_amdgcn_s_barrier();

    const char* lds = (const char*)(ab + cur*TILE);
    __builtin_amdgcn_s_setprio(1);
    #pragma unroll
    for (int ks=0; ks<2; ++ks){
      short8 af[FM], bfr[FN];
      #pragma unroll
      for (int mi=0;mi<FM;mi++){
        int r_ = wr*WM + mi*16 + row16;
        af[mi] = *(const short8*)(lds + r_*128 + (((ks*4 + kgrp) ^ (r_&7))<<4));
      }
      #pragma unroll
      for (int ni=0;ni<FN;ni++){
        int r_ = wc*WN + ni*16 + row16;
        bfr[ni] = *(const short8*)(lds + BM*128 + r_*128 + (((ks*4 + kgrp) ^ (r_&7))<<4));
      }
      #pragma unroll
      for (int mi=0;mi<FM;mi++)
        #pragma unroll
        for (int ni=0;ni<FN;ni++)
          acc[mi][ni] = __builtin_amdgcn_mfma_f32_16x16x32_bf16(af[mi], bfr[ni], acc[mi][ni], 0, 0, 0);
    }
    __builtin_amdgcn_s_setprio(0);

    asm volatile("s_waitcnt lgkmcnt(0)" ::: "memory");
    __builtin_amdgcn_sched_barrier(0);
    __builtin_amdgcn_s_barrier();
    if (kt+2 < nIT) stage(kt+2, cur);
    cur ^= 1;
  }

  #pragma unroll
  for (int mi=0;mi<FM;mi++){
    #pragma unroll
    for (int r=0;r<4;r++){
      const int ml = wr*WM + mi*16 + kgrp*4 + r;
      const long mg = bm0 + ml;
      #pragma unroll
      for (int ni=0;ni<FN;ni++){
        const int nl = wc*WN + ni*16 + row16;
        const int ng = bn0 + nl;
        float v = acc[mi][ni][r] + bias[ng];
        if constexpr (MODE==EP_F32RES){
          v += resid[mg*ldc + ng];
          of32[mg*ldc + ng] = v;
        } else if constexpr (MODE==EP_GELU){
          obf[mg*ldc + ng] = f2bs(gelu_f(v));
        } else {
          obf[mg*ldc + ng] = f2bs(v);
        }
      }
    }
  }
}

// ---- LoRA stage-1 via MFMA ----
template<int NT>
__global__ __launch_bounds__(64) void lora_mfma(
    const u16* __restrict__ A, const int K,
    const u16* __restrict__ lat,
    u16* __restrict__ t, int tld)
{
  const int lane = threadIdx.x & 63;
  const int c = lane & 15, kg = lane >> 4;
  const int m0 = blockIdx.x * 16;
  const u16* Arow = A + (long)(m0 + c)*K + kg*8;
  const u16* Brow = lat + (long)c*K + kg*8;
  floatx4 acc[NT];
  #pragma unroll
  for (int tj=0;tj<NT;tj++) acc[tj] = (floatx4){0.f,0.f,0.f,0.f};
  const int nKS = K >> 5;
  #pragma unroll 4
  for (int ks=0; ks<nKS; ++ks){
    short8 a = *(const short8*)(Arow + ks*32);
    #pragma unroll
    for (int tj=0; tj<NT; ++tj){
      short8 b = *(const short8*)(Brow + (long)tj*16*K + ks*32);
      acc[tj] = __builtin_amdgcn_mfma_f32_16x16x32_bf16(a, b, acc[tj], 0, 0, 0);
    }
  }
  #pragma unroll
  for (int tj=0; tj<NT; ++tj)
    #pragma unroll
    for (int r=0;r<4;r++){
      u16* dst = t + (long)(m0 + kg*4 + r)*tld + tj*64;
      dst[c] = f2bs(acc[tj][r]);
      dst[16+c] = 0; dst[32+c] = 0; dst[48+c] = 0;
    }
}

// ---- fused flash attention ----
__global__ __launch_bounds__(256) void flash_attn(
    const u16* __restrict__ qkv,
    const u16* __restrict__ vt,
    const float* __restrict__ mask,
    u16* __restrict__ attn_o)
{
  __shared__ u16 sm[33792];
  u16* Qs = sm;
  u16* Ps = sm + 24576;

  const int tid = threadIdx.x, lane = tid & 63, wave = tid >> 6;
  const int c = lane & 15, kg = lane >> 4;
  const int qt = blockIdx.x;
  const int z  = blockIdx.y;
  const int b = z >> 4, h = z & 15;
  const int q0 = qt * 128;
  const int srow = lane >> 3;
  const int scol = ((lane&7) ^ srow) * 8;

  const u16* kbase = qkv + ((long)(b*512))*3072 + 1024 + h*64;
  const u16* vbase = vt + (long)z*64*512;

  auto stage_kv = [&](int kv, int buf){
    char* Kd = (char*)(sm + 8192  + buf*4096);
    char* Vd = (char*)(sm + 16384 + buf*4096);
    #pragma unroll
    for (int i=0;i<2;i++){
      int rb = i*32 + wave*8;
      GLL16(kbase + (long)(kv*64 + rb + srow)*3072 + scol, Kd + rb*128);
      GLL16(vbase + (long)(rb + srow)*512 + kv*64 + scol, Vd + rb*128);
    }
  };

  {
    const u16* src = qkv + ((long)(b*512 + q0))*3072 + h*64;
    #pragma unroll
    for (int i=0;i<4;i++){
      int rb = i*32 + wave*8;
      GLL16(src + (long)(rb + srow)*3072 + scol, (char*)Qs + rb*128);
    }
  }
  stage_kv(0, 0);
  __syncthreads();

  auto ld_swz = [&](const u16* t, int row, int koff8) -> short8 {
    return *(const short8*)((const char*)t + row*128 + ((koff8 ^ (row&7))<<4));
  };

  short8 af[2][2];
  #pragma unroll
  for (int mi=0;mi<2;mi++)
    #pragma unroll
    for (int ks=0;ks<2;ks++)
      af[mi][ks] = ld_swz(Qs, wave*32 + mi*16 + c, ks*4 + kg);

  floatx4 o_acc[2][4];
  float m_run[2][4], l_run[2][4];
  #pragma unroll
  for (int mi=0;mi<2;mi++){
    #pragma unroll
    for (int dj=0;dj<4;dj++) o_acc[mi][dj] = (floatx4){0.f,0.f,0.f,0.f};
    #pragma unroll
    for (int r=0;r<4;r++){ m_run[mi][r] = -3.0e38f; l_run[mi][r] = 0.f; }
  }

  int cur = 0;
  for (int kv=0; kv<8; ++kv){
    if (kv+1 < 8) stage_kv(kv+1, cur^1);
    const u16* Ks = sm + 8192  + cur*4096;
    const u16* Vs = sm + 16384 + cur*4096;

    floatx4 s_acc[2][4];
    #pragma unroll
    for (int mi=0;mi<2;mi++)
      #pragma unroll
      for (int ni=0;ni<4;ni++)
        s_acc[mi][ni] = (floatx4){0.f,0.f,0.f,0.f};
    #pragma unroll
    for (int ks=0;ks<2;ks++){
      short8 bf[4];
      #pragma unroll
      for (int ni=0;ni<4;ni++)
        bf[ni] = ld_swz(Ks, ni*16 + c, ks*4 + kg);
      #pragma unroll
      for (int mi=0;mi<2;mi++)
        #pragma unroll
        for (int ni=0;ni<4;ni++)
          s_acc[mi][ni] = __builtin_amdgcn_mfma_f32_16x16x32_bf16(af[mi][ks], bf[ni], s_acc[mi][ni], 0, 0, 0);
    }

    float mv[4];
    #pragma unroll
    for (int ni=0;ni<4;ni++) mv[ni] = mask[b*512 + kv*64 + ni*16 + c];

    #pragma unroll
    for (int mi=0;mi<2;mi++){
      #pragma unroll
      for (int r=0;r<4;r++){
        float s0 = s_acc[mi][0][r]*0.125f + mv[0];
        float s1 = s_acc[mi][1][r]*0.125f + mv[1];
        float s2 = s_acc[mi][2][r]*0.125f + mv[2];
        float s3 = s_acc[mi][3][r]*0.125f + mv[3];
        float tmax = fmaxf(fmaxf(s0,s1), fmaxf(s2,s3));
        #pragma unroll
        for (int o=1;o<16;o<<=1) tmax = fmaxf(tmax, __shfl_xor(tmax, o));
        const float mnew = fmaxf(m_run[mi][r], tmax);
        const float p0 = __expf(s0 - mnew), p1 = __expf(s1 - mnew);
        const float p2 = __expf(s2 - mnew), p3 = __expf(s3 - mnew);
        float psum = p0+p1+p2+p3;
        #pragma unroll
        for (int o=1;o<16;o<<=1) psum += __shfl_xor(psum, o);
        const float alpha = __expf(m_run[mi][r] - mnew);
        l_run[mi][r] = l_run[mi][r]*alpha + psum;
        m_run[mi][r] = mnew;
        #pragma unroll
        for (int dj=0;dj<4;dj++) o_acc[mi][dj][r] *= alpha;
        const int rl = mi*16 + kg*4 + r;
        u16* pw = Ps + wave*2304 + rl*72;
        pw[c]      = f2bs(p0);
        pw[16 + c] = f2bs(p1);
        pw[32 + c] = f2bs(p2);
        pw[48 + c] = f2bs(p3);
      }
    }
    __syncthreads();

    #pragma unroll
    for (int ks=0;ks<2;ks++){
      short8 pa[2], vb[4];
      #pragma unroll
      for (int mi=0;mi<2;mi++)
        pa[mi] = *(const short8*)&Ps[wave*2304 + (mi*16 + c)*72 + ks*32 + kg*8];
      #pragma unroll
      for (int dj=0;dj<4;dj++)
        vb[dj] = ld_swz(Vs, dj*16 + c, ks*4 + kg);
      __builtin_amdgcn_s_setprio(1);
      #pragma unroll
      for (int mi=0;mi<2;mi++)
        #pragma unroll
        for (int dj=0;dj<4;dj++)
          o_acc[mi][dj] = __builtin_amdgcn_mfma_f32_16x16x32_bf16(pa[mi], vb[dj], o_acc[mi][dj], 0, 0, 0);
      __builtin_amdgcn_s_setprio(0);
    }
    __syncthreads();
    cur ^= 1;
  }

  #pragma unroll
  for (int mi=0;mi<2;mi++){
    #pragma unroll
    for (int r=0;r<4;r++){
      const float inv = 1.f / l_run[mi][r];
      const int s_g = q0 + wave*32 + mi*16 + kg*4 + r;
      u16* dst = attn_o + (long)(b*512 + s_g)*1024 + h*64;
      #pragma unroll
      for (int dj=0;dj<4;dj++)
        dst[dj*16 + c] = f2bs(o_acc[mi][dj][r]*inv);
    }
  }
}

// ---- bulk fp32 -> bf16 conversion, float4 wide ----
__global__ __launch_bounds__(256) void convert_bulk(
  const float* __restrict__ x,
  const float* __restrict__ wq, const float* __restrict__ wk, const float* __restrict__ wv,
  const float* __restrict__ wo, const float* __restrict__ wup, const float* __restrict__ wdn,
  u16* __restrict__ xb, u16* __restrict__ wqkv, u16* __restrict__ wob,
  u16* __restrict__ wupb, u16* __restrict__ wdnb)
{
  const long NX = 4194304, NWt = 1048576;
  const long T4 = (NX + 3*NWt + NWt + NX + NX) >> 2;
  for (long i4 = (long)blockIdx.x*256 + threadIdx.x; i4 < T4; i4 += (long)gridDim.x*256){
    long j = i4 << 2;
    const float* src; u16* dst; long soff, doff;
    if (j < NX){ src=x; dst=xb; soff=j; doff=j; }
    else { j -= NX;
      if (j < 3*NWt){ int p=(int)(j>>20); src = p==0?wq:(p==1?wk:wv); dst=wqkv; soff = j & (NWt-1); doff = j; }
      else { j -= 3*NWt;
        if (j < NWt){ src=wo; dst=wob; soff=j; doff=j; }
        else { j -= NWt;
          if (j < NX){ src=wup; dst=wupb; soff=j; doff=j; }
          else { j -= NX; src=wdn; dst=wdnb; soff=j; doff=j; }
        }
      }
    }
    const float4 v = *(const float4*)(src + soff);
    ushort4 o;
    o.x = f2bs(v.x); o.y = f2bs(v.y); o.z = f2bs(v.z); o.w = f2bs(v.w);
    *(ushort4*)(dst + doff) = o;
  }
}

// ---- small conversions ----
__global__ __launch_bounds__(256) void convert_small(
  const float* __restrict__ bq, const float* __restrict__ bk, const float* __restrict__ bv,
  const float* __restrict__ lbq, const float* __restrict__ lbk, const float* __restrict__ lbv,
  const float* __restrict__ lbo, const float* __restrict__ lbup, const float* __restrict__ lbdn,
  const float* __restrict__ laq, const float* __restrict__ lak, const float* __restrict__ lav,
  const float* __restrict__ lao, const float* __restrict__ laup, const float* __restrict__ ladn,
  float* __restrict__ biascat, u16* __restrict__ lbtqkv, u16* __restrict__ lbto,
  u16* __restrict__ lbtup, u16* __restrict__ lbtdn,
  u16* __restrict__ latqkv, u16* __restrict__ lato,
  u16* __restrict__ latup, u16* __restrict__ latdn)
{
  long i = (long)blockIdx.x*256 + threadIdx.x;
  if (i < 3072){ int p=(int)(i>>10); biascat[i] = (p==0?bq:(p==1?bk:bv))[i&1023]; return; }
  i -= 3072;
  if (i < 49152){ int k=(int)(i/3072), n=(int)(i%3072); int p=n>>10;
    const float* l = p==0?lbq:(p==1?lbk:lbv);
    u16* d = lbtqkv + (long)n*64 + k;
    d[0] = f2bs(l[k*1024 + (n&1023)]); d[16]=0; d[32]=0; d[48]=0; return; }
  i -= 49152;
  if (i < 16384){ int k=(int)(i>>10), n=(int)(i&1023);
    u16* d = lbto + (long)n*64 + k;
    d[0] = f2bs(lbo[k*1024+n]); d[16]=0; d[32]=0; d[48]=0; return; }
  i -= 16384;
  if (i < 65536){ int k=(int)(i>>12), n=(int)(i&4095);
    u16* d = lbtup + (long)n*64 + k;
    d[0] = f2bs(lbup[k*4096+n]); d[16]=0; d[32]=0; d[48]=0; return; }
  i -= 65536;
  if (i < 16384){ int k=(int)(i>>10), n=(int)(i&1023);
    u16* d = lbtdn + (long)n*64 + k;
    d[0] = f2bs(lbdn[k*1024+n]); d[16]=0; d[32]=0; d[48]=0; return; }
  i -= 16384;
  if (i < 49152){ int r=(int)(i>>10), k=(int)(i&1023);
    const float* l = r<16 ? laq : (r<32 ? lak : lav);
    latqkv[i] = f2bs(l[k*16 + (r&15)]); return; }
  i -= 49152;
  if (i < 16384){ int r=(int)(i>>10), k=(int)(i&1023);
    lato[i] = f2bs(lao[k*16+r]); return; }
  i -= 16384;
  if (i < 16384){ int r=(int)(i>>10), k=(int)(i&1023);
    latup[i] = f2bs(laup[k*16+r]); return; }
  i -= 16384;
  if (i < 65536){ int r=(int)(i>>12), k=(int)(i&4095);
    latdn[i] = f2bs(ladn[k*16+r]); }
}

// ---- V transpose ----
__global__ __launch_bounds__(256) void transpose_v(const u16* __restrict__ qkv, u16* __restrict__ vt){
  const int st = blockIdx.x;
  const int z = blockIdx.y;
  const int b = z >> 4, h = z & 15;
  __shared__ u16 tile[64][68];
  const int t = threadIdx.x;
  const int q16 = t & 15, g16 = t >> 4;
  const u16* src = qkv + ((long)(b*512 + st*64))*3072 + 2048 + h*64;
  #pragma unroll
  for (int i=0;i<4;i++){
    int s_l = i*16 + g16;
    const u16* pp = src + (long)s_l*3072 + q16*4;
    #pragma unroll
    for (int jj=0;jj<4;jj++) tile[s_l][q16*4+jj] = pp[jj];
  }
  __syncthreads();
  u16* dst = vt + (long)z*64*512 + st*64;
  #pragma unroll
  for (int i=0;i<4;i++){
    int d_l = i*16 + g16;
    int s_l = q16*4;
    unsigned long long v = (unsigned long long)tile[s_l][d_l]
      | ((unsigned long long)tile[s_l+1][d_l] << 16)
      | ((unsigned long long)tile[s_l+2][d_l] << 32)
      | ((unsigned long long)tile[s_l+3][d_l] << 48);
    *(unsigned long long*)(dst + (long)d_l*512 + s_l) = v;
  }
}

// ---- LayerNorm ----
__global__ __launch_bounds__(256) void ln_k(
    const float* __restrict__ in, float* __restrict__ outf, u16* __restrict__ outb,
    const float* __restrict__ gam, const float* __restrict__ bet)
{
  const long row = blockIdx.x;
  const float4 v = ((const float4*)(in + row*1024))[threadIdx.x];
  float s = v.x+v.y+v.z+v.w;
  float q = v.x*v.x + v.y*v.y + v.z*v.z + v.w*v.w;
  const int lane = threadIdx.x & 63, w = threadIdx.x >> 6;
  __shared__ float rs[4], rq[4];
  #pragma unroll
  for (int o=32;o;o>>=1){ s += __shfl_down(s,o); q += __shfl_down(q,o); }
  if (!lane){ rs[w]=s; rq[w]=q; }
  __syncthreads();
  const float S = rs[0]+rs[1]+rs[2]+rs[3];
  const float Q = rq[0]+rq[1]+rq[2]+rq[3];
  const float mu = S*(1.f/1024.f);
  const float var = Q*(1.f/1024.f) - mu*mu;
  const float rstd = rsqrtf(var + 1e-5f);
  const float4 g = ((const float4*)gam)[threadIdx.x];
  const float4 b = ((const float4*)bet)[threadIdx.x];
  float4 o;
  o.x = (v.x-mu)*rstd*g.x + b.x;
  o.y = (v.y-mu)*rstd*g.y + b.y;
  o.z = (v.z-mu)*rstd*g.z + b.z;
  o.w = (v.w-mu)*rstd*g.w + b.w;
  if (outf) ((float4*)(outf + row*1024))[threadIdx.x] = o;
  if (outb){
    uint2 u;
    u.x = (unsigned)f2bs(o.x) | ((unsigned)f2bs(o.y) << 16);
    u.y = (unsigned)f2bs(o.z) | ((unsigned)f2bs(o.w) << 16);
    ((uint2*)(outb + row*1024))[threadIdx.x] = u;
  }
}

extern "C" void kernel_launch(void* const* d_in, const int* in_sizes, int n_in,
                              void* d_out, int out_size, void* d_ws, size_t ws_size,
                              hipStream_t stream) {
  const float* x      = (const float*)d_in[0];
  const float* mask   = (const float*)d_in[1];
  const float* w_q    = (const float*)d_in[2];
  const float* b_q    = (const float*)d_in[3];
  const float* la_q   = (const float*)d_in[4];
  const float* lb_q   = (const float*)d_in[5];
  const float* w_k    = (const float*)d_in[6];
  const float* b_k    = (const float*)d_in[7];
  const float* la_k   = (const float*)d_in[8];
  const float* lb_k   = (const float*)d_in[9];
  const float* w_v    = (const float*)d_in[10];
  const float* b_v    = (const float*)d_in[11];
  const float* la_v   = (const float*)d_in[12];
  const float* lb_v   = (const float*)d_in[13];
  const float* w_o    = (const float*)d_in[14];
  const float* b_o    = (const float*)d_in[15];
  const float* la_o   = (const float*)d_in[16];
  const float* lb_o   = (const float*)d_in[17];
  const float* nw1    = (const float*)d_in[18];
  const float* nb1    = (const float*)d_in[19];
  const float* w_up   = (const float*)d_in[20];
  const float* b_up   = (const float*)d_in[21];
  const float* la_up  = (const float*)d_in[22];
  const float* lb_up  = (const float*)d_in[23];
  const float* w_dn   = (const float*)d_in[24];
  const float* b_dn   = (const float*)d_in[25];
  const float* la_dn  = (const float*)d_in[26];
  const float* lb_dn  = (const float*)d_in[27];
  const float* nw2    = (const float*)d_in[28];
  const float* nb2    = (const float*)d_in[29];
  float* out = (float*)d_out;

  char* ws = (char*)d_ws;
  size_t used = 0;
  auto alloc = [&](size_t bytes) -> char* {
    char* p = ws + used;
    used += (bytes + 255) & ~(size_t)255;
    return p;
  };
  u16*   xb      = (u16*)  alloc(4194304*2);
  u16*   wqkv    = (u16*)  alloc(3145728*2);
  u16*   wob     = (u16*)  alloc(1048576*2);
  u16*   wupb    = (u16*)  alloc(4194304*2);
  u16*   wdnb    = (u16*)  alloc(4194304*2);
  float* biascat = (float*)alloc(3072*4);
  u16*   lbtqkv  = (u16*)  alloc((size_t)3072*64*2);
  u16*   lbto    = (u16*)  alloc((size_t)1024*64*2);
  u16*   lbtup   = (u16*)  alloc((size_t)4096*64*2);
  u16*   lbtdn   = (u16*)  alloc((size_t)1024*64*2);
  u16*   latqkv  = (u16*)  alloc(48*1024*2);
  u16*   lato    = (u16*)  alloc(16*1024*2);
  u16*   latup   = (u16*)  alloc(16*1024*2);
  u16*   latdn   = (u16*)  alloc(16*4096*2);
  u16*   t_all   = (u16*)  alloc((size_t)4096*192*2);
  u16*   t_o     = (u16*)  alloc((size_t)4096*64*2);
  u16*   t_up    = (u16*)  alloc((size_t)4096*64*2);
  u16*   t_dn    = (u16*)  alloc((size_t)4096*64*2);
  u16*   qkv     = (u16*)  alloc((size_t)4096*3072*2);
  u16*   vt      = (u16*)  alloc((size_t)128*64*512*2);
  u16*   attn_o  = (u16*)  alloc(4194304*2);
  float* o_final = (float*)alloc((size_t)4194304*4);
  float* x_med   = (float*)alloc((size_t)4194304*4);
  u16*   x_med_b = (u16*)  alloc(4194304*2);
  u16*   fn      = (u16*)  alloc((size_t)4096*4096*2);
  if (used > ws_size) return;

  // 1. convert
  convert_bulk<<<2048, 256, 0, stream>>>(x, w_q, w_k, w_v, w_o, w_up, w_dn,
                                         xb, wqkv, wob, wupb, wdnb);
  convert_small<<<1164, 256, 0, stream>>>(b_q, b_k, b_v, lb_q, lb_k, lb_v,
                                          lb_o, lb_up, lb_dn,
                                          la_q, la_k, la_v, la_o, la_up, la_dn,
                                          biascat, lbtqkv, lbto, lbtup, lbtdn,
                                          latqkv, lato, latup, latdn);
  // 2. LoRA stage-1 q,k,v fused
  lora_mfma<3><<<256, 64, 0, stream>>>(xb, 1024, latqkv, t_all, 192);
  // 3. fused QKV GEMM (8-phase 256^2)
  gemm8<EP_BF16,true,true><<<dim3(12,16,1), 512, 0, stream>>>(
      xb, 1024, wqkv, 1024, 1024, qkv, nullptr, 3072,
      biascat, t_all, 192, lbtqkv, nullptr);
  // 4. V transpose
  transpose_v<<<dim3(8,128), 256, 0, stream>>>(qkv, vt);
  // 5. flash attention
  flash_attn<<<dim3(4,128), 256, 0, stream>>>(qkv, vt, mask, attn_o);
  // 6. LoRA stage-1 for O
  lora_mfma<1><<<256, 64, 0, stream>>>(attn_o, 1024, lato, t_o, 64);
  // 7. O projection (R9 depth-2, 64x128)
  gemm_bt<64,128,32,64,EP_F32RES,true,true><<<dim3(8,64,1), 256, 0, stream>>>(
      attn_o, 1024, wob, 1024, 1024, nullptr, o_final, 1024,
      b_o, t_o, 64, lbto, x);
  // 8. LN1
  ln_k<<<4096, 256, 0, stream>>>(o_final, x_med, x_med_b, nw1, nb1);
  // 9. LoRA stage-1 for up
  lora_mfma<1><<<256, 64, 0, stream>>>(x_med_b, 1024, latup, t_up, 64);
  // 10. up GEMM (8-phase 256^2)
  gemm8<EP_GELU,true,true><<<dim3(16,16,1), 512, 0, stream>>>(
      x_med_b, 1024, wupb, 1024, 1024, fn, nullptr, 4096,
      b_up, t_up, 64, lbtup, nullptr);
  // 11. LoRA stage-1 for down (K=4096)
  lora_mfma<1><<<256, 64, 0, stream>>>(fn, 4096, latdn, t_dn, 64);
  // 12. down GEMM (R9 depth-2, 64x128)
  gemm_bt<64,128,32,64,EP_F32RES,true,true><<<dim3(8,64,1), 256, 0, stream>>>(
      fn, 4096, wdnb, 4096, 4096, nullptr, out, 1024,
      b_dn, t_dn, 64, lbtdn, x_med);
  // 13. LN2
  ln_k<<<4096, 256, 0, stream>>>(out, out, nullptr, nw2, nb2);
}

// Round 14
// 274.688 us; speedup vs baseline: 1.3762x; 1.0052x over previous
//
#include <hip/hip_runtime.h>
#include <math.h>

typedef unsigned short u16;
typedef __attribute__((ext_vector_type(8))) short short8;
typedef __attribute__((ext_vector_type(4))) float floatx4;

#define DEV __device__ __forceinline__

DEV u16 f2bs(float f){ union{float f; unsigned u;} v; v.f=f; unsigned r = v.u + 0x7fffu + ((v.u>>16)&1u); return (u16)(r>>16); }
DEV float bs2f(u16 u){ union{float f; unsigned u;} v; v.u = ((unsigned)u)<<16; return v.f; }

// tanh-form GELU (max |delta| vs exact-erf gelu ~3e-4; bf16-safe).
DEV float gelu_f(float x){
  float u2 = 2.f * x * (0.7978845608028654f + 0.03567740813636141f*x*x);
  float e = __expf(u2);
  float th = 1.f - 2.f/(e + 1.f);
  return 0.5f*x*(1.f + th);
}

#define GLL16(G,L) __builtin_amdgcn_global_load_lds((__attribute__((address_space(1))) const void*)(G), (__attribute__((address_space(3))) void*)(L), 16, 0, 0)
#define SB0() __builtin_amdgcn_sched_barrier(0)

enum { EP_BF16=0, EP_F32RES=3, EP_GELU=4 };

// XCD-chunked bijective block swizzle (m204) + group-major (G rows) ordering.
DEV void swizzle_bid(int orig, int gx, int gy, int& bx, int& by){
  const int nwg = gx*gy;
  const int q = nwg >> 3, r = nwg & 7;
  const int xcd = orig & 7, idx = orig >> 3;
  const int logical = (xcd < r) ? xcd*(q+1) + idx : r*(q+1) + (xcd-r)*q + idx;
  const int G = 8;
  const int per = G*gx;
  const int gid = logical / per;
  const int rem = logical - gid*per;
  const int by0 = gid*G;
  const int rows = min(G, gy - by0);
  by = by0 + rem % rows;
  bx = rem / rows;
}

// ================= 256x256 reg-pipelined GEMM (m201-style interleave) =====
// 8 waves (2M x 4N), per-wave C 128x64 (interleaved halves). Per K-tile:
// issue the MINIMAL 24 ds_read_b128 in 3 SB-fenced groups with COUNTED
// lgkmcnt so reads complete under preceding MFMAs:
//   [A0(8),B0(4)] SB [B1(4)] lgkm(4) SB MFMA(0,0)
//   [A1(8)]            lgkm(8) SB MFMA(0,1)
//   lgkm(0) SB barrier stage(t+2.A0B0) MFMA(1,1) MFMA(1,0)
// B frags held in regs across both mh halves (no re-reads). 2 barriers/tile;
// vmcnt(8) once per tile (full next tile stays in flight).
template<int MODE,bool LORA,bool SWZ>
__global__ __launch_bounds__(512,2) void gemm8(
    const u16* __restrict__ A, int lda,
    const u16* __restrict__ B, int ldb,
    int K,
    u16* __restrict__ obf, float* __restrict__ of32, int ldc,
    const float* __restrict__ bias,
    const u16* __restrict__ tA, int tlda,   // [M][tlda], 64-wide slices, cols 16..63 zero
    const u16* __restrict__ lbB,            // [N][64], cols 16..63 zero
    const float* __restrict__ resid)
{
  __shared__ u16 sm8[65536];  // 128 KB: 2 bufs x (A 32KB + B 32KB)
  const int tid = threadIdx.x;
  const int lane = tid & 63, wave = tid >> 6;
  const int wr = wave >> 2, wc = wave & 3;
  const int row16 = lane & 15, kgrp = lane >> 4;
  int bx = blockIdx.x, by = blockIdx.y;
  if constexpr (SWZ)
    swizzle_bid(blockIdx.y*gridDim.x + blockIdx.x, gridDim.x, gridDim.y, bx, by);
  const int bm0 = by*256, bn0 = bx*256;
  const u16* Ab = A + (long)bm0*lda;
  const u16* Bb = B + (long)bn0*ldb;
  const int tsel = (LORA && tlda==192) ? ((bn0>>10)*64) : 0;
  const int srow = lane >> 3;
  const int gcol = ((lane&7) ^ srow) * 8;
  const int nKT = K >> 6;
  const int nIT = nKT + (LORA ? 1 : 0);

  // stage one half-tile h of tile kt into buffer buf. h: 0=A0,1=B0,2=A1,3=B1.
  auto stage_half = [&](int kt, int h, int buf){
    const int isB = h & 1, hi = h >> 1;
    const u16* src; long ld;
    if (!LORA || kt < nKT){
      if (isB){ src = Bb + kt*64; ld = ldb; } else { src = Ab + kt*64; ld = lda; }
    } else {
      if (isB){ src = lbB + (long)bn0*64; ld = 64; }
      else    { src = tA + (long)bm0*tlda + tsel; ld = tlda; }
    }
    char* base = (char*)sm8 + buf*65536 + isB*32768 + hi*16384;
    #pragma unroll
    for (int rr=0; rr<2; ++rr){
      int g = wave + rr*8;
      GLL16(src + (long)(hi*128 + g*8 + srow)*ld + gcol, base + g*1024);
    }
  };
  auto ldA = [&](int buf, int mh, int i, int ks)->short8{
    int r_ = mh*128 + wr*64 + i*16 + row16;
    return *(const short8*)((const char*)sm8 + buf*65536 + r_*128 + (((ks*4+kgrp) ^ (r_&7))<<4));
  };
  auto ldB = [&](int buf, int nh, int j, int ks)->short8{
    int r_ = nh*128 + wc*32 + j*16 + row16;
    return *(const short8*)((const char*)sm8 + buf*65536 + 32768 + r_*128 + (((ks*4+kgrp) ^ (r_&7))<<4));
  };

  floatx4 acc[8][4];
  #pragma unroll
  for (int i=0;i<8;i++)
    #pragma unroll
    for (int j=0;j<4;j++)
      acc[i][j] = (floatx4){0.f,0.f,0.f,0.f};

  // prologue: tile0 full, tile1 A0+B0
  stage_half(0,0,0); stage_half(0,1,0); stage_half(0,2,0); stage_half(0,3,0);
  if (nIT>1){ stage_half(1,0,1); stage_half(1,1,1); }

#define MM8(mh,nh,AR,BR) \
  { _Pragma("unroll") \
    for (int i=0;i<4;i++) \
      _Pragma("unroll") \
      for (int j=0;j<2;j++) \
        _Pragma("unroll") \
        for (int ks=0;ks<2;ks++) \
          acc[(mh)*4+i][(nh)*2+j] = __builtin_amdgcn_mfma_f32_16x16x32_bf16(AR[i][ks], BR[j][ks], acc[(mh)*4+i][(nh)*2+j], 0, 0, 0); }

  int buf = 0;
  for (int t=0; t<nIT; ++t, buf^=1){
    const bool n1 = (t+1 < nIT), n2 = (t+2 < nIT);
    // start: stage next tile's second half; gate this tile's staging
    if (n1){ stage_half(t+1,2,buf^1); stage_half(t+1,3,buf^1); }
    if (n1) asm volatile("s_waitcnt vmcnt(8)" ::: "memory");
    else    asm volatile("s_waitcnt vmcnt(0)" ::: "memory");
    __builtin_amdgcn_s_barrier();

    short8 a0[4][2], a1[4][2], b0[2][2], b1[2][2];
    // group 1: A0 + B0
    #pragma unroll
    for (int i=0;i<4;i++){ a0[i][0]=ldA(buf,0,i,0); a0[i][1]=ldA(buf,0,i,1); }
    #pragma unroll
    for (int j=0;j<2;j++){ b0[j][0]=ldB(buf,0,j,0); b0[j][1]=ldB(buf,0,j,1); }
    SB0();
    // group 2: B1
    #pragma unroll
    for (int j=0;j<2;j++){ b1[j][0]=ldB(buf,1,j,0); b1[j][1]=ldB(buf,1,j,1); }
    asm volatile("s_waitcnt lgkmcnt(4)" ::: "memory");  // A0,B0 ready; B1 in flight
    SB0();
    __builtin_amdgcn_s_setprio(1);
    MM8(0,0,a0,b0);
    __builtin_amdgcn_s_setprio(0);
    SB0();
    // group 3: A1 (lands under q(0,1) MFMAs)
    #pragma unroll
    for (int i=0;i<4;i++){ a1[i][0]=ldA(buf,1,i,0); a1[i][1]=ldA(buf,1,i,1); }
    asm volatile("s_waitcnt lgkmcnt(8)" ::: "memory");  // B1 ready; A1 in flight
    SB0();
    __builtin_amdgcn_s_setprio(1);
    MM8(0,1,a0,b1);
    __builtin_amdgcn_s_setprio(0);
    asm volatile("s_waitcnt lgkmcnt(0)" ::: "memory");  // A1 ready; all buf reads done
    SB0();
    __builtin_amdgcn_s_barrier();                        // all waves done reading buf
    if (n2){ stage_half(t+2,0,buf); stage_half(t+2,1,buf); }  // refill freed slots
    __builtin_amdgcn_s_setprio(1);
    MM8(1,1,a1,b1);
    MM8(1,0,a1,b0);
    __builtin_amdgcn_s_setprio(0);
  }
#undef MM8

  #pragma unroll
  for (int mi=0;mi<8;mi++){
    const int mloc = (mi<4) ? (wr*64 + mi*16) : (128 + wr*64 + (mi-4)*16);
    #pragma unroll
    for (int r=0;r<4;r++){
      const long mg = bm0 + mloc + kgrp*4 + r;
      #pragma unroll
      for (int ni=0;ni<4;ni++){
        const int nloc = (ni<2) ? (wc*32 + ni*16) : (128 + wc*32 + (ni-2)*16);
        const int ng = bn0 + nloc + row16;
        float v = acc[mi][ni][r] + bias[ng];
        if constexpr (MODE==EP_F32RES){
          v += resid[mg*ldc + ng];
          of32[mg*ldc + ng] = v;
        } else if constexpr (MODE==EP_GELU){
          obf[mg*ldc + ng] = f2bs(gelu_f(v));
        } else {
          obf[mg*ldc + ng] = f2bs(v);
        }
      }
    }
  }
}

// ============== R9/R10 depth-2 GEMM (for down / O: 64x128, 4 waves) ======
template<int BM,int BN,int WM,int WN,int MODE,bool LORA,bool SWZ>
__global__ __launch_bounds__((BM/WM)*(BN/WN)*64) void gemm_bt(
    const u16* __restrict__ A, int lda,
    const u16* __restrict__ B, int ldb,
    int K,
    u16* __restrict__ obf, float* __restrict__ of32, int ldc,
    const float* __restrict__ bias,
    const u16* __restrict__ tA, int tlda,
    const u16* __restrict__ lbB,
    const float* __restrict__ resid)
{
  constexpr int NWM = BM/WM, NWN = BN/WN, NW = NWM*NWN;
  constexpr int FM = WM/16, FN = WN/16;
  constexpr int TILE = (BM+BN)*64;
  constexpr int LPT = (BM+BN)/(8*NW);
  static_assert(NW==4 || NW==8, "4 or 8 waves");
  static_assert((BM/8)%NW==0 && (BN/8)%NW==0, "row-group striping");
  __shared__ u16 ab[2*TILE];

  const int tid = threadIdx.x;
  const int lane = tid & 63, wave = tid >> 6;
  const int wr = wave / NWN, wc = wave % NWN;
  const int row16 = lane & 15, kgrp = lane >> 4;
  int bx = blockIdx.x, by = blockIdx.y;
  if constexpr (SWZ)
    swizzle_bid(blockIdx.y*gridDim.x + blockIdx.x, gridDim.x, gridDim.y, bx, by);
  const int bm0 = by * BM, bn0 = bx * BN;

  const u16* Ab = A + (long)bm0*lda;
  const u16* Bb = B + (long)bn0*ldb;
  const int tsel = (LORA && tlda==192) ? ((bn0>>10)*64) : 0;
  const int srow = lane >> 3;
  const int gcol = ((lane&7) ^ srow) * 8;

  const int nKT = K >> 6;
  const int nIT = nKT + (LORA ? 1 : 0);

  auto stage = [&](int kt, int buf){
    const u16 *Ak, *Bk; long la_, lb_;
    if (!LORA || kt < nKT){ Ak = Ab + kt*64; la_ = lda; Bk = Bb + kt*64; lb_ = ldb; }
    else { Ak = tA + (long)bm0*tlda + tsel; la_ = tlda; Bk = lbB + (long)bn0*64; lb_ = 64; }
    char* l = (char*)(ab + buf*TILE);
    #pragma unroll
    for (int g0=0; g0<BM/8; g0+=NW){
      int g = g0 + wave;
      GLL16(Ak + (long)(g*8 + srow)*la_ + gcol, l + g*1024);
    }
    #pragma unroll
    for (int g0=0; g0<BN/8; g0+=NW){
      int g = g0 + wave;
      GLL16(Bk + (long)(g*8 + srow)*lb_ + gcol, l + BM*128 + g*1024);
    }
  };

  floatx4 acc[FM][FN];
  #pragma unroll
  for (int i=0;i<FM;i++)
    #pragma unroll
    for (int j=0;j<FN;j++)
      acc[i][j] = (floatx4){0.f,0.f,0.f,0.f};

  stage(0, 0);
  if (nIT > 1) stage(1, 1);
  int cur = 0;
  for (int kt=0; kt<nIT; ++kt){
    if (kt+1 < nIT) asm volatile("s_waitcnt vmcnt(%0)" :: "n"(LPT) : "memory");
    else            asm volatile("s_waitcnt vmcnt(0)" ::: "memory");
    __builtin_amdgcn_s_barrier();

    const char* lds = (const char*)(ab + cur*TILE);
    __builtin_amdgcn_s_setprio(1);
    #pragma unroll
    for (int ks=0; ks<2; ++ks){
      short8 af[FM], bfr[FN];
      #pragma unroll
      for (int mi=0;mi<FM;mi++){
        int r_ = wr*WM + mi*16 + row16;
        af[mi] = *(const short8*)(lds + r_*128 + (((ks*4 + kgrp) ^ (r_&7))<<4));
      }
      #pragma unroll
      for (int ni=0;ni<FN;ni++){
        int r_ = wc*WN + ni*16 + row16;
        bfr[ni] = *(const short8*)(lds + BM*128 + r_*128 + (((ks*4 + kgrp) ^ (r_&7))<<4));
      }
      #pragma unroll
      for (int mi=0;mi<FM;mi++)
        #pragma unroll
        for (int ni=0;ni<FN;ni++)
          acc[mi][ni] = __builtin_amdgcn_mfma_f32_16x16x32_bf16(af[mi], bfr[ni], acc[mi][ni], 0, 0, 0);
    }
    __builtin_amdgcn_s_setprio(0);

    asm volatile("s_waitcnt lgkmcnt(0)" ::: "memory");
    __builtin_amdgcn_sched_barrier(0);
    __builtin_amdgcn_s_barrier();
    if (kt+2 < nIT) stage(kt+2, cur);
    cur ^= 1;
  }

  #pragma unroll
  for (int mi=0;mi<FM;mi++){
    #pragma unroll
    for (int r=0;r<4;r++){
      const int ml = wr*WM + mi*16 + kgrp*4 + r;
      const long mg = bm0 + ml;
      #pragma unroll
      for (int ni=0;ni<FN;ni++){
        const int nl = wc*WN + ni*16 + row16;
        const int ng = bn0 + nl;
        float v = acc[mi][ni][r] + bias[ng];
        if constexpr (MODE==EP_F32RES){
          v += resid[mg*ldc + ng];
          of32[mg*ldc + ng] = v;
        } else if constexpr (MODE==EP_GELU){
          obf[mg*ldc + ng] = f2bs(gelu_f(v));
        } else {
          obf[mg*ldc + ng] = f2bs(v);
        }
      }
    }
  }
}

// ---- LoRA stage-1 via MFMA ----
template<int NT>
__global__ __launch_bounds__(64) void lora_mfma(
    const u16* __restrict__ A, const int K,
    const u16* __restrict__ lat,
    u16* __restrict__ t, int tld)
{
  const int lane = threadIdx.x & 63;
  const int c = lane & 15, kg = lane >> 4;
  const int m0 = blockIdx.x * 16;
  const u16* Arow = A + (long)(m0 + c)*K + kg*8;
  const u16* Brow = lat + (long)c*K + kg*8;
  floatx4 acc[NT];
  #pragma unroll
  for (int tj=0;tj<NT;tj++) acc[tj] = (floatx4){0.f,0.f,0.f,0.f};
  const int nKS = K >> 5;
  #pragma unroll 4
  for (int ks=0; ks<nKS; ++ks){
    short8 a = *(const short8*)(Arow + ks*32);
    #pragma unroll
    for (int tj=0; tj<NT; ++tj){
      short8 b = *(const short8*)(Brow + (long)tj*16*K + ks*32);
      acc[tj] = __builtin_amdgcn_mfma_f32_16x16x32_bf16(a, b, acc[tj], 0, 0, 0);
    }
  }
  #pragma unroll
  for (int tj=0; tj<NT; ++tj)
    #pragma unroll
    for (int r=0;r<4;r++){
      u16* dst = t + (long)(m0 + kg*4 + r)*tld + tj*64;
      dst[c] = f2bs(acc[tj][r]);
      dst[16+c] = 0; dst[32+c] = 0; dst[48+c] = 0;
    }
}

// ---- fused flash attention ----
__global__ __launch_bounds__(256) void flash_attn(
    const u16* __restrict__ qkv,
    const u16* __restrict__ vt,
    const float* __restrict__ mask,
    u16* __restrict__ attn_o)
{
  __shared__ u16 sm[33792];
  u16* Qs = sm;
  u16* Ps = sm + 24576;

  const int tid = threadIdx.x, lane = tid & 63, wave = tid >> 6;
  const int c = lane & 15, kg = lane >> 4;
  const int qt = blockIdx.x;
  const int z  = blockIdx.y;
  const int b = z >> 4, h = z & 15;
  const int q0 = qt * 128;
  const int srow = lane >> 3;
  const int scol = ((lane&7) ^ srow) * 8;

  const u16* kbase = qkv + ((long)(b*512))*3072 + 1024 + h*64;
  const u16* vbase = vt + (long)z*64*512;

  auto stage_kv = [&](int kv, int buf){
    char* Kd = (char*)(sm + 8192  + buf*4096);
    char* Vd = (char*)(sm + 16384 + buf*4096);
    #pragma unroll
    for (int i=0;i<2;i++){
      int rb = i*32 + wave*8;
      GLL16(kbase + (long)(kv*64 + rb + srow)*3072 + scol, Kd + rb*128);
      GLL16(vbase + (long)(rb + srow)*512 + kv*64 + scol, Vd + rb*128);
    }
  };

  {
    const u16* src = qkv + ((long)(b*512 + q0))*3072 + h*64;
    #pragma unroll
    for (int i=0;i<4;i++){
      int rb = i*32 + wave*8;
      GLL16(src + (long)(rb + srow)*3072 + scol, (char*)Qs + rb*128);
    }
  }
  stage_kv(0, 0);
  __syncthreads();

  auto ld_swz = [&](const u16* t, int row, int koff8) -> short8 {
    return *(const short8*)((const char*)t + row*128 + ((koff8 ^ (row&7))<<4));
  };

  short8 af[2][2];
  #pragma unroll
  for (int mi=0;mi<2;mi++)
    #pragma unroll
    for (int ks=0;ks<2;ks++)
      af[mi][ks] = ld_swz(Qs, wave*32 + mi*16 + c, ks*4 + kg);

  floatx4 o_acc[2][4];
  float m_run[2][4], l_run[2][4];
  #pragma unroll
  for (int mi=0;mi<2;mi++){
    #pragma unroll
    for (int dj=0;dj<4;dj++) o_acc[mi][dj] = (floatx4){0.f,0.f,0.f,0.f};
    #pragma unroll
    for (int r=0;r<4;r++){ m_run[mi][r] = -3.0e38f; l_run[mi][r] = 0.f; }
  }

  int cur = 0;
  for (int kv=0; kv<8; ++kv){
    if (kv+1 < 8) stage_kv(kv+1, cur^1);
    const u16* Ks = sm + 8192  + cur*4096;
    const u16* Vs = sm + 16384 + cur*4096;

    floatx4 s_acc[2][4];
    #pragma unroll
    for (int mi=0;mi<2;mi++)
      #pragma unroll
      for (int ni=0;ni<4;ni++)
        s_acc[mi][ni] = (floatx4){0.f,0.f,0.f,0.f};
    #pragma unroll
    for (int ks=0;ks<2;ks++){
      short8 bf[4];
      #pragma unroll
      for (int ni=0;ni<4;ni++)
        bf[ni] = ld_swz(Ks, ni*16 + c, ks*4 + kg);
      #pragma unroll
      for (int mi=0;mi<2;mi++)
        #pragma unroll
        for (int ni=0;ni<4;ni++)
          s_acc[mi][ni] = __builtin_amdgcn_mfma_f32_16x16x32_bf16(af[mi][ks], bf[ni], s_acc[mi][ni], 0, 0, 0);
    }

    float mv[4];
    #pragma unroll
    for (int ni=0;ni<4;ni++) mv[ni] = mask[b*512 + kv*64 + ni*16 + c];

    #pragma unroll
    for (int mi=0;mi<2;mi++){
      #pragma unroll
      for (int r=0;r<4;r++){
        float s0 = s_acc[mi][0][r]*0.125f + mv[0];
        float s1 = s_acc[mi][1][r]*0.125f + mv[1];
        float s2 = s_acc[mi][2][r]*0.125f + mv[2];
        float s3 = s_acc[mi][3][r]*0.125f + mv[3];
        float tmax = fmaxf(fmaxf(s0,s1), fmaxf(s2,s3));
        #pragma unroll
        for (int o=1;o<16;o<<=1) tmax = fmaxf(tmax, __shfl_xor(tmax, o));
        const float mnew = fmaxf(m_run[mi][r], tmax);
        const float p0 = __expf(s0 - mnew), p1 = __expf(s1 - mnew);
        const float p2 = __expf(s2 - mnew), p3 = __expf(s3 - mnew);
        float psum = p0+p1+p2+p3;
        #pragma unroll
        for (int o=1;o<16;o<<=1) psum += __shfl_xor(psum, o);
        const float alpha = __expf(m_run[mi][r] - mnew);
        l_run[mi][r] = l_run[mi][r]*alpha + psum;
        m_run[mi][r] = mnew;
        #pragma unroll
        for (int dj=0;dj<4;dj++) o_acc[mi][dj][r] *= alpha;
        const int rl = mi*16 + kg*4 + r;
        u16* pw = Ps + wave*2304 + rl*72;
        pw[c]      = f2bs(p0);
        pw[16 + c] = f2bs(p1);
        pw[32 + c] = f2bs(p2);
        pw[48 + c] = f2bs(p3);
      }
    }
    __syncthreads();

    #pragma unroll
    for (int ks=0;ks<2;ks++){
      short8 pa[2], vb[4];
      #pragma unroll
      for (int mi=0;mi<2;mi++)
        pa[mi] = *(const short8*)&Ps[wave*2304 + (mi*16 + c)*72 + ks*32 + kg*8];
      #pragma unroll
      for (int dj=0;dj<4;dj++)
        vb[dj] = ld_swz(Vs, dj*16 + c, ks*4 + kg);
      __builtin_amdgcn_s_setprio(1);
      #pragma unroll
      for (int mi=0;mi<2;mi++)
        #pragma unroll
        for (int dj=0;dj<4;dj++)
          o_acc[mi][dj] = __builtin_amdgcn_mfma_f32_16x16x32_bf16(pa[mi], vb[dj], o_acc[mi][dj], 0, 0, 0);
      __builtin_amdgcn_s_setprio(0);
    }
    __syncthreads();
    cur ^= 1;
  }

  #pragma unroll
  for (int mi=0;mi<2;mi++){
    #pragma unroll
    for (int r=0;r<4;r++){
      const float inv = 1.f / l_run[mi][r];
      const int s_g = q0 + wave*32 + mi*16 + kg*4 + r;
      u16* dst = attn_o + (long)(b*512 + s_g)*1024 + h*64;
      #pragma unroll
      for (int dj=0;dj<4;dj++)
        dst[dj*16 + c] = f2bs(o_acc[mi][dj][r]*inv);
    }
  }
}

// ---- bulk fp32 -> bf16 conversion, float4 wide ----
__global__ __launch_bounds__(256) void convert_bulk(
  const float* __restrict__ x,
  const float* __restrict__ wq, const float* __restrict__ wk, const float* __restrict__ wv,
  const float* __restrict__ wo, const float* __restrict__ wup, const float* __restrict__ wdn,
  u16* __restrict__ xb, u16* __restrict__ wqkv, u16* __restrict__ wob,
  u16* __restrict__ wupb, u16* __restrict__ wdnb)
{
  const long NX = 4194304, NWt = 1048576;
  const long T4 = (NX + 3*NWt + NWt + NX + NX) >> 2;
  for (long i4 = (long)blockIdx.x*256 + threadIdx.x; i4 < T4; i4 += (long)gridDim.x*256){
    long j = i4 << 2;
    const float* src; u16* dst; long soff, doff;
    if (j < NX){ src=x; dst=xb; soff=j; doff=j; }
    else { j -= NX;
      if (j < 3*NWt){ int p=(int)(j>>20); src = p==0?wq:(p==1?wk:wv); dst=wqkv; soff = j & (NWt-1); doff = j; }
      else { j -= 3*NWt;
        if (j < NWt){ src=wo; dst=wob; soff=j; doff=j; }
        else { j -= NWt;
          if (j < NX){ src=wup; dst=wupb; soff=j; doff=j; }
          else { j -= NX; src=wdn; dst=wdnb; soff=j; doff=j; }
        }
      }
    }
    const float4 v = *(const float4*)(src + soff);
    ushort4 o;
    o.x = f2bs(v.x); o.y = f2bs(v.y); o.z = f2bs(v.z); o.w = f2bs(v.w);
    *(ushort4*)(dst + doff) = o;
  }
}

// ---- small conversions ----
__global__ __launch_bounds__(256) void convert_small(
  const float* __restrict__ bq, const float* __restrict__ bk, const float* __restrict__ bv,
  const float* __restrict__ lbq, const float* __restrict__ lbk, const float* __restrict__ lbv,
  const float* __restrict__ lbo, const float* __restrict__ lbup, const float* __restrict__ lbdn,
  const float* __restrict__ laq, const float* __restrict__ lak, const float* __restrict__ lav,
  const float* __restrict__ lao, const float* __restrict__ laup, const float* __restrict__ ladn,
  float* __restrict__ biascat, u16* __restrict__ lbtqkv, u16* __restrict__ lbto,
  u16* __restrict__ lbtup, u16* __restrict__ lbtdn,
  u16* __restrict__ latqkv, u16* __restrict__ lato,
  u16* __restrict__ latup, u16* __restrict__ latdn)
{
  long i = (long)blockIdx.x*256 + threadIdx.x;
  if (i < 3072){ int p=(int)(i>>10); biascat[i] = (p==0?bq:(p==1?bk:bv))[i&1023]; return; }
  i -= 3072;
  if (i < 49152){ int k=(int)(i/3072), n=(int)(i%3072); int p=n>>10;
    const float* l = p==0?lbq:(p==1?lbk:lbv);
    u16* d = lbtqkv + (long)n*64 + k;
    d[0] = f2bs(l[k*1024 + (n&1023)]); d[16]=0; d[32]=0; d[48]=0; return; }
  i -= 49152;
  if (i < 16384){ int k=(int)(i>>10), n=(int)(i&1023);
    u16* d = lbto + (long)n*64 + k;
    d[0] = f2bs(lbo[k*1024+n]); d[16]=0; d[32]=0; d[48]=0; return; }
  i -= 16384;
  if (i < 65536){ int k=(int)(i>>12), n=(int)(i&4095);
    u16* d = lbtup + (long)n*64 + k;
    d[0] = f2bs(lbup[k*4096+n]); d[16]=0; d[32]=0; d[48]=0; return; }
  i -= 65536;
  if (i < 16384){ int k=(int)(i>>10), n=(int)(i&1023);
    u16* d = lbtdn + (long)n*64 + k;
    d[0] = f2bs(lbdn[k*1024+n]); d[16]=0; d[32]=0; d[48]=0; return; }
  i -= 16384;
  if (i < 49152){ int r=(int)(i>>10), k=(int)(i&1023);
    const float* l = r<16 ? laq : (r<32 ? lak : lav);
    latqkv[i] = f2bs(l[k*16 + (r&15)]); return; }
  i -= 49152;
  if (i < 16384){ int r=(int)(i>>10), k=(int)(i&1023);
    lato[i] = f2bs(lao[k*16+r]); return; }
  i -= 16384;
  if (i < 16384){ int r=(int)(i>>10), k=(int)(i&1023);
    latup[i] = f2bs(laup[k*16+r]); return; }
  i -= 16384;
  if (i < 65536){ int r=(int)(i>>12), k=(int)(i&4095);
    latdn[i] = f2bs(ladn[k*16+r]); }
}

// ---- V transpose ----
__global__ __launch_bounds__(256) void transpose_v(const u16* __restrict__ qkv, u16* __restrict__ vt){
  const int st = blockIdx.x;
  const int z = blockIdx.y;
  const int b = z >> 4, h = z & 15;
  __shared__ u16 tile[64][68];
  const int t = threadIdx.x;
  const int q16 = t & 15, g16 = t >> 4;
  const u16* src = qkv + ((long)(b*512 + st*64))*3072 + 2048 + h*64;
  #pragma unroll
  for (int i=0;i<4;i++){
    int s_l = i*16 + g16;
    const u16* pp = src + (long)s_l*3072 + q16*4;
    #pragma unroll
    for (int jj=0;jj<4;jj++) tile[s_l][q16*4+jj] = pp[jj];
  }
  __syncthreads();
  u16* dst = vt + (long)z*64*512 + st*64;
  #pragma unroll
  for (int i=0;i<4;i++){
    int d_l = i*16 + g16;
    int s_l = q16*4;
    unsigned long long v = (unsigned long long)tile[s_l][d_l]
      | ((unsigned long long)tile[s_l+1][d_l] << 16)
      | ((unsigned long long)tile[s_l+2][d_l] << 32)
      | ((unsigned long long)tile[s_l+3][d_l] << 48);
    *(unsigned long long*)(dst + (long)d_l*512 + s_l) = v;
  }
}

// ---- LayerNorm ----
__global__ __launch_bounds__(256) void ln_k(
    const float* __restrict__ in, float* __restrict__ outf, u16* __restrict__ outb,
    const float* __restrict__ gam, const float* __restrict__ bet)
{
  const long row = blockIdx.x;
  const float4 v = ((const float4*)(in + row*1024))[threadIdx.x];
  float s = v.x+v.y+v.z+v.w;
  float q = v.x*v.x + v.y*v.y + v.z*v.z + v.w*v.w;
  const int lane = threadIdx.x & 63, w = threadIdx.x >> 6;
  __shared__ float rs[4], rq[4];
  #pragma unroll
  for (int o=32;o;o>>=1){ s += __shfl_down(s,o); q += __shfl_down(q,o); }
  if (!lane){ rs[w]=s; rq[w]=q; }
  __syncthreads();
  const float S = rs[0]+rs[1]+rs[2]+rs[3];
  const float Q = rq[0]+rq[1]+rq[2]+rq[3];
  const float mu = S*(1.f/1024.f);
  const float var = Q*(1.f/1024.f) - mu*mu;
  const float rstd = rsqrtf(var + 1e-5f);
  const float4 g = ((const float4*)gam)[threadIdx.x];
  const float4 b = ((const float4*)bet)[threadIdx.x];
  float4 o;
  o.x = (v.x-mu)*rstd*g.x + b.x;
  o.y = (v.y-mu)*rstd*g.y + b.y;
  o.z = (v.z-mu)*rstd*g.z + b.z;
  o.w = (v.w-mu)*rstd*g.w + b.w;
  if (outf) ((float4*)(outf + row*1024))[threadIdx.x] = o;
  if (outb){
    uint2 u;
    u.x = (unsigned)f2bs(o.x) | ((unsigned)f2bs(o.y) << 16);
    u.y = (unsigned)f2bs(o.z) | ((unsigned)f2bs(o.w) << 16);
    ((uint2*)(outb + row*1024))[threadIdx.x] = u;
  }
}

extern "C" void kernel_launch(void* const* d_in, const int* in_sizes, int n_in,
                              void* d_out, int out_size, void* d_ws, size_t ws_size,
                              hipStream_t stream) {
  const float* x      = (const float*)d_in[0];
  const float* mask   = (const float*)d_in[1];
  const float* w_q    = (const float*)d_in[2];
  const float* b_q    = (const float*)d_in[3];
  const float* la_q   = (const float*)d_in[4];
  const float* lb_q   = (const float*)d_in[5];
  const float* w_k    = (const float*)d_in[6];
  const float* b_k    = (const float*)d_in[7];
  const float* la_k   = (const float*)d_in[8];
  const float* lb_k   = (const float*)d_in[9];
  const float* w_v    = (const float*)d_in[10];
  const float* b_v    = (const float*)d_in[11];
  const float* la_v   = (const float*)d_in[12];
  const float* lb_v   = (const float*)d_in[13];
  const float* w_o    = (const float*)d_in[14];
  const float* b_o    = (const float*)d_in[15];
  const float* la_o   = (const float*)d_in[16];
  const float* lb_o   = (const float*)d_in[17];
  const float* nw1    = (const float*)d_in[18];
  const float* nb1    = (const float*)d_in[19];
  const float* w_up   = (const float*)d_in[20];
  const float* b_up   = (const float*)d_in[21];
  const float* la_up  = (const float*)d_in[22];
  const float* lb_up  = (const float*)d_in[23];
  const float* w_dn   = (const float*)d_in[24];
  const float* b_dn   = (const float*)d_in[25];
  const float* la_dn  = (const float*)d_in[26];
  const float* lb_dn  = (const float*)d_in[27];
  const float* nw2    = (const float*)d_in[28];
  const float* nb2    = (const float*)d_in[29];
  float* out = (float*)d_out;

  char* ws = (char*)d_ws;
  size_t used = 0;
  auto alloc = [&](size_t bytes) -> char* {
    char* p = ws + used;
    used += (bytes + 255) & ~(size_t)255;
    return p;
  };
  u16*   xb      = (u16*)  alloc(4194304*2);
  u16*   wqkv    = (u16*)  alloc(3145728*2);
  u16*   wob     = (u16*)  alloc(1048576*2);
  u16*   wupb    = (u16*)  alloc(4194304*2);
  u16*   wdnb    = (u16*)  alloc(4194304*2);
  float* biascat = (float*)alloc(3072*4);
  u16*   lbtqkv  = (u16*)  alloc((size_t)3072*64*2);
  u16*   lbto    = (u16*)  alloc((size_t)1024*64*2);
  u16*   lbtup   = (u16*)  alloc((size_t)4096*64*2);
  u16*   lbtdn   = (u16*)  alloc((size_t)1024*64*2);
  u16*   latqkv  = (u16*)  alloc(48*1024*2);
  u16*   lato    = (u16*)  alloc(16*1024*2);
  u16*   latup   = (u16*)  alloc(16*1024*2);
  u16*   latdn   = (u16*)  alloc(16*4096*2);
  u16*   t_all   = (u16*)  alloc((size_t)4096*192*2);
  u16*   t_o     = (u16*)  alloc((size_t)4096*64*2);
  u16*   t_up    = (u16*)  alloc((size_t)4096*64*2);
  u16*   t_dn    = (u16*)  alloc((size_t)4096*64*2);
  u16*   qkv     = (u16*)  alloc((size_t)4096*3072*2);
  u16*   vt      = (u16*)  alloc((size_t)128*64*512*2);
  u16*   attn_o  = (u16*)  alloc(4194304*2);
  float* o_final = (float*)alloc((size_t)4194304*4);
  float* x_med   = (float*)alloc((size_t)4194304*4);
  u16*   x_med_b = (u16*)  alloc(4194304*2);
  u16*   fn      = (u16*)  alloc((size_t)4096*4096*2);
  if (used > ws_size) return;

  // 1. convert
  convert_bulk<<<2048, 256, 0, stream>>>(x, w_q, w_k, w_v, w_o, w_up, w_dn,
                                         xb, wqkv, wob, wupb, wdnb);
  convert_small<<<1164, 256, 0, stream>>>(b_q, b_k, b_v, lb_q, lb_k, lb_v,
                                          lb_o, lb_up, lb_dn,
                                          la_q, la_k, la_v, la_o, la_up, la_dn,
                                          biascat, lbtqkv, lbto, lbtup, lbtdn,
                                          latqkv, lato, latup, latdn);
  // 2. LoRA stage-1 q,k,v fused
  lora_mfma<3><<<256, 64, 0, stream>>>(xb, 1024, latqkv, t_all, 192);
  // 3. fused QKV GEMM (reg-pipelined 256^2)
  gemm8<EP_BF16,true,true><<<dim3(12,16,1), 512, 0, stream>>>(
      xb, 1024, wqkv, 1024, 1024, qkv, nullptr, 3072,
      biascat, t_all, 192, lbtqkv, nullptr);
  // 4. V transpose
  transpose_v<<<dim3(8,128), 256, 0, stream>>>(qkv, vt);
  // 5. flash attention
  flash_attn<<<dim3(4,128), 256, 0, stream>>>(qkv, vt, mask, attn_o);
  // 6. LoRA stage-1 for O
  lora_mfma<1><<<256, 64, 0, stream>>>(attn_o, 1024, lato, t_o, 64);
  // 7. O projection (R9 depth-2, 64x128)
  gemm_bt<64,128,32,64,EP_F32RES,true,true><<<dim3(8,64,1), 256, 0, stream>>>(
      attn_o, 1024, wob, 1024, 1024, nullptr, o_final, 1024,
      b_o, t_o, 64, lbto, x);
  // 8. LN1
  ln_k<<<4096, 256, 0, stream>>>(o_final, x_med, x_med_b, nw1, nb1);
  // 9. LoRA stage-1 for up
  lora_mfma<1><<<256, 64, 0, stream>>>(x_med_b, 1024, latup, t_up, 64);
  // 10. up GEMM (reg-pipelined 256^2)
  gemm8<EP_GELU,true,true><<<dim3(16,16,1), 512, 0, stream>>>(
      x_med_b, 1024, wupb, 1024, 1024, fn, nullptr, 4096,
      b_up, t_up, 64, lbtup, nullptr);
  // 11. LoRA stage-1 for down (K=4096)
  lora_mfma<1><<<256, 64, 0, stream>>>(fn, 4096, latdn, t_dn, 64);
  // 12. down GEMM (R9 depth-2, 64x128)
  gemm_bt<64,128,32,64,EP_F32RES,true,true><<<dim3(8,64,1), 256, 0, stream>>>(
      fn, 4096, wdnb, 4096, 4096, nullptr, out, 1024,
      b_dn, t_dn, 64, lbtdn, x_med);
  // 13. LN2
  ln_k<<<4096, 256, 0, stream>>>(out, out, nullptr, nw2, nb2);
}

// Round 15
// 270.608 us; speedup vs baseline: 1.3969x; 1.0151x over previous
//
#include <hip/hip_runtime.h>
#include <math.h>

typedef unsigned short u16;
typedef __attribute__((ext_vector_type(8))) short short8;
typedef __attribute__((ext_vector_type(4))) float floatx4;

#define DEV __device__ __forceinline__

DEV u16 f2bs(float f){ union{float f; unsigned u;} v; v.f=f; unsigned r = v.u + 0x7fffu + ((v.u>>16)&1u); return (u16)(r>>16); }
DEV float bs2f(u16 u){ union{float f; unsigned u;} v; v.u = ((unsigned)u)<<16; return v.f; }

// tanh-form GELU (max |delta| vs exact-erf gelu ~3e-4; bf16-safe).
DEV float gelu_f(float x){
  float u2 = 2.f * x * (0.7978845608028654f + 0.03567740813636141f*x*x);
  float e = __expf(u2);
  float th = 1.f - 2.f/(e + 1.f);
  return 0.5f*x*(1.f + th);
}

#define GLL16(G,L) __builtin_amdgcn_global_load_lds((__attribute__((address_space(1))) const void*)(G), (__attribute__((address_space(3))) void*)(L), 16, 0, 0)
#define SB0() __builtin_amdgcn_sched_barrier(0)

enum { EP_BF16=0, EP_F32RES=3, EP_GELU=4 };

// XCD-chunked bijective block swizzle (m204) + group-major (G rows) ordering.
DEV void swizzle_bid(int orig, int gx, int gy, int& bx, int& by){
  const int nwg = gx*gy;
  const int q = nwg >> 3, r = nwg & 7;
  const int xcd = orig & 7, idx = orig >> 3;
  const int logical = (xcd < r) ? xcd*(q+1) + idx : r*(q+1) + (xcd-r)*q + idx;
  const int G = 8;
  const int per = G*gx;
  const int gid = logical / per;
  const int rem = logical - gid*per;
  const int by0 = gid*G;
  const int rows = min(G, gy - by0);
  by = by0 + rem % rows;
  bx = rem / rows;
}

// ================= 256x256 reg-pipelined GEMM (R14-verified) =====
template<int MODE,bool LORA,bool SWZ>
__global__ __launch_bounds__(512,2) void gemm8(
    const u16* __restrict__ A, int lda,
    const u16* __restrict__ B, int ldb,
    int K,
    u16* __restrict__ obf, float* __restrict__ of32, int ldc,
    const float* __restrict__ bias,
    const u16* __restrict__ tA, int tlda,
    const u16* __restrict__ lbB,
    const float* __restrict__ resid)
{
  __shared__ u16 sm8[65536];
  const int tid = threadIdx.x;
  const int lane = tid & 63, wave = tid >> 6;
  const int wr = wave >> 2, wc = wave & 3;
  const int row16 = lane & 15, kgrp = lane >> 4;
  int bx = blockIdx.x, by = blockIdx.y;
  if constexpr (SWZ)
    swizzle_bid(blockIdx.y*gridDim.x + blockIdx.x, gridDim.x, gridDim.y, bx, by);
  const int bm0 = by*256, bn0 = bx*256;
  const u16* Ab = A + (long)bm0*lda;
  const u16* Bb = B + (long)bn0*ldb;
  const int tsel = (LORA && tlda==192) ? ((bn0>>10)*64) : 0;
  const int srow = lane >> 3;
  const int gcol = ((lane&7) ^ srow) * 8;
  const int nKT = K >> 6;
  const int nIT = nKT + (LORA ? 1 : 0);

  auto stage_half = [&](int kt, int h, int buf){
    const int isB = h & 1, hi = h >> 1;
    const u16* src; long ld;
    if (!LORA || kt < nKT){
      if (isB){ src = Bb + kt*64; ld = ldb; } else { src = Ab + kt*64; ld = lda; }
    } else {
      if (isB){ src = lbB + (long)bn0*64; ld = 64; }
      else    { src = tA + (long)bm0*tlda + tsel; ld = tlda; }
    }
    char* base = (char*)sm8 + buf*65536 + isB*32768 + hi*16384;
    #pragma unroll
    for (int rr=0; rr<2; ++rr){
      int g = wave + rr*8;
      GLL16(src + (long)(hi*128 + g*8 + srow)*ld + gcol, base + g*1024);
    }
  };
  auto ldA = [&](int buf, int mh, int i, int ks)->short8{
    int r_ = mh*128 + wr*64 + i*16 + row16;
    return *(const short8*)((const char*)sm8 + buf*65536 + r_*128 + (((ks*4+kgrp) ^ (r_&7))<<4));
  };
  auto ldB = [&](int buf, int nh, int j, int ks)->short8{
    int r_ = nh*128 + wc*32 + j*16 + row16;
    return *(const short8*)((const char*)sm8 + buf*65536 + 32768 + r_*128 + (((ks*4+kgrp) ^ (r_&7))<<4));
  };

  floatx4 acc[8][4];
  #pragma unroll
  for (int i=0;i<8;i++)
    #pragma unroll
    for (int j=0;j<4;j++)
      acc[i][j] = (floatx4){0.f,0.f,0.f,0.f};

  stage_half(0,0,0); stage_half(0,1,0); stage_half(0,2,0); stage_half(0,3,0);
  if (nIT>1){ stage_half(1,0,1); stage_half(1,1,1); }

#define MM8(mh,nh,AR,BR) \
  { _Pragma("unroll") \
    for (int i=0;i<4;i++) \
      _Pragma("unroll") \
      for (int j=0;j<2;j++) \
        _Pragma("unroll") \
        for (int ks=0;ks<2;ks++) \
          acc[(mh)*4+i][(nh)*2+j] = __builtin_amdgcn_mfma_f32_16x16x32_bf16(AR[i][ks], BR[j][ks], acc[(mh)*4+i][(nh)*2+j], 0, 0, 0); }

  int buf = 0;
  for (int t=0; t<nIT; ++t, buf^=1){
    const bool n1 = (t+1 < nIT), n2 = (t+2 < nIT);
    if (n1){ stage_half(t+1,2,buf^1); stage_half(t+1,3,buf^1); }
    if (n1) asm volatile("s_waitcnt vmcnt(8)" ::: "memory");
    else    asm volatile("s_waitcnt vmcnt(0)" ::: "memory");
    __builtin_amdgcn_s_barrier();

    short8 a0[4][2], a1[4][2], b0[2][2], b1[2][2];
    #pragma unroll
    for (int i=0;i<4;i++){ a0[i][0]=ldA(buf,0,i,0); a0[i][1]=ldA(buf,0,i,1); }
    #pragma unroll
    for (int j=0;j<2;j++){ b0[j][0]=ldB(buf,0,j,0); b0[j][1]=ldB(buf,0,j,1); }
    SB0();
    #pragma unroll
    for (int j=0;j<2;j++){ b1[j][0]=ldB(buf,1,j,0); b1[j][1]=ldB(buf,1,j,1); }
    asm volatile("s_waitcnt lgkmcnt(4)" ::: "memory");
    SB0();
    __builtin_amdgcn_s_setprio(1);
    MM8(0,0,a0,b0);
    __builtin_amdgcn_s_setprio(0);
    SB0();
    #pragma unroll
    for (int i=0;i<4;i++){ a1[i][0]=ldA(buf,1,i,0); a1[i][1]=ldA(buf,1,i,1); }
    asm volatile("s_waitcnt lgkmcnt(8)" ::: "memory");
    SB0();
    __builtin_amdgcn_s_setprio(1);
    MM8(0,1,a0,b1);
    __builtin_amdgcn_s_setprio(0);
    asm volatile("s_waitcnt lgkmcnt(0)" ::: "memory");
    SB0();
    __builtin_amdgcn_s_barrier();
    if (n2){ stage_half(t+2,0,buf); stage_half(t+2,1,buf); }
    __builtin_amdgcn_s_setprio(1);
    MM8(1,1,a1,b1);
    MM8(1,0,a1,b0);
    __builtin_amdgcn_s_setprio(0);
  }
#undef MM8

  #pragma unroll
  for (int mi=0;mi<8;mi++){
    const int mloc = (mi<4) ? (wr*64 + mi*16) : (128 + wr*64 + (mi-4)*16);
    #pragma unroll
    for (int r=0;r<4;r++){
      const long mg = bm0 + mloc + kgrp*4 + r;
      #pragma unroll
      for (int ni=0;ni<4;ni++){
        const int nloc = (ni<2) ? (wc*32 + ni*16) : (128 + wc*32 + (ni-2)*16);
        const int ng = bn0 + nloc + row16;
        float v = acc[mi][ni][r] + bias[ng];
        if constexpr (MODE==EP_F32RES){
          v += resid[mg*ldc + ng];
          of32[mg*ldc + ng] = v;
        } else if constexpr (MODE==EP_GELU){
          obf[mg*ldc + ng] = f2bs(gelu_f(v));
        } else {
          obf[mg*ldc + ng] = f2bs(v);
        }
      }
    }
  }
}

// ============== depth-2 GEMM (down / O). SPLITK: gridDim.z=2, z=0 does
// K-low + bias+lora+resid -> of32; z=1 does K-high raw -> of32b. ==========
template<int BM,int BN,int WM,int WN,int MODE,bool LORA,bool SWZ,bool SPLITK>
__global__ __launch_bounds__((BM/WM)*(BN/WN)*64) void gemm_bt(
    const u16* __restrict__ A, int lda,
    const u16* __restrict__ B, int ldb,
    int K,
    u16* __restrict__ obf, float* __restrict__ of32, int ldc,
    const float* __restrict__ bias,
    const u16* __restrict__ tA, int tlda,
    const u16* __restrict__ lbB,
    const float* __restrict__ resid,
    float* __restrict__ of32b)
{
  constexpr int NWM = BM/WM, NWN = BN/WN, NW = NWM*NWN;
  constexpr int FM = WM/16, FN = WN/16;
  constexpr int TILE = (BM+BN)*64;
  constexpr int LPT = (BM+BN)/(8*NW);
  static_assert(NW==4 || NW==8, "4 or 8 waves");
  static_assert((BM/8)%NW==0 && (BN/8)%NW==0, "row-group striping");
  __shared__ u16 ab[2*TILE];

  const int tid = threadIdx.x;
  const int lane = tid & 63, wave = tid >> 6;
  const int wr = wave / NWN, wc = wave % NWN;
  const int row16 = lane & 15, kgrp = lane >> 4;
  int bx = blockIdx.x, by = blockIdx.y;
  if constexpr (SWZ)
    swizzle_bid(blockIdx.y*gridDim.x + blockIdx.x, gridDim.x, gridDim.y, bx, by);
  const int bm0 = by * BM, bn0 = bx * BN;
  int kz = 0;
  if constexpr (SPLITK) kz = blockIdx.z;
  const int Keff = SPLITK ? (K >> 1) : K;
  const long koff = SPLITK ? (long)kz * Keff : 0;

  const u16* Ab = A + (long)bm0*lda + koff;
  const u16* Bb = B + (long)bn0*ldb + koff;
  const int tsel = (LORA && tlda==192) ? ((bn0>>10)*64) : 0;
  const int srow = lane >> 3;
  const int gcol = ((lane&7) ^ srow) * 8;

  const int nKT = Keff >> 6;
  const bool doLora = LORA && (!SPLITK || kz == 0);
  const int nIT = nKT + (doLora ? 1 : 0);

  auto stage = [&](int kt, int buf){
    const u16 *Ak, *Bk; long la_, lb_;
    if (kt < nKT){ Ak = Ab + kt*64; la_ = lda; Bk = Bb + kt*64; lb_ = ldb; }
    else { Ak = tA + (long)bm0*tlda + tsel; la_ = tlda; Bk = lbB + (long)bn0*64; lb_ = 64; }
    char* l = (char*)(ab + buf*TILE);
    #pragma unroll
    for (int g0=0; g0<BM/8; g0+=NW){
      int g = g0 + wave;
      GLL16(Ak + (long)(g*8 + srow)*la_ + gcol, l + g*1024);
    }
    #pragma unroll
    for (int g0=0; g0<BN/8; g0+=NW){
      int g = g0 + wave;
      GLL16(Bk + (long)(g*8 + srow)*lb_ + gcol, l + BM*128 + g*1024);
    }
  };

  floatx4 acc[FM][FN];
  #pragma unroll
  for (int i=0;i<FM;i++)
    #pragma unroll
    for (int j=0;j<FN;j++)
      acc[i][j] = (floatx4){0.f,0.f,0.f,0.f};

  stage(0, 0);
  if (nIT > 1) stage(1, 1);
  int cur = 0;
  for (int kt=0; kt<nIT; ++kt){
    if (kt+1 < nIT) asm volatile("s_waitcnt vmcnt(%0)" :: "n"(LPT) : "memory");
    else            asm volatile("s_waitcnt vmcnt(0)" ::: "memory");
    __builtin_amdgcn_s_barrier();

    const char* lds = (const char*)(ab + cur*TILE);
    __builtin_amdgcn_s_setprio(1);
    #pragma unroll
    for (int ks=0; ks<2; ++ks){
      short8 af[FM], bfr[FN];
      #pragma unroll
      for (int mi=0;mi<FM;mi++){
        int r_ = wr*WM + mi*16 + row16;
        af[mi] = *(const short8*)(lds + r_*128 + (((ks*4 + kgrp) ^ (r_&7))<<4));
      }
      #pragma unroll
      for (int ni=0;ni<FN;ni++){
        int r_ = wc*WN + ni*16 + row16;
        bfr[ni] = *(const short8*)(lds + BM*128 + r_*128 + (((ks*4 + kgrp) ^ (r_&7))<<4));
      }
      #pragma unroll
      for (int mi=0;mi<FM;mi++)
        #pragma unroll
        for (int ni=0;ni<FN;ni++)
          acc[mi][ni] = __builtin_amdgcn_mfma_f32_16x16x32_bf16(af[mi], bfr[ni], acc[mi][ni], 0, 0, 0);
    }
    __builtin_amdgcn_s_setprio(0);

    asm volatile("s_waitcnt lgkmcnt(0)" ::: "memory");
    __builtin_amdgcn_sched_barrier(0);
    __builtin_amdgcn_s_barrier();
    if (kt+2 < nIT) stage(kt+2, cur);
    cur ^= 1;
  }

  #pragma unroll
  for (int mi=0;mi<FM;mi++){
    #pragma unroll
    for (int r=0;r<4;r++){
      const int ml = wr*WM + mi*16 + kgrp*4 + r;
      const long mg = bm0 + ml;
      #pragma unroll
      for (int ni=0;ni<FN;ni++){
        const int nl = wc*WN + ni*16 + row16;
        const int ng = bn0 + nl;
        if (SPLITK && kz == 1){
          of32b[mg*ldc + ng] = acc[mi][ni][r];
          continue;
        }
        float v = acc[mi][ni][r] + bias[ng];
        if constexpr (MODE==EP_F32RES){
          v += resid[mg*ldc + ng];
          of32[mg*ldc + ng] = v;
        } else if constexpr (MODE==EP_GELU){
          obf[mg*ldc + ng] = f2bs(gelu_f(v));
        } else {
          obf[mg*ldc + ng] = f2bs(v);
        }
      }
    }
  }
}

// ---- LoRA stage-1 via MFMA; KS waves split K and LDS-reduce ----
template<int NT,int KS>
__global__ __launch_bounds__(64*KS) void lora_mfma(
    const u16* __restrict__ A, const int K,
    const u16* __restrict__ lat,
    u16* __restrict__ t, int tld)
{
  const int lane = threadIdx.x & 63, wv = threadIdx.x >> 6;
  const int c = lane & 15, kg = lane >> 4;
  const int m0 = blockIdx.x * 16;
  const int Kw = K / KS;
  const u16* Arow = A + (long)(m0 + c)*K + (long)wv*Kw + kg*8;
  const u16* Brow = lat + (long)c*K + (long)wv*Kw + kg*8;
  floatx4 acc[NT];
  #pragma unroll
  for (int tj=0;tj<NT;tj++) acc[tj] = (floatx4){0.f,0.f,0.f,0.f};
  const int nKS = Kw >> 5;
  #pragma unroll 4
  for (int ks=0; ks<nKS; ++ks){
    short8 a = *(const short8*)(Arow + ks*32);
    #pragma unroll
    for (int tj=0; tj<NT; ++tj){
      short8 b = *(const short8*)(Brow + (long)tj*16*K + ks*32);
      acc[tj] = __builtin_amdgcn_mfma_f32_16x16x32_bf16(a, b, acc[tj], 0, 0, 0);
    }
  }
  if constexpr (KS == 2){
    __shared__ float red[NT*256];
    if (wv == 1){
      #pragma unroll
      for (int tj=0;tj<NT;tj++)
        #pragma unroll
        for (int r=0;r<4;r++) red[(tj*4+r)*64 + lane] = acc[tj][r];
    }
    __syncthreads();
    if (wv == 1) return;
    #pragma unroll
    for (int tj=0;tj<NT;tj++)
      #pragma unroll
      for (int r=0;r<4;r++) acc[tj][r] += red[(tj*4+r)*64 + lane];
  }
  #pragma unroll
  for (int tj=0; tj<NT; ++tj)
    #pragma unroll
    for (int r=0;r<4;r++){
      u16* dst = t + (long)(m0 + kg*4 + r)*tld + tj*64;
      dst[c] = f2bs(acc[tj][r]);
      dst[16+c] = 0; dst[32+c] = 0; dst[48+c] = 0;
    }
}

// ---- fused flash attention ----
__global__ __launch_bounds__(256) void flash_attn(
    const u16* __restrict__ qkv,
    const u16* __restrict__ vt,
    const float* __restrict__ mask,
    u16* __restrict__ attn_o)
{
  __shared__ u16 sm[33792];
  u16* Qs = sm;
  u16* Ps = sm + 24576;

  const int tid = threadIdx.x, lane = tid & 63, wave = tid >> 6;
  const int c = lane & 15, kg = lane >> 4;
  const int qt = blockIdx.x;
  const int z  = blockIdx.y;
  const int b = z >> 4, h = z & 15;
  const int q0 = qt * 128;
  const int srow = lane >> 3;
  const int scol = ((lane&7) ^ srow) * 8;

  const u16* kbase = qkv + ((long)(b*512))*3072 + 1024 + h*64;
  const u16* vbase = vt + (long)z*64*512;

  auto stage_kv = [&](int kv, int buf){
    char* Kd = (char*)(sm + 8192  + buf*4096);
    char* Vd = (char*)(sm + 16384 + buf*4096);
    #pragma unroll
    for (int i=0;i<2;i++){
      int rb = i*32 + wave*8;
      GLL16(kbase + (long)(kv*64 + rb + srow)*3072 + scol, Kd + rb*128);
      GLL16(vbase + (long)(rb + srow)*512 + kv*64 + scol, Vd + rb*128);
    }
  };

  {
    const u16* src = qkv + ((long)(b*512 + q0))*3072 + h*64;
    #pragma unroll
    for (int i=0;i<4;i++){
      int rb = i*32 + wave*8;
      GLL16(src + (long)(rb + srow)*3072 + scol, (char*)Qs + rb*128);
    }
  }
  stage_kv(0, 0);
  __syncthreads();

  auto ld_swz = [&](const u16* t, int row, int koff8) -> short8 {
    return *(const short8*)((const char*)t + row*128 + ((koff8 ^ (row&7))<<4));
  };

  short8 af[2][2];
  #pragma unroll
  for (int mi=0;mi<2;mi++)
    #pragma unroll
    for (int ks=0;ks<2;ks++)
      af[mi][ks] = ld_swz(Qs, wave*32 + mi*16 + c, ks*4 + kg);

  floatx4 o_acc[2][4];
  float m_run[2][4], l_run[2][4];
  #pragma unroll
  for (int mi=0;mi<2;mi++){
    #pragma unroll
    for (int dj=0;dj<4;dj++) o_acc[mi][dj] = (floatx4){0.f,0.f,0.f,0.f};
    #pragma unroll
    for (int r=0;r<4;r++){ m_run[mi][r] = -3.0e38f; l_run[mi][r] = 0.f; }
  }

  int cur = 0;
  for (int kv=0; kv<8; ++kv){
    if (kv+1 < 8) stage_kv(kv+1, cur^1);
    const u16* Ks = sm + 8192  + cur*4096;
    const u16* Vs = sm + 16384 + cur*4096;

    floatx4 s_acc[2][4];
    #pragma unroll
    for (int mi=0;mi<2;mi++)
      #pragma unroll
      for (int ni=0;ni<4;ni++)
        s_acc[mi][ni] = (floatx4){0.f,0.f,0.f,0.f};
    #pragma unroll
    for (int ks=0;ks<2;ks++){
      short8 bf[4];
      #pragma unroll
      for (int ni=0;ni<4;ni++)
        bf[ni] = ld_swz(Ks, ni*16 + c, ks*4 + kg);
      #pragma unroll
      for (int mi=0;mi<2;mi++)
        #pragma unroll
        for (int ni=0;ni<4;ni++)
          s_acc[mi][ni] = __builtin_amdgcn_mfma_f32_16x16x32_bf16(af[mi][ks], bf[ni], s_acc[mi][ni], 0, 0, 0);
    }

    float mv[4];
    #pragma unroll
    for (int ni=0;ni<4;ni++) mv[ni] = mask[b*512 + kv*64 + ni*16 + c];

    #pragma unroll
    for (int mi=0;mi<2;mi++){
      #pragma unroll
      for (int r=0;r<4;r++){
        float s0 = s_acc[mi][0][r]*0.125f + mv[0];
        float s1 = s_acc[mi][1][r]*0.125f + mv[1];
        float s2 = s_acc[mi][2][r]*0.125f + mv[2];
        float s3 = s_acc[mi][3][r]*0.125f + mv[3];
        float tmax = fmaxf(fmaxf(s0,s1), fmaxf(s2,s3));
        #pragma unroll
        for (int o=1;o<16;o<<=1) tmax = fmaxf(tmax, __shfl_xor(tmax, o));
        const float mnew = fmaxf(m_run[mi][r], tmax);
        const float p0 = __expf(s0 - mnew), p1 = __expf(s1 - mnew);
        const float p2 = __expf(s2 - mnew), p3 = __expf(s3 - mnew);
        float psum = p0+p1+p2+p3;
        #pragma unroll
        for (int o=1;o<16;o<<=1) psum += __shfl_xor(psum, o);
        const float alpha = __expf(m_run[mi][r] - mnew);
        l_run[mi][r] = l_run[mi][r]*alpha + psum;
        m_run[mi][r] = mnew;
        #pragma unroll
        for (int dj=0;dj<4;dj++) o_acc[mi][dj][r] *= alpha;
        const int rl = mi*16 + kg*4 + r;
        u16* pw = Ps + wave*2304 + rl*72;
        pw[c]      = f2bs(p0);
        pw[16 + c] = f2bs(p1);
        pw[32 + c] = f2bs(p2);
        pw[48 + c] = f2bs(p3);
      }
    }
    __syncthreads();

    #pragma unroll
    for (int ks=0;ks<2;ks++){
      short8 pa[2], vb[4];
      #pragma unroll
      for (int mi=0;mi<2;mi++)
        pa[mi] = *(const short8*)&Ps[wave*2304 + (mi*16 + c)*72 + ks*32 + kg*8];
      #pragma unroll
      for (int dj=0;dj<4;dj++)
        vb[dj] = ld_swz(Vs, dj*16 + c, ks*4 + kg);
      __builtin_amdgcn_s_setprio(1);
      #pragma unroll
      for (int mi=0;mi<2;mi++)
        #pragma unroll
        for (int dj=0;dj<4;dj++)
          o_acc[mi][dj] = __builtin_amdgcn_mfma_f32_16x16x32_bf16(pa[mi], vb[dj], o_acc[mi][dj], 0, 0, 0);
      __builtin_amdgcn_s_setprio(0);
    }
    __syncthreads();
    cur ^= 1;
  }

  #pragma unroll
  for (int mi=0;mi<2;mi++){
    #pragma unroll
    for (int r=0;r<4;r++){
      const float inv = 1.f / l_run[mi][r];
      const int s_g = q0 + wave*32 + mi*16 + kg*4 + r;
      u16* dst = attn_o + (long)(b*512 + s_g)*1024 + h*64;
      #pragma unroll
      for (int dj=0;dj<4;dj++)
        dst[dj*16 + c] = f2bs(o_acc[mi][dj][r]*inv);
    }
  }
}

// ---- bulk fp32 -> bf16 conversion, float4 wide ----
__global__ __launch_bounds__(256) void convert_bulk(
  const float* __restrict__ x,
  const float* __restrict__ wq, const float* __restrict__ wk, const float* __restrict__ wv,
  const float* __restrict__ wo, const float* __restrict__ wup, const float* __restrict__ wdn,
  u16* __restrict__ xb, u16* __restrict__ wqkv, u16* __restrict__ wob,
  u16* __restrict__ wupb, u16* __restrict__ wdnb)
{
  const long NX = 4194304, NWt = 1048576;
  const long T4 = (NX + 3*NWt + NWt + NX + NX) >> 2;
  for (long i4 = (long)blockIdx.x*256 + threadIdx.x; i4 < T4; i4 += (long)gridDim.x*256){
    long j = i4 << 2;
    const float* src; u16* dst; long soff, doff;
    if (j < NX){ src=x; dst=xb; soff=j; doff=j; }
    else { j -= NX;
      if (j < 3*NWt){ int p=(int)(j>>20); src = p==0?wq:(p==1?wk:wv); dst=wqkv; soff = j & (NWt-1); doff = j; }
      else { j -= 3*NWt;
        if (j < NWt){ src=wo; dst=wob; soff=j; doff=j; }
        else { j -= NWt;
          if (j < NX){ src=wup; dst=wupb; soff=j; doff=j; }
          else { j -= NX; src=wdn; dst=wdnb; soff=j; doff=j; }
        }
      }
    }
    const float4 v = *(const float4*)(src + soff);
    ushort4 o;
    o.x = f2bs(v.x); o.y = f2bs(v.y); o.z = f2bs(v.z); o.w = f2bs(v.w);
    *(ushort4*)(dst + doff) = o;
  }
}

// ---- small conversions ----
__global__ __launch_bounds__(256) void convert_small(
  const float* __restrict__ bq, const float* __restrict__ bk, const float* __restrict__ bv,
  const float* __restrict__ lbq, const float* __restrict__ lbk, const float* __restrict__ lbv,
  const float* __restrict__ lbo, const float* __restrict__ lbup, const float* __restrict__ lbdn,
  const float* __restrict__ laq, const float* __restrict__ lak, const float* __restrict__ lav,
  const float* __restrict__ lao, const float* __restrict__ laup, const float* __restrict__ ladn,
  float* __restrict__ biascat, u16* __restrict__ lbtqkv, u16* __restrict__ lbto,
  u16* __restrict__ lbtup, u16* __restrict__ lbtdn,
  u16* __restrict__ latqkv, u16* __restrict__ lato,
  u16* __restrict__ latup, u16* __restrict__ latdn)
{
  long i = (long)blockIdx.x*256 + threadIdx.x;
  if (i < 3072){ int p=(int)(i>>10); biascat[i] = (p==0?bq:(p==1?bk:bv))[i&1023]; return; }
  i -= 3072;
  if (i < 49152){ int k=(int)(i/3072), n=(int)(i%3072); int p=n>>10;
    const float* l = p==0?lbq:(p==1?lbk:lbv);
    u16* d = lbtqkv + (long)n*64 + k;
    d[0] = f2bs(l[k*1024 + (n&1023)]); d[16]=0; d[32]=0; d[48]=0; return; }
  i -= 49152;
  if (i < 16384){ int k=(int)(i>>10), n=(int)(i&1023);
    u16* d = lbto + (long)n*64 + k;
    d[0] = f2bs(lbo[k*1024+n]); d[16]=0; d[32]=0; d[48]=0; return; }
  i -= 16384;
  if (i < 65536){ int k=(int)(i>>12), n=(int)(i&4095);
    u16* d = lbtup + (long)n*64 + k;
    d[0] = f2bs(lbup[k*4096+n]); d[16]=0; d[32]=0; d[48]=0; return; }
  i -= 65536;
  if (i < 16384){ int k=(int)(i>>10), n=(int)(i&1023);
    u16* d = lbtdn + (long)n*64 + k;
    d[0] = f2bs(lbdn[k*1024+n]); d[16]=0; d[32]=0; d[48]=0; return; }
  i -= 16384;
  if (i < 49152){ int r=(int)(i>>10), k=(int)(i&1023);
    const float* l = r<16 ? laq : (r<32 ? lak : lav);
    latqkv[i] = f2bs(l[k*16 + (r&15)]); return; }
  i -= 49152;
  if (i < 16384){ int r=(int)(i>>10), k=(int)(i&1023);
    lato[i] = f2bs(lao[k*16+r]); return; }
  i -= 16384;
  if (i < 16384){ int r=(int)(i>>10), k=(int)(i&1023);
    latup[i] = f2bs(laup[k*16+r]); return; }
  i -= 16384;
  if (i < 65536){ int r=(int)(i>>12), k=(int)(i&4095);
    latdn[i] = f2bs(ladn[k*16+r]); }
}

// ---- V transpose ----
__global__ __launch_bounds__(256) void transpose_v(const u16* __restrict__ qkv, u16* __restrict__ vt){
  const int st = blockIdx.x;
  const int z = blockIdx.y;
  const int b = z >> 4, h = z & 15;
  __shared__ u16 tile[64][68];
  const int t = threadIdx.x;
  const int q16 = t & 15, g16 = t >> 4;
  const u16* src = qkv + ((long)(b*512 + st*64))*3072 + 2048 + h*64;
  #pragma unroll
  for (int i=0;i<4;i++){
    int s_l = i*16 + g16;
    const u16* pp = src + (long)s_l*3072 + q16*4;
    #pragma unroll
    for (int jj=0;jj<4;jj++) tile[s_l][q16*4+jj] = pp[jj];
  }
  __syncthreads();
  u16* dst = vt + (long)z*64*512 + st*64;
  #pragma unroll
  for (int i=0;i<4;i++){
    int d_l = i*16 + g16;
    int s_l = q16*4;
    unsigned long long v = (unsigned long long)tile[s_l][d_l]
      | ((unsigned long long)tile[s_l+1][d_l] << 16)
      | ((unsigned long long)tile[s_l+2][d_l] << 32)
      | ((unsigned long long)tile[s_l+3][d_l] << 48);
    *(unsigned long long*)(dst + (long)d_l*512 + s_l) = v;
  }
}

// ---- LayerNorm; optional second input summed pre-norm ----
__global__ __launch_bounds__(256) void ln_k(
    const float* __restrict__ in, const float* __restrict__ in2,
    float* __restrict__ outf, u16* __restrict__ outb,
    const float* __restrict__ gam, const float* __restrict__ bet)
{
  const long row = blockIdx.x;
  float4 v = ((const float4*)(in + row*1024))[threadIdx.x];
  if (in2){
    const float4 v2 = ((const float4*)(in2 + row*1024))[threadIdx.x];
    v.x += v2.x; v.y += v2.y; v.z += v2.z; v.w += v2.w;
  }
  float s = v.x+v.y+v.z+v.w;
  float q = v.x*v.x + v.y*v.y + v.z*v.z + v.w*v.w;
  const int lane = threadIdx.x & 63, w = threadIdx.x >> 6;
  __shared__ float rs[4], rq[4];
  #pragma unroll
  for (int o=32;o;o>>=1){ s += __shfl_down(s,o); q += __shfl_down(q,o); }
  if (!lane){ rs[w]=s; rq[w]=q; }
  __syncthreads();
  const float S = rs[0]+rs[1]+rs[2]+rs[3];
  const float Q = rq[0]+rq[1]+rq[2]+rq[3];
  const float mu = S*(1.f/1024.f);
  const float var = Q*(1.f/1024.f) - mu*mu;
  const float rstd = rsqrtf(var + 1e-5f);
  const float4 g = ((const float4*)gam)[threadIdx.x];
  const float4 b = ((const float4*)bet)[threadIdx.x];
  float4 o;
  o.x = (v.x-mu)*rstd*g.x + b.x;
  o.y = (v.y-mu)*rstd*g.y + b.y;
  o.z = (v.z-mu)*rstd*g.z + b.z;
  o.w = (v.w-mu)*rstd*g.w + b.w;
  if (outf) ((float4*)(outf + row*1024))[threadIdx.x] = o;
  if (outb){
    uint2 u;
    u.x = (unsigned)f2bs(o.x) | ((unsigned)f2bs(o.y) << 16);
    u.y = (unsigned)f2bs(o.z) | ((unsigned)f2bs(o.w) << 16);
    ((uint2*)(outb + row*1024))[threadIdx.x] = u;
  }
}

extern "C" void kernel_launch(void* const* d_in, const int* in_sizes, int n_in,
                              void* d_out, int out_size, void* d_ws, size_t ws_size,
                              hipStream_t stream) {
  const float* x      = (const float*)d_in[0];
  const float* mask   = (const float*)d_in[1];
  const float* w_q    = (const float*)d_in[2];
  const float* b_q    = (const float*)d_in[3];
  const float* la_q   = (const float*)d_in[4];
  const float* lb_q   = (const float*)d_in[5];
  const float* w_k    = (const float*)d_in[6];
  const float* b_k    = (const float*)d_in[7];
  const float* la_k   = (const float*)d_in[8];
  const float* lb_k   = (const float*)d_in[9];
  const float* w_v    = (const float*)d_in[10];
  const float* b_v    = (const float*)d_in[11];
  const float* la_v   = (const float*)d_in[12];
  const float* lb_v   = (const float*)d_in[13];
  const float* w_o    = (const float*)d_in[14];
  const float* b_o    = (const float*)d_in[15];
  const float* la_o   = (const float*)d_in[16];
  const float* lb_o   = (const float*)d_in[17];
  const float* nw1    = (const float*)d_in[18];
  const float* nb1    = (const float*)d_in[19];
  const float* w_up   = (const float*)d_in[20];
  const float* b_up   = (const float*)d_in[21];
  const float* la_up  = (const float*)d_in[22];
  const float* lb_up  = (const float*)d_in[23];
  const float* w_dn   = (const float*)d_in[24];
  const float* b_dn   = (const float*)d_in[25];
  const float* la_dn  = (const float*)d_in[26];
  const float* lb_dn  = (const float*)d_in[27];
  const float* nw2    = (const float*)d_in[28];
  const float* nb2    = (const float*)d_in[29];
  float* out = (float*)d_out;

  char* ws = (char*)d_ws;
  size_t used = 0;
  auto alloc = [&](size_t bytes) -> char* {
    char* p = ws + used;
    used += (bytes + 255) & ~(size_t)255;
    return p;
  };
  u16*   xb      = (u16*)  alloc(4194304*2);
  u16*   wqkv    = (u16*)  alloc(3145728*2);
  u16*   wob     = (u16*)  alloc(1048576*2);
  u16*   wupb    = (u16*)  alloc(4194304*2);
  u16*   wdnb    = (u16*)  alloc(4194304*2);
  float* biascat = (float*)alloc(3072*4);
  u16*   lbtqkv  = (u16*)  alloc((size_t)3072*64*2);
  u16*   lbto    = (u16*)  alloc((size_t)1024*64*2);
  u16*   lbtup   = (u16*)  alloc((size_t)4096*64*2);
  u16*   lbtdn   = (u16*)  alloc((size_t)1024*64*2);
  u16*   latqkv  = (u16*)  alloc(48*1024*2);
  u16*   lato    = (u16*)  alloc(16*1024*2);
  u16*   latup   = (u16*)  alloc(16*1024*2);
  u16*   latdn   = (u16*)  alloc(16*4096*2);
  u16*   t_all   = (u16*)  alloc((size_t)4096*192*2);
  u16*   t_o     = (u16*)  alloc((size_t)4096*64*2);
  u16*   t_up    = (u16*)  alloc((size_t)4096*64*2);
  u16*   t_dn    = (u16*)  alloc((size_t)4096*64*2);
  u16*   qkv     = (u16*)  alloc((size_t)4096*3072*2);
  u16*   vt      = (u16*)  alloc((size_t)128*64*512*2);
  u16*   attn_o  = (u16*)  alloc(4194304*2);
  float* o_final = (float*)alloc((size_t)4194304*4);
  float* x_med   = (float*)alloc((size_t)4194304*4);
  u16*   x_med_b = (u16*)  alloc(4194304*2);
  u16*   fn      = (u16*)  alloc((size_t)4096*4096*2);
  float* p_dn    = (float*)alloc((size_t)4194304*4);
  if (used > ws_size) return;

  // 1. convert
  convert_bulk<<<2048, 256, 0, stream>>>(x, w_q, w_k, w_v, w_o, w_up, w_dn,
                                         xb, wqkv, wob, wupb, wdnb);
  convert_small<<<1164, 256, 0, stream>>>(b_q, b_k, b_v, lb_q, lb_k, lb_v,
                                          lb_o, lb_up, lb_dn,
                                          la_q, la_k, la_v, la_o, la_up, la_dn,
                                          biascat, lbtqkv, lbto, lbtup, lbtdn,
                                          latqkv, lato, latup, latdn);
  // 2. LoRA stage-1 q,k,v fused
  lora_mfma<3,1><<<256, 64, 0, stream>>>(xb, 1024, latqkv, t_all, 192);
  // 3. fused QKV GEMM (reg-pipelined 256^2)
  gemm8<EP_BF16,true,true><<<dim3(12,16,1), 512, 0, stream>>>(
      xb, 1024, wqkv, 1024, 1024, qkv, nullptr, 3072,
      biascat, t_all, 192, lbtqkv, nullptr);
  // 4. V transpose
  transpose_v<<<dim3(8,128), 256, 0, stream>>>(qkv, vt);
  // 5. flash attention
  flash_attn<<<dim3(4,128), 256, 0, stream>>>(qkv, vt, mask, attn_o);
  // 6. LoRA stage-1 for O
  lora_mfma<1,1><<<256, 64, 0, stream>>>(attn_o, 1024, lato, t_o, 64);
  // 7. O projection (depth-2, 64x128)
  gemm_bt<64,128,32,64,EP_F32RES,true,true,false><<<dim3(8,64,1), 256, 0, stream>>>(
      attn_o, 1024, wob, 1024, 1024, nullptr, o_final, 1024,
      b_o, t_o, 64, lbto, x, nullptr);
  // 8. LN1
  ln_k<<<4096, 256, 0, stream>>>(o_final, nullptr, x_med, x_med_b, nw1, nb1);
  // 9. LoRA stage-1 for up
  lora_mfma<1,1><<<256, 64, 0, stream>>>(x_med_b, 1024, latup, t_up, 64);
  // 10. up GEMM (reg-pipelined 256^2)
  gemm8<EP_GELU,true,true><<<dim3(16,16,1), 512, 0, stream>>>(
      x_med_b, 1024, wupb, 1024, 1024, fn, nullptr, 4096,
      b_up, t_up, 64, lbtup, nullptr);
  // 11. LoRA stage-1 for down (K=4096, 2-wave K-split)
  lora_mfma<1,2><<<256, 128, 0, stream>>>(fn, 4096, latdn, t_dn, 64);
  // 12. down GEMM split-K=2: z0 -> o_final (bias+lora+resid), z1 -> p_dn (raw)
  gemm_bt<64,128,32,64,EP_F32RES,true,true,true><<<dim3(8,64,2), 256, 0, stream>>>(
      fn, 4096, wdnb, 4096, 4096, nullptr, o_final, 1024,
      b_dn, t_dn, 64, lbtdn, x_med, p_dn);
  // 13. LN2 over (o_final + p_dn) -> out
  ln_k<<<4096, 256, 0, stream>>>(o_final, p_dn, out, nullptr, nw2, nb2);
}

// Round 16
// 256.433 us; speedup vs baseline: 1.4742x; 1.0553x over previous
//
#include <hip/hip_runtime.h>
#include <math.h>

typedef unsigned short u16;
typedef __attribute__((ext_vector_type(8))) short short8;
typedef __attribute__((ext_vector_type(4))) float floatx4;

#define DEV __device__ __forceinline__

DEV u16 f2bs(float f){ union{float f; unsigned u;} v; v.f=f; unsigned r = v.u + 0x7fffu + ((v.u>>16)&1u); return (u16)(r>>16); }
DEV float bs2f(u16 u){ union{float f; unsigned u;} v; v.u = ((unsigned)u)<<16; return v.f; }

// tanh-form GELU (max |delta| vs exact-erf gelu ~3e-4; bf16-safe).
DEV float gelu_f(float x){
  float u2 = 2.f * x * (0.7978845608028654f + 0.03567740813636141f*x*x);
  float e = __expf(u2);
  float th = 1.f - 2.f/(e + 1.f);
  return 0.5f*x*(1.f + th);
}

#define GLL16(G,L) __builtin_amdgcn_global_load_lds((__attribute__((address_space(1))) const void*)(G), (__attribute__((address_space(3))) void*)(L), 16, 0, 0)
#define SB0() __builtin_amdgcn_sched_barrier(0)

enum { EP_BF16=0, EP_F32RES=3, EP_GELU=4 };

// XCD-chunked bijective block swizzle (m204) + group-major (G rows) ordering.
DEV void swizzle_bid(int orig, int gx, int gy, int& bx, int& by){
  const int nwg = gx*gy;
  const int q = nwg >> 3, r = nwg & 7;
  const int xcd = orig & 7, idx = orig >> 3;
  const int logical = (xcd < r) ? xcd*(q+1) + idx : r*(q+1) + (xcd-r)*q + idx;
  const int G = 8;
  const int per = G*gx;
  const int gid = logical / per;
  const int rem = logical - gid*per;
  const int by0 = gid*G;
  const int rows = min(G, gy - by0);
  by = by0 + rem % rows;
  bx = rem / rows;
}

// ================= 256x256 reg-pipelined GEMM (R14-verified) =====
template<int MODE,bool LORA,bool SWZ>
__global__ __launch_bounds__(512,2) void gemm8(
    const u16* __restrict__ A, int lda,
    const u16* __restrict__ B, int ldb,
    int K,
    u16* __restrict__ obf, float* __restrict__ of32, int ldc,
    const float* __restrict__ bias,
    const u16* __restrict__ tA, int tlda,
    const u16* __restrict__ lbB,
    const float* __restrict__ resid)
{
  __shared__ u16 sm8[65536];
  const int tid = threadIdx.x;
  const int lane = tid & 63, wave = tid >> 6;
  const int wr = wave >> 2, wc = wave & 3;
  const int row16 = lane & 15, kgrp = lane >> 4;
  int bx = blockIdx.x, by = blockIdx.y;
  if constexpr (SWZ)
    swizzle_bid(blockIdx.y*gridDim.x + blockIdx.x, gridDim.x, gridDim.y, bx, by);
  const int bm0 = by*256, bn0 = bx*256;
  const u16* Ab = A + (long)bm0*lda;
  const u16* Bb = B + (long)bn0*ldb;
  const int tsel = (LORA && tlda==192) ? ((bn0>>10)*64) : 0;
  const int srow = lane >> 3;
  const int gcol = ((lane&7) ^ srow) * 8;
  const int nKT = K >> 6;
  const int nIT = nKT + (LORA ? 1 : 0);

  auto stage_half = [&](int kt, int h, int buf){
    const int isB = h & 1, hi = h >> 1;
    const u16* src; long ld;
    if (!LORA || kt < nKT){
      if (isB){ src = Bb + kt*64; ld = ldb; } else { src = Ab + kt*64; ld = lda; }
    } else {
      if (isB){ src = lbB + (long)bn0*64; ld = 64; }
      else    { src = tA + (long)bm0*tlda + tsel; ld = tlda; }
    }
    char* base = (char*)sm8 + buf*65536 + isB*32768 + hi*16384;
    #pragma unroll
    for (int rr=0; rr<2; ++rr){
      int g = wave + rr*8;
      GLL16(src + (long)(hi*128 + g*8 + srow)*ld + gcol, base + g*1024);
    }
  };
  auto ldA = [&](int buf, int mh, int i, int ks)->short8{
    int r_ = mh*128 + wr*64 + i*16 + row16;
    return *(const short8*)((const char*)sm8 + buf*65536 + r_*128 + (((ks*4+kgrp) ^ (r_&7))<<4));
  };
  auto ldB = [&](int buf, int nh, int j, int ks)->short8{
    int r_ = nh*128 + wc*32 + j*16 + row16;
    return *(const short8*)((const char*)sm8 + buf*65536 + 32768 + r_*128 + (((ks*4+kgrp) ^ (r_&7))<<4));
  };

  floatx4 acc[8][4];
  #pragma unroll
  for (int i=0;i<8;i++)
    #pragma unroll
    for (int j=0;j<4;j++)
      acc[i][j] = (floatx4){0.f,0.f,0.f,0.f};

  stage_half(0,0,0); stage_half(0,1,0); stage_half(0,2,0); stage_half(0,3,0);
  if (nIT>1){ stage_half(1,0,1); stage_half(1,1,1); }

#define MM8(mh,nh,AR,BR) \
  { _Pragma("unroll") \
    for (int i=0;i<4;i++) \
      _Pragma("unroll") \
      for (int j=0;j<2;j++) \
        _Pragma("unroll") \
        for (int ks=0;ks<2;ks++) \
          acc[(mh)*4+i][(nh)*2+j] = __builtin_amdgcn_mfma_f32_16x16x32_bf16(AR[i][ks], BR[j][ks], acc[(mh)*4+i][(nh)*2+j], 0, 0, 0); }

  int buf = 0;
  for (int t=0; t<nIT; ++t, buf^=1){
    const bool n1 = (t+1 < nIT), n2 = (t+2 < nIT);
    if (n1){ stage_half(t+1,2,buf^1); stage_half(t+1,3,buf^1); }
    if (n1) asm volatile("s_waitcnt vmcnt(8)" ::: "memory");
    else    asm volatile("s_waitcnt vmcnt(0)" ::: "memory");
    __builtin_amdgcn_s_barrier();

    short8 a0[4][2], a1[4][2], b0[2][2], b1[2][2];
    #pragma unroll
    for (int i=0;i<4;i++){ a0[i][0]=ldA(buf,0,i,0); a0[i][1]=ldA(buf,0,i,1); }
    #pragma unroll
    for (int j=0;j<2;j++){ b0[j][0]=ldB(buf,0,j,0); b0[j][1]=ldB(buf,0,j,1); }
    SB0();
    #pragma unroll
    for (int j=0;j<2;j++){ b1[j][0]=ldB(buf,1,j,0); b1[j][1]=ldB(buf,1,j,1); }
    asm volatile("s_waitcnt lgkmcnt(4)" ::: "memory");
    SB0();
    __builtin_amdgcn_s_setprio(1);
    MM8(0,0,a0,b0);
    __builtin_amdgcn_s_setprio(0);
    SB0();
    #pragma unroll
    for (int i=0;i<4;i++){ a1[i][0]=ldA(buf,1,i,0); a1[i][1]=ldA(buf,1,i,1); }
    asm volatile("s_waitcnt lgkmcnt(8)" ::: "memory");
    SB0();
    __builtin_amdgcn_s_setprio(1);
    MM8(0,1,a0,b1);
    __builtin_amdgcn_s_setprio(0);
    asm volatile("s_waitcnt lgkmcnt(0)" ::: "memory");
    SB0();
    __builtin_amdgcn_s_barrier();
    if (n2){ stage_half(t+2,0,buf); stage_half(t+2,1,buf); }
    __builtin_amdgcn_s_setprio(1);
    MM8(1,1,a1,b1);
    MM8(1,0,a1,b0);
    __builtin_amdgcn_s_setprio(0);
  }
#undef MM8

  #pragma unroll
  for (int mi=0;mi<8;mi++){
    const int mloc = (mi<4) ? (wr*64 + mi*16) : (128 + wr*64 + (mi-4)*16);
    #pragma unroll
    for (int r=0;r<4;r++){
      const long mg = bm0 + mloc + kgrp*4 + r;
      #pragma unroll
      for (int ni=0;ni<4;ni++){
        const int nloc = (ni<2) ? (wc*32 + ni*16) : (128 + wc*32 + (ni-2)*16);
        const int ng = bn0 + nloc + row16;
        float v = acc[mi][ni][r] + bias[ng];
        if constexpr (MODE==EP_F32RES){
          v += resid[mg*ldc + ng];
          of32[mg*ldc + ng] = v;
        } else if constexpr (MODE==EP_GELU){
          obf[mg*ldc + ng] = f2bs(gelu_f(v));
        } else {
          obf[mg*ldc + ng] = f2bs(v);
        }
      }
    }
  }
}

// ============== depth-2 GEMM (down / O: 64x128, 4 waves; R14-verified) ====
template<int BM,int BN,int WM,int WN,int MODE,bool LORA,bool SWZ>
__global__ __launch_bounds__((BM/WM)*(BN/WN)*64) void gemm_bt(
    const u16* __restrict__ A, int lda,
    const u16* __restrict__ B, int ldb,
    int K,
    u16* __restrict__ obf, float* __restrict__ of32, int ldc,
    const float* __restrict__ bias,
    const u16* __restrict__ tA, int tlda,
    const u16* __restrict__ lbB,
    const float* __restrict__ resid)
{
  constexpr int NWM = BM/WM, NWN = BN/WN, NW = NWM*NWN;
  constexpr int FM = WM/16, FN = WN/16;
  constexpr int TILE = (BM+BN)*64;
  constexpr int LPT = (BM+BN)/(8*NW);
  static_assert(NW==4 || NW==8, "4 or 8 waves");
  static_assert((BM/8)%NW==0 && (BN/8)%NW==0, "row-group striping");
  __shared__ u16 ab[2*TILE];

  const int tid = threadIdx.x;
  const int lane = tid & 63, wave = tid >> 6;
  const int wr = wave / NWN, wc = wave % NWN;
  const int row16 = lane & 15, kgrp = lane >> 4;
  int bx = blockIdx.x, by = blockIdx.y;
  if constexpr (SWZ)
    swizzle_bid(blockIdx.y*gridDim.x + blockIdx.x, gridDim.x, gridDim.y, bx, by);
  const int bm0 = by * BM, bn0 = bx * BN;

  const u16* Ab = A + (long)bm0*lda;
  const u16* Bb = B + (long)bn0*ldb;
  const int tsel = (LORA && tlda==192) ? ((bn0>>10)*64) : 0;
  const int srow = lane >> 3;
  const int gcol = ((lane&7) ^ srow) * 8;

  const int nKT = K >> 6;
  const int nIT = nKT + (LORA ? 1 : 0);

  auto stage = [&](int kt, int buf){
    const u16 *Ak, *Bk; long la_, lb_;
    if (kt < nKT){ Ak = Ab + kt*64; la_ = lda; Bk = Bb + kt*64; lb_ = ldb; }
    else { Ak = tA + (long)bm0*tlda + tsel; la_ = tlda; Bk = lbB + (long)bn0*64; lb_ = 64; }
    char* l = (char*)(ab + buf*TILE);
    #pragma unroll
    for (int g0=0; g0<BM/8; g0+=NW){
      int g = g0 + wave;
      GLL16(Ak + (long)(g*8 + srow)*la_ + gcol, l + g*1024);
    }
    #pragma unroll
    for (int g0=0; g0<BN/8; g0+=NW){
      int g = g0 + wave;
      GLL16(Bk + (long)(g*8 + srow)*lb_ + gcol, l + BM*128 + g*1024);
    }
  };

  floatx4 acc[FM][FN];
  #pragma unroll
  for (int i=0;i<FM;i++)
    #pragma unroll
    for (int j=0;j<FN;j++)
      acc[i][j] = (floatx4){0.f,0.f,0.f,0.f};

  stage(0, 0);
  if (nIT > 1) stage(1, 1);
  int cur = 0;
  for (int kt=0; kt<nIT; ++kt){
    if (kt+1 < nIT) asm volatile("s_waitcnt vmcnt(%0)" :: "n"(LPT) : "memory");
    else            asm volatile("s_waitcnt vmcnt(0)" ::: "memory");
    __builtin_amdgcn_s_barrier();

    const char* lds = (const char*)(ab + cur*TILE);
    __builtin_amdgcn_s_setprio(1);
    #pragma unroll
    for (int ks=0; ks<2; ++ks){
      short8 af[FM], bfr[FN];
      #pragma unroll
      for (int mi=0;mi<FM;mi++){
        int r_ = wr*WM + mi*16 + row16;
        af[mi] = *(const short8*)(lds + r_*128 + (((ks*4 + kgrp) ^ (r_&7))<<4));
      }
      #pragma unroll
      for (int ni=0;ni<FN;ni++){
        int r_ = wc*WN + ni*16 + row16;
        bfr[ni] = *(const short8*)(lds + BM*128 + r_*128 + (((ks*4 + kgrp) ^ (r_&7))<<4));
      }
      #pragma unroll
      for (int mi=0;mi<FM;mi++)
        #pragma unroll
        for (int ni=0;ni<FN;ni++)
          acc[mi][ni] = __builtin_amdgcn_mfma_f32_16x16x32_bf16(af[mi], bfr[ni], acc[mi][ni], 0, 0, 0);
    }
    __builtin_amdgcn_s_setprio(0);

    asm volatile("s_waitcnt lgkmcnt(0)" ::: "memory");
    __builtin_amdgcn_sched_barrier(0);
    __builtin_amdgcn_s_barrier();
    if (kt+2 < nIT) stage(kt+2, cur);
    cur ^= 1;
  }

  #pragma unroll
  for (int mi=0;mi<FM;mi++){
    #pragma unroll
    for (int r=0;r<4;r++){
      const int ml = wr*WM + mi*16 + kgrp*4 + r;
      const long mg = bm0 + ml;
      #pragma unroll
      for (int ni=0;ni<FN;ni++){
        const int nl = wc*WN + ni*16 + row16;
        const int ng = bn0 + nl;
        float v = acc[mi][ni][r] + bias[ng];
        if constexpr (MODE==EP_F32RES){
          v += resid[mg*ldc + ng];
          of32[mg*ldc + ng] = v;
        } else if constexpr (MODE==EP_GELU){
          obf[mg*ldc + ng] = f2bs(gelu_f(v));
        } else {
          obf[mg*ldc + ng] = f2bs(v);
        }
      }
    }
  }
}

// ---- LoRA stage-1 via MFMA; KS waves split K and LDS-reduce ----
template<int NT,int KS>
__global__ __launch_bounds__(64*KS) void lora_mfma(
    const u16* __restrict__ A, const int K,
    const u16* __restrict__ lat,
    u16* __restrict__ t, int tld)
{
  const int lane = threadIdx.x & 63, wv = threadIdx.x >> 6;
  const int c = lane & 15, kg = lane >> 4;
  const int m0 = blockIdx.x * 16;
  const int Kw = K / KS;
  const u16* Arow = A + (long)(m0 + c)*K + (long)wv*Kw + kg*8;
  const u16* Brow = lat + (long)c*K + (long)wv*Kw + kg*8;
  floatx4 acc[NT];
  #pragma unroll
  for (int tj=0;tj<NT;tj++) acc[tj] = (floatx4){0.f,0.f,0.f,0.f};
  const int nKS = Kw >> 5;
  #pragma unroll 4
  for (int ks=0; ks<nKS; ++ks){
    short8 a = *(const short8*)(Arow + ks*32);
    #pragma unroll
    for (int tj=0; tj<NT; ++tj){
      short8 b = *(const short8*)(Brow + (long)tj*16*K + ks*32);
      acc[tj] = __builtin_amdgcn_mfma_f32_16x16x32_bf16(a, b, acc[tj], 0, 0, 0);
    }
  }
  if constexpr (KS == 2){
    __shared__ float red[NT*256];
    if (wv == 1){
      #pragma unroll
      for (int tj=0;tj<NT;tj++)
        #pragma unroll
        for (int r=0;r<4;r++) red[(tj*4+r)*64 + lane] = acc[tj][r];
    }
    __syncthreads();
    if (wv == 1) return;
    #pragma unroll
    for (int tj=0;tj<NT;tj++)
      #pragma unroll
      for (int r=0;r<4;r++) acc[tj][r] += red[(tj*4+r)*64 + lane];
  }
  #pragma unroll
  for (int tj=0; tj<NT; ++tj)
    #pragma unroll
    for (int r=0;r<4;r++){
      u16* dst = t + (long)(m0 + kg*4 + r)*tld + tj*64;
      dst[c] = f2bs(acc[tj][r]);
      dst[16+c] = 0; dst[32+c] = 0; dst[48+c] = 0;
    }
}

// ---- fused flash attention ----
__global__ __launch_bounds__(256) void flash_attn(
    const u16* __restrict__ qkv,
    const u16* __restrict__ vt,
    const float* __restrict__ mask,
    u16* __restrict__ attn_o)
{
  __shared__ u16 sm[33792];
  u16* Qs = sm;
  u16* Ps = sm + 24576;

  const int tid = threadIdx.x, lane = tid & 63, wave = tid >> 6;
  const int c = lane & 15, kg = lane >> 4;
  const int qt = blockIdx.x;
  const int z  = blockIdx.y;
  const int b = z >> 4, h = z & 15;
  const int q0 = qt * 128;
  const int srow = lane >> 3;
  const int scol = ((lane&7) ^ srow) * 8;

  const u16* kbase = qkv + ((long)(b*512))*3072 + 1024 + h*64;
  const u16* vbase = vt + (long)z*64*512;

  auto stage_kv = [&](int kv, int buf){
    char* Kd = (char*)(sm + 8192  + buf*4096);
    char* Vd = (char*)(sm + 16384 + buf*4096);
    #pragma unroll
    for (int i=0;i<2;i++){
      int rb = i*32 + wave*8;
      GLL16(kbase + (long)(kv*64 + rb + srow)*3072 + scol, Kd + rb*128);
      GLL16(vbase + (long)(rb + srow)*512 + kv*64 + scol, Vd + rb*128);
    }
  };

  {
    const u16* src = qkv + ((long)(b*512 + q0))*3072 + h*64;
    #pragma unroll
    for (int i=0;i<4;i++){
      int rb = i*32 + wave*8;
      GLL16(src + (long)(rb + srow)*3072 + scol, (char*)Qs + rb*128);
    }
  }
  stage_kv(0, 0);
  __syncthreads();

  auto ld_swz = [&](const u16* t, int row, int koff8) -> short8 {
    return *(const short8*)((const char*)t + row*128 + ((koff8 ^ (row&7))<<4));
  };

  short8 af[2][2];
  #pragma unroll
  for (int mi=0;mi<2;mi++)
    #pragma unroll
    for (int ks=0;ks<2;ks++)
      af[mi][ks] = ld_swz(Qs, wave*32 + mi*16 + c, ks*4 + kg);

  floatx4 o_acc[2][4];
  float m_run[2][4], l_run[2][4];
  #pragma unroll
  for (int mi=0;mi<2;mi++){
    #pragma unroll
    for (int dj=0;dj<4;dj++) o_acc[mi][dj] = (floatx4){0.f,0.f,0.f,0.f};
    #pragma unroll
    for (int r=0;r<4;r++){ m_run[mi][r] = -3.0e38f; l_run[mi][r] = 0.f; }
  }

  int cur = 0;
  for (int kv=0; kv<8; ++kv){
    if (kv+1 < 8) stage_kv(kv+1, cur^1);
    const u16* Ks = sm + 8192  + cur*4096;
    const u16* Vs = sm + 16384 + cur*4096;

    floatx4 s_acc[2][4];
    #pragma unroll
    for (int mi=0;mi<2;mi++)
      #pragma unroll
      for (int ni=0;ni<4;ni++)
        s_acc[mi][ni] = (floatx4){0.f,0.f,0.f,0.f};
    #pragma unroll
    for (int ks=0;ks<2;ks++){
      short8 bf[4];
      #pragma unroll
      for (int ni=0;ni<4;ni++)
        bf[ni] = ld_swz(Ks, ni*16 + c, ks*4 + kg);
      #pragma unroll
      for (int mi=0;mi<2;mi++)
        #pragma unroll
        for (int ni=0;ni<4;ni++)
          s_acc[mi][ni] = __builtin_amdgcn_mfma_f32_16x16x32_bf16(af[mi][ks], bf[ni], s_acc[mi][ni], 0, 0, 0);
    }

    float mv[4];
    #pragma unroll
    for (int ni=0;ni<4;ni++) mv[ni] = mask[b*512 + kv*64 + ni*16 + c];

    #pragma unroll
    for (int mi=0;mi<2;mi++){
      #pragma unroll
      for (int r=0;r<4;r++){
        float s0 = s_acc[mi][0][r]*0.125f + mv[0];
        float s1 = s_acc[mi][1][r]*0.125f + mv[1];
        float s2 = s_acc[mi][2][r]*0.125f + mv[2];
        float s3 = s_acc[mi][3][r]*0.125f + mv[3];
        float tmax = fmaxf(fmaxf(s0,s1), fmaxf(s2,s3));
        #pragma unroll
        for (int o=1;o<16;o<<=1) tmax = fmaxf(tmax, __shfl_xor(tmax, o));
        const float mnew = fmaxf(m_run[mi][r], tmax);
        const float p0 = __expf(s0 - mnew), p1 = __expf(s1 - mnew);
        const float p2 = __expf(s2 - mnew), p3 = __expf(s3 - mnew);
        float psum = p0+p1+p2+p3;
        #pragma unroll
        for (int o=1;o<16;o<<=1) psum += __shfl_xor(psum, o);
        const float alpha = __expf(m_run[mi][r] - mnew);
        l_run[mi][r] = l_run[mi][r]*alpha + psum;
        m_run[mi][r] = mnew;
        #pragma unroll
        for (int dj=0;dj<4;dj++) o_acc[mi][dj][r] *= alpha;
        const int rl = mi*16 + kg*4 + r;
        u16* pw = Ps + wave*2304 + rl*72;
        pw[c]      = f2bs(p0);
        pw[16 + c] = f2bs(p1);
        pw[32 + c] = f2bs(p2);
        pw[48 + c] = f2bs(p3);
      }
    }
    __syncthreads();

    #pragma unroll
    for (int ks=0;ks<2;ks++){
      short8 pa[2], vb[4];
      #pragma unroll
      for (int mi=0;mi<2;mi++)
        pa[mi] = *(const short8*)&Ps[wave*2304 + (mi*16 + c)*72 + ks*32 + kg*8];
      #pragma unroll
      for (int dj=0;dj<4;dj++)
        vb[dj] = ld_swz(Vs, dj*16 + c, ks*4 + kg);
      __builtin_amdgcn_s_setprio(1);
      #pragma unroll
      for (int mi=0;mi<2;mi++)
        #pragma unroll
        for (int dj=0;dj<4;dj++)
          o_acc[mi][dj] = __builtin_amdgcn_mfma_f32_16x16x32_bf16(pa[mi], vb[dj], o_acc[mi][dj], 0, 0, 0);
      __builtin_amdgcn_s_setprio(0);
    }
    __syncthreads();
    cur ^= 1;
  }

  #pragma unroll
  for (int mi=0;mi<2;mi++){
    #pragma unroll
    for (int r=0;r<4;r++){
      const float inv = 1.f / l_run[mi][r];
      const int s_g = q0 + wave*32 + mi*16 + kg*4 + r;
      u16* dst = attn_o + (long)(b*512 + s_g)*1024 + h*64;
      #pragma unroll
      for (int dj=0;dj<4;dj++)
        dst[dj*16 + c] = f2bs(o_acc[mi][dj][r]*inv);
    }
  }
}

// ---- bulk fp32 -> bf16 conversion, float4 wide ----
__global__ __launch_bounds__(256) void convert_bulk(
  const float* __restrict__ x,
  const float* __restrict__ wq, const float* __restrict__ wk, const float* __restrict__ wv,
  const float* __restrict__ wo, const float* __restrict__ wup, const float* __restrict__ wdn,
  u16* __restrict__ xb, u16* __restrict__ wqkv, u16* __restrict__ wob,
  u16* __restrict__ wupb, u16* __restrict__ wdnb)
{
  const long NX = 4194304, NWt = 1048576;
  const long T4 = (NX + 3*NWt + NWt + NX + NX) >> 2;
  for (long i4 = (long)blockIdx.x*256 + threadIdx.x; i4 < T4; i4 += (long)gridDim.x*256){
    long j = i4 << 2;
    const float* src; u16* dst; long soff, doff;
    if (j < NX){ src=x; dst=xb; soff=j; doff=j; }
    else { j -= NX;
      if (j < 3*NWt){ int p=(int)(j>>20); src = p==0?wq:(p==1?wk:wv); dst=wqkv; soff = j & (NWt-1); doff = j; }
      else { j -= 3*NWt;
        if (j < NWt){ src=wo; dst=wob; soff=j; doff=j; }
        else { j -= NWt;
          if (j < NX){ src=wup; dst=wupb; soff=j; doff=j; }
          else { j -= NX; src=wdn; dst=wdnb; soff=j; doff=j; }
        }
      }
    }
    const float4 v = *(const float4*)(src + soff);
    ushort4 o;
    o.x = f2bs(v.x); o.y = f2bs(v.y); o.z = f2bs(v.z); o.w = f2bs(v.w);
    *(ushort4*)(dst + doff) = o;
  }
}

// ---- small conversions ----
__global__ __launch_bounds__(256) void convert_small(
  const float* __restrict__ bq, const float* __restrict__ bk, const float* __restrict__ bv,
  const float* __restrict__ lbq, const float* __restrict__ lbk, const float* __restrict__ lbv,
  const float* __restrict__ lbo, const float* __restrict__ lbup, const float* __restrict__ lbdn,
  const float* __restrict__ laq, const float* __restrict__ lak, const float* __restrict__ lav,
  const float* __restrict__ lao, const float* __restrict__ laup, const float* __restrict__ ladn,
  float* __restrict__ biascat, u16* __restrict__ lbtqkv, u16* __restrict__ lbto,
  u16* __restrict__ lbtup, u16* __restrict__ lbtdn,
  u16* __restrict__ latqkv, u16* __restrict__ lato,
  u16* __restrict__ latup, u16* __restrict__ latdn)
{
  long i = (long)blockIdx.x*256 + threadIdx.x;
  if (i < 3072){ int p=(int)(i>>10); biascat[i] = (p==0?bq:(p==1?bk:bv))[i&1023]; return; }
  i -= 3072;
  if (i < 49152){ int k=(int)(i/3072), n=(int)(i%3072); int p=n>>10;
    const float* l = p==0?lbq:(p==1?lbk:lbv);
    u16* d = lbtqkv + (long)n*64 + k;
    d[0] = f2bs(l[k*1024 + (n&1023)]); d[16]=0; d[32]=0; d[48]=0; return; }
  i -= 49152;
  if (i < 16384){ int k=(int)(i>>10), n=(int)(i&1023);
    u16* d = lbto + (long)n*64 + k;
    d[0] = f2bs(lbo[k*1024+n]); d[16]=0; d[32]=0; d[48]=0; return; }
  i -= 16384;
  if (i < 65536){ int k=(int)(i>>12), n=(int)(i&4095);
    u16* d = lbtup + (long)n*64 + k;
    d[0] = f2bs(lbup[k*4096+n]); d[16]=0; d[32]=0; d[48]=0; return; }
  i -= 65536;
  if (i < 16384){ int k=(int)(i>>10), n=(int)(i&1023);
    u16* d = lbtdn + (long)n*64 + k;
    d[0] = f2bs(lbdn[k*1024+n]); d[16]=0; d[32]=0; d[48]=0; return; }
  i -= 16384;
  if (i < 49152){ int r=(int)(i>>10), k=(int)(i&1023);
    const float* l = r<16 ? laq : (r<32 ? lak : lav);
    latqkv[i] = f2bs(l[k*16 + (r&15)]); return; }
  i -= 49152;
  if (i < 16384){ int r=(int)(i>>10), k=(int)(i&1023);
    lato[i] = f2bs(lao[k*16+r]); return; }
  i -= 16384;
  if (i < 16384){ int r=(int)(i>>10), k=(int)(i&1023);
    latup[i] = f2bs(laup[k*16+r]); return; }
  i -= 16384;
  if (i < 65536){ int r=(int)(i>>12), k=(int)(i&4095);
    latdn[i] = f2bs(ladn[k*16+r]); }
}

// ---- V transpose ----
__global__ __launch_bounds__(256) void transpose_v(const u16* __restrict__ qkv, u16* __restrict__ vt){
  const int st = blockIdx.x;
  const int z = blockIdx.y;
  const int b = z >> 4, h = z & 15;
  __shared__ u16 tile[64][68];
  const int t = threadIdx.x;
  const int q16 = t & 15, g16 = t >> 4;
  const u16* src = qkv + ((long)(b*512 + st*64))*3072 + 2048 + h*64;
  #pragma unroll
  for (int i=0;i<4;i++){
    int s_l = i*16 + g16;
    const u16* pp = src + (long)s_l*3072 + q16*4;
    #pragma unroll
    for (int jj=0;jj<4;jj++) tile[s_l][q16*4+jj] = pp[jj];
  }
  __syncthreads();
  u16* dst = vt + (long)z*64*512 + st*64;
  #pragma unroll
  for (int i=0;i<4;i++){
    int d_l = i*16 + g16;
    int s_l = q16*4;
    unsigned long long v = (unsigned long long)tile[s_l][d_l]
      | ((unsigned long long)tile[s_l+1][d_l] << 16)
      | ((unsigned long long)tile[s_l+2][d_l] << 32)
      | ((unsigned long long)tile[s_l+3][d_l] << 48);
    *(unsigned long long*)(dst + (long)d_l*512 + s_l) = v;
  }
}

// ---- LayerNorm; optional second input summed pre-norm ----
__global__ __launch_bounds__(256) void ln_k(
    const float* __restrict__ in, const float* __restrict__ in2,
    float* __restrict__ outf, u16* __restrict__ outb,
    const float* __restrict__ gam, const float* __restrict__ bet)
{
  const long row = blockIdx.x;
  float4 v = ((const float4*)(in + row*1024))[threadIdx.x];
  if (in2){
    const float4 v2 = ((const float4*)(in2 + row*1024))[threadIdx.x];
    v.x += v2.x; v.y += v2.y; v.z += v2.z; v.w += v2.w;
  }
  float s = v.x+v.y+v.z+v.w;
  float q = v.x*v.x + v.y*v.y + v.z*v.z + v.w*v.w;
  const int lane = threadIdx.x & 63, w = threadIdx.x >> 6;
  __shared__ float rs[4], rq[4];
  #pragma unroll
  for (int o=32;o;o>>=1){ s += __shfl_down(s,o); q += __shfl_down(q,o); }
  if (!lane){ rs[w]=s; rq[w]=q; }
  __syncthreads();
  const float S = rs[0]+rs[1]+rs[2]+rs[3];
  const float Q = rq[0]+rq[1]+rq[2]+rq[3];
  const float mu = S*(1.f/1024.f);
  const float var = Q*(1.f/1024.f) - mu*mu;
  const float rstd = rsqrtf(var + 1e-5f);
  const float4 g = ((const float4*)gam)[threadIdx.x];
  const float4 b = ((const float4*)bet)[threadIdx.x];
  float4 o;
  o.x = (v.x-mu)*rstd*g.x + b.x;
  o.y = (v.y-mu)*rstd*g.y + b.y;
  o.z = (v.z-mu)*rstd*g.z + b.z;
  o.w = (v.w-mu)*rstd*g.w + b.w;
  if (outf) ((float4*)(outf + row*1024))[threadIdx.x] = o;
  if (outb){
    uint2 u;
    u.x = (unsigned)f2bs(o.x) | ((unsigned)f2bs(o.y) << 16);
    u.y = (unsigned)f2bs(o.z) | ((unsigned)f2bs(o.w) << 16);
    ((uint2*)(outb + row*1024))[threadIdx.x] = u;
  }
}

extern "C" void kernel_launch(void* const* d_in, const int* in_sizes, int n_in,
                              void* d_out, int out_size, void* d_ws, size_t ws_size,
                              hipStream_t stream) {
  const float* x      = (const float*)d_in[0];
  const float* mask   = (const float*)d_in[1];
  const float* w_q    = (const float*)d_in[2];
  const float* b_q    = (const float*)d_in[3];
  const float* la_q   = (const float*)d_in[4];
  const float* lb_q   = (const float*)d_in[5];
  const float* w_k    = (const float*)d_in[6];
  const float* b_k    = (const float*)d_in[7];
  const float* la_k   = (const float*)d_in[8];
  const float* lb_k   = (const float*)d_in[9];
  const float* w_v    = (const float*)d_in[10];
  const float* b_v    = (const float*)d_in[11];
  const float* la_v   = (const float*)d_in[12];
  const float* lb_v   = (const float*)d_in[13];
  const float* w_o    = (const float*)d_in[14];
  const float* b_o    = (const float*)d_in[15];
  const float* la_o   = (const float*)d_in[16];
  const float* lb_o   = (const float*)d_in[17];
  const float* nw1    = (const float*)d_in[18];
  const float* nb1    = (const float*)d_in[19];
  const float* w_up   = (const float*)d_in[20];
  const float* b_up   = (const float*)d_in[21];
  const float* la_up  = (const float*)d_in[22];
  const float* lb_up  = (const float*)d_in[23];
  const float* w_dn   = (const float*)d_in[24];
  const float* b_dn   = (const float*)d_in[25];
  const float* la_dn  = (const float*)d_in[26];
  const float* lb_dn  = (const float*)d_in[27];
  const float* nw2    = (const float*)d_in[28];
  const float* nb2    = (const float*)d_in[29];
  float* out = (float*)d_out;

  char* ws = (char*)d_ws;
  size_t used = 0;
  auto alloc = [&](size_t bytes) -> char* {
    char* p = ws + used;
    used += (bytes + 255) & ~(size_t)255;
    return p;
  };
  u16*   xb      = (u16*)  alloc(4194304*2);
  u16*   wqkv    = (u16*)  alloc(3145728*2);
  u16*   wob     = (u16*)  alloc(1048576*2);
  u16*   wupb    = (u16*)  alloc(4194304*2);
  u16*   wdnb    = (u16*)  alloc(4194304*2);
  float* biascat = (float*)alloc(3072*4);
  u16*   lbtqkv  = (u16*)  alloc((size_t)3072*64*2);
  u16*   lbto    = (u16*)  alloc((size_t)1024*64*2);
  u16*   lbtup   = (u16*)  alloc((size_t)4096*64*2);
  u16*   lbtdn   = (u16*)  alloc((size_t)1024*64*2);
  u16*   latqkv  = (u16*)  alloc(48*1024*2);
  u16*   lato    = (u16*)  alloc(16*1024*2);
  u16*   latup   = (u16*)  alloc(16*1024*2);
  u16*   latdn   = (u16*)  alloc(16*4096*2);
  u16*   t_all   = (u16*)  alloc((size_t)4096*192*2);
  u16*   t_o     = (u16*)  alloc((size_t)4096*64*2);
  u16*   t_up    = (u16*)  alloc((size_t)4096*64*2);
  u16*   t_dn    = (u16*)  alloc((size_t)4096*64*2);
  u16*   qkv     = (u16*)  alloc((size_t)4096*3072*2);
  u16*   vt      = (u16*)  alloc((size_t)128*64*512*2);
  u16*   attn_o  = (u16*)  alloc(4194304*2);
  float* o_final = (float*)alloc((size_t)4194304*4);
  float* x_med   = (float*)alloc((size_t)4194304*4);
  u16*   x_med_b = (u16*)  alloc(4194304*2);
  u16*   fn      = (u16*)  alloc((size_t)4096*4096*2);
  if (used > ws_size) return;

  // 1. convert
  convert_bulk<<<2048, 256, 0, stream>>>(x, w_q, w_k, w_v, w_o, w_up, w_dn,
                                         xb, wqkv, wob, wupb, wdnb);
  convert_small<<<1164, 256, 0, stream>>>(b_q, b_k, b_v, lb_q, lb_k, lb_v,
                                          lb_o, lb_up, lb_dn,
                                          la_q, la_k, la_v, la_o, la_up, la_dn,
                                          biascat, lbtqkv, lbto, lbtup, lbtdn,
                                          latqkv, lato, latup, latdn);
  // 2. LoRA stage-1 q,k,v fused
  lora_mfma<3,1><<<256, 64, 0, stream>>>(xb, 1024, latqkv, t_all, 192);
  // 3. fused QKV GEMM (reg-pipelined 256^2)
  gemm8<EP_BF16,true,true><<<dim3(12,16,1), 512, 0, stream>>>(
      xb, 1024, wqkv, 1024, 1024, qkv, nullptr, 3072,
      biascat, t_all, 192, lbtqkv, nullptr);
  // 4. V transpose
  transpose_v<<<dim3(8,128), 256, 0, stream>>>(qkv, vt);
  // 5. flash attention
  flash_attn<<<dim3(4,128), 256, 0, stream>>>(qkv, vt, mask, attn_o);
  // 6. LoRA stage-1 for O
  lora_mfma<1,1><<<256, 64, 0, stream>>>(attn_o, 1024, lato, t_o, 64);
  // 7. O projection (depth-2, 64x128)
  gemm_bt<64,128,32,64,EP_F32RES,true,true><<<dim3(8,64,1), 256, 0, stream>>>(
      attn_o, 1024, wob, 1024, 1024, nullptr, o_final, 1024,
      b_o, t_o, 64, lbto, x);
  // 8. LN1
  ln_k<<<4096, 256, 0, stream>>>(o_final, nullptr, x_med, x_med_b, nw1, nb1);
  // 9. LoRA stage-1 for up
  lora_mfma<1,1><<<256, 64, 0, stream>>>(x_med_b, 1024, latup, t_up, 64);
  // 10. up GEMM (reg-pipelined 256^2)
  gemm8<EP_GELU,true,true><<<dim3(16,16,1), 512, 0, stream>>>(
      x_med_b, 1024, wupb, 1024, 1024, fn, nullptr, 4096,
      b_up, t_up, 64, lbtup, nullptr);
  // 11. LoRA stage-1 for down (K=4096, 2-wave K-split)
  lora_mfma<1,2><<<256, 128, 0, stream>>>(fn, 4096, latdn, t_dn, 64);
  // 12. down GEMM (depth-2, 64x128, full K — split-K reverted, R15 regression)
  gemm_bt<64,128,32,64,EP_F32RES,true,true><<<dim3(8,64,1), 256, 0, stream>>>(
      fn, 4096, wdnb, 4096, 4096, nullptr, o_final, 1024,
      b_dn, t_dn, 64, lbtdn, x_med);
  // 13. LN2 -> out
  ln_k<<<4096, 256, 0, stream>>>(o_final, nullptr, out, nullptr, nw2, nb2);
}